// Round 1
// baseline (1962.509 us; speedup 1.0000x reference)
//
#include <hip/hip_runtime.h>
#include <math.h>

#define WF 64

__device__ __forceinline__ float lrelu(float v){ return v > 0.f ? v : 0.01f * v; }

__device__ __forceinline__ float wave_sum(float v){
#pragma unroll
  for (int s = 32; s > 0; s >>= 1) v += __shfl_xor(v, s);
  return v;
}

// float -> orderable unsigned key (monotone)
__device__ __forceinline__ unsigned fkey(float x){
  unsigned u = __float_as_uint(x);
  return (u & 0x80000000u) ? ~u : (u | 0x80000000u);
}
__device__ __forceinline__ float funkey(unsigned k){
  unsigned u = (k & 0x80000000u) ? (k & 0x7fffffffu) : ~k;
  return __uint_as_float(u);
}

// ---------------- node prep: x = lrelu(na*w1+b1); y = x@wg1[:, :64].T ; xr = dot(x, att_r)
__global__ void k_node_prep(const float* __restrict__ na, const float* __restrict__ w1,
                            const float* __restrict__ b1, const float* __restrict__ wg1,
                            const float* __restrict__ att_r,
                            float* __restrict__ y, float* __restrict__ xr, int N){
  int lane = threadIdx.x & 63;
  int wid  = (blockIdx.x * blockDim.x + threadIdx.x) >> 6;
  if (wid >= N) return;
  float xv = lrelu(na[wid] * w1[lane] + b1[lane]);
  float acc = 0.f;
  for (int k = 0; k < 64; k++){
    float xk = __shfl(xv, k);
    acc += xk * wg1[lane * 65 + k];
  }
  y[(size_t)wid * 64 + lane] = acc;
  float t = wave_sum(xv * att_r[lane]);
  if (lane == 0) xr[wid] = t;
}

// ---------------- CSR build ----------------
__global__ void k_deg(const int* __restrict__ dst, int* __restrict__ deg, int E){
  int e = blockIdx.x * 256 + threadIdx.x;
  if (e >= E) return;
  atomicAdd(&deg[dst[e]], 1);
}

__global__ void k_scan1(const int* __restrict__ deg, int* __restrict__ partial, int N){
  __shared__ int lds[1024];
  int gid = blockIdx.x * 1024 + threadIdx.x;
  lds[threadIdx.x] = (gid < N) ? deg[gid] : 0;
  __syncthreads();
  for (int s = 512; s > 0; s >>= 1){
    if (threadIdx.x < s) lds[threadIdx.x] += lds[threadIdx.x + s];
    __syncthreads();
  }
  if (threadIdx.x == 0) partial[blockIdx.x] = lds[0];
}

__global__ void k_scan2(int* __restrict__ partial, int nb, int* __restrict__ off, int N){
  if (threadIdx.x == 0){
    int run = 0;
    for (int b = 0; b < nb; b++){ int t = partial[b]; partial[b] = run; run += t; }
    off[N] = run;
  }
}

__global__ void k_scan3(const int* __restrict__ deg, const int* __restrict__ partial,
                        int* __restrict__ off, int* __restrict__ fill, int N){
  __shared__ int lds[1024];
  int gid = blockIdx.x * 1024 + threadIdx.x;
  int v = (gid < N) ? deg[gid] : 0;
  lds[threadIdx.x] = v;
  __syncthreads();
  for (int s = 1; s < 1024; s <<= 1){
    int t = (threadIdx.x >= s) ? lds[threadIdx.x - s] : 0;
    __syncthreads();
    lds[threadIdx.x] += t;
    __syncthreads();
  }
  if (gid < N){
    int excl = partial[blockIdx.x] + lds[threadIdx.x] - v;
    off[gid] = excl;
    fill[gid] = excl;
  }
}

__global__ void k_fill(const int* __restrict__ dst, const int* __restrict__ src,
                       const float* __restrict__ ea, int* __restrict__ fill,
                       int* __restrict__ csr_src, float* __restrict__ csr_ea, int E){
  int e = blockIdx.x * 256 + threadIdx.x;
  if (e >= E) return;
  int d = dst[e];
  int pos = atomicAdd(&fill[d], 1);
  csr_src[pos] = src[e];
  csr_ea[pos]  = ea[e];
}

// ---------------- edge pass A: a[e], online softmax stats per node ----------------
__global__ void k_edge_a(const int* __restrict__ off, const int* __restrict__ csr_src,
                         const float* __restrict__ csr_ea, const float* __restrict__ y,
                         const float* __restrict__ xr, const float* __restrict__ wg1,
                         const float* __restrict__ att_l,
                         float* __restrict__ av, float* __restrict__ mb, float* __restrict__ db, int N){
  int lane = threadIdx.x & 63;
  int wid  = (blockIdx.x * blockDim.x + threadIdx.x) >> 6;
  if (wid >= N) return;
  float wc  = wg1[lane * 65 + 64];
  float al  = att_l[lane];
  float xrn = xr[wid];
  int i0 = off[wid], i1 = off[wid + 1];
  float m = -1e30f, s = 0.f;
  for (int i = i0; i < i1; i++){
    int   sn = csr_src[i];
    float ea = csr_ea[i];
    float he = lrelu(y[(size_t)sn * 64 + lane] + ea * wc);
    float d  = wave_sum(he * al);
    float a  = lrelu(d + xrn);
    if (lane == 0) av[i] = a;
    float nm = fmaxf(m, a);
    s = s * __expf(m - nm) + __expf(a - nm);
    m = nm;
  }
  if (lane == 0){ mb[wid] = m; db[wid] = s; }
}

// ---------------- edge pass C: sout[n] = sum alpha * h_e ----------------
__global__ void k_edge_c(const int* __restrict__ off, const int* __restrict__ csr_src,
                         const float* __restrict__ csr_ea, const float* __restrict__ y,
                         const float* __restrict__ av, const float* __restrict__ mb,
                         const float* __restrict__ db, const float* __restrict__ wg1,
                         float* __restrict__ sout, int N){
  int lane = threadIdx.x & 63;
  int wid  = (blockIdx.x * blockDim.x + threadIdx.x) >> 6;
  if (wid >= N) return;
  float wc = wg1[lane * 65 + 64];
  float m  = mb[wid];
  float dn = db[wid];
  float inv = (dn > 0.f) ? 1.f / dn : 0.f;
  int i0 = off[wid], i1 = off[wid + 1];
  float acc = 0.f;
  for (int i = i0; i < i1; i++){
    int   sn = csr_src[i];
    float ea = csr_ea[i];
    float he = lrelu(y[(size_t)sn * 64 + lane] + ea * wc);
    float alpha = __expf(av[i] - m) * inv;
    acc += alpha * he;
  }
  sout[(size_t)wid * 64 + lane] = acc;
}

// ---------------- GRU1 (4 nodes per wave): h = sout@wg2.T+bg; x2 = relu(gru(elu(h), x)) ----------------
__global__ void k_gru1(const float* __restrict__ sout, const float* __restrict__ na,
                       const float* __restrict__ w1, const float* __restrict__ b1,
                       const float* __restrict__ wg2, const float* __restrict__ bg,
                       const float* __restrict__ wih, const float* __restrict__ whh,
                       const float* __restrict__ bih, const float* __restrict__ bhh,
                       float* __restrict__ x2, int N){
  int lane = threadIdx.x & 63;
  int wid  = (blockIdx.x * blockDim.x + threadIdx.x) >> 6;
  int base = wid * 4;
  if (base >= N) return;
  float sv[4], xo[4];
#pragma unroll
  for (int p = 0; p < 4; p++){
    int n = base + p;
    if (n < N){ sv[p] = sout[(size_t)n * 64 + lane]; xo[p] = lrelu(na[n] * w1[lane] + b1[lane]); }
    else { sv[p] = 0.f; xo[p] = 0.f; }
  }
  float bgl = bg[lane];
  float h[4] = {bgl, bgl, bgl, bgl};
  for (int k = 0; k < 64; k++){
    float wv = wg2[lane * 64 + k];
#pragma unroll
    for (int p = 0; p < 4; p++) h[p] += __shfl(sv[p], k) * wv;
  }
  float xg[4];
#pragma unroll
  for (int p = 0; p < 4; p++){ float v = h[p]; xg[p] = v > 0.f ? v : __expf(v) - 1.f; }
  float gir[4], giz[4], gin[4], ghr[4], ghz[4], ghn[4];
#pragma unroll
  for (int p = 0; p < 4; p++){
    gir[p] = bih[lane]; giz[p] = bih[64 + lane]; gin[p] = bih[128 + lane];
    ghr[p] = bhh[lane]; ghz[p] = bhh[64 + lane]; ghn[p] = bhh[128 + lane];
  }
  for (int k = 0; k < 64; k++){
    float wir = wih[lane * 64 + k], wiz = wih[(64 + lane) * 64 + k], win = wih[(128 + lane) * 64 + k];
    float whr = whh[lane * 64 + k], whz = whh[(64 + lane) * 64 + k], whn = whh[(128 + lane) * 64 + k];
#pragma unroll
    for (int p = 0; p < 4; p++){
      float a = __shfl(xg[p], k), b = __shfl(xo[p], k);
      gir[p] += a * wir; giz[p] += a * wiz; gin[p] += a * win;
      ghr[p] += b * whr; ghz[p] += b * whz; ghn[p] += b * whn;
    }
  }
#pragma unroll
  for (int p = 0; p < 4; p++){
    int n = base + p;
    if (n >= N) break;
    float r  = 1.f / (1.f + __expf(-(gir[p] + ghr[p])));
    float z  = 1.f / (1.f + __expf(-(giz[p] + ghz[p])));
    float nn = tanhf(gin[p] + r * ghn[p]);
    float xn = (1.f - z) * nn + z * xo[p];
    x2[(size_t)n * 64 + lane] = fmaxf(xn, 0.f);
  }
}

// ---------------- part2a: osum += x2; xs = x2@wm.T (in-place); t = dot(xs, att_src) ----------------
__global__ void k_part2a(const float* __restrict__ x2, const float* __restrict__ wm,
                         const float* __restrict__ att_src,
                         float* __restrict__ xs, float* __restrict__ tb,
                         float* __restrict__ scal, int N){
  int lane = threadIdx.x & 63, w = threadIdx.x >> 6;
  int gw = blockIdx.x * 4 + w, nw = gridDim.x * 4;
  float as = att_src[lane];
  float os = 0.f;
  for (int n = gw; n < N; n += nw){
    float xv = x2[(size_t)n * 64 + lane];
    os += xv;
    float acc = 0.f;
    for (int k = 0; k < 64; k++) acc += __shfl(xv, k) * wm[lane * 64 + k];
    xs[(size_t)n * 64 + lane] = acc;
    float t = wave_sum(acc * as);
    if (lane == 0) tb[n] = t;
  }
  __shared__ float lds[256];
  lds[threadIdx.x] = os;
  __syncthreads();
  if (threadIdx.x < 64)
    atomicAdd(&scal[threadIdx.x],
              lds[threadIdx.x] + lds[64 + threadIdx.x] + lds[128 + threadIdx.x] + lds[192 + threadIdx.x]);
}

// ---------------- part2b (1 wave): out = relu(osum); xd = out@wm.T; c = dot(xd, att_dst) ----------------
__global__ void k_part2b(float* __restrict__ scal, const float* __restrict__ wm,
                         const float* __restrict__ att_dst){
  int lane = threadIdx.x;
  float o = fmaxf(scal[lane], 0.f);
  float acc = 0.f;
  for (int k = 0; k < 64; k++) acc += __shfl(o, k) * wm[lane * 64 + k];
  float c = wave_sum(acc * att_dst[lane]);
  scal[64 + lane] = o;
  if (lane == 0) scal[128] = c;
}

// ---------------- a2 max reduction ----------------
__global__ void k_a2max(const float* __restrict__ tb, const float* __restrict__ scal,
                        unsigned* __restrict__ mkey, int N){
  int gid = blockIdx.x * 256 + threadIdx.x;
  float c = scal[128];
  float v = (gid < N) ? lrelu(tb[gid] + c) : -1e30f;
  __shared__ float lds[256];
  lds[threadIdx.x] = v;
  __syncthreads();
  for (int s = 128; s > 0; s >>= 1){
    if (threadIdx.x < s) lds[threadIdx.x] = fmaxf(lds[threadIdx.x], lds[threadIdx.x + s]);
    __syncthreads();
  }
  if (threadIdx.x == 0) atomicMax(mkey, fkey(lds[0]));
}

// ---------------- a2 weighted sums: S = sum w; h2acc = sum w*xs ----------------
__global__ void k_a2sum(const float* __restrict__ tb, const float* __restrict__ xs,
                        float* __restrict__ scal, int N){
  int lane = threadIdx.x & 63, w = threadIdx.x >> 6;
  int gw = blockIdx.x * 4 + w, nw = gridDim.x * 4;
  float c = scal[128];
  float M = funkey(__float_as_uint(scal[130]));
  float hloc = 0.f, sloc = 0.f;
  for (int n = gw; n < N; n += nw){
    float a2 = lrelu(tb[n] + c);
    float wt = __expf(a2 - M);
    sloc += wt;
    hloc += wt * xs[(size_t)n * 64 + lane];
  }
  __shared__ float lds[256];
  __shared__ float sred[4];
  lds[threadIdx.x] = hloc;
  if (lane == 0) sred[w] = sloc;
  __syncthreads();
  if (threadIdx.x < 64)
    atomicAdd(&scal[192 + threadIdx.x],
              lds[threadIdx.x] + lds[64 + threadIdx.x] + lds[128 + threadIdx.x] + lds[192 + threadIdx.x]);
  if (threadIdx.x == 0) atomicAdd(&scal[129], sred[0] + sred[1] + sred[2] + sred[3]);
}

// ---------------- final (1 wave): h2; GRU2; out@w2.T + b2 ----------------
__global__ void k_final(const float* __restrict__ scal, const float* __restrict__ bm,
                        const float* __restrict__ wih, const float* __restrict__ whh,
                        const float* __restrict__ bih, const float* __restrict__ bhh,
                        const float* __restrict__ w2, const float* __restrict__ b2,
                        float* __restrict__ dout){
  int lane = threadIdx.x;
  float S  = scal[129];
  float h2 = scal[192 + lane] / S + bm[lane];
  float xg = h2 > 0.f ? h2 : __expf(h2) - 1.f;
  float xo = scal[64 + lane];
  float gir = bih[lane], giz = bih[64 + lane], gin = bih[128 + lane];
  float ghr = bhh[lane], ghz = bhh[64 + lane], ghn = bhh[128 + lane];
  for (int k = 0; k < 64; k++){
    float a = __shfl(xg, k), b = __shfl(xo, k);
    gir += a * wih[lane * 64 + k]; giz += a * wih[(64 + lane) * 64 + k]; gin += a * wih[(128 + lane) * 64 + k];
    ghr += b * whh[lane * 64 + k]; ghz += b * whh[(64 + lane) * 64 + k]; ghn += b * whh[(128 + lane) * 64 + k];
  }
  float r  = 1.f / (1.f + __expf(-(gir + ghr)));
  float z  = 1.f / (1.f + __expf(-(giz + ghz)));
  float nn = tanhf(gin + r * ghn);
  float o2 = fmaxf((1.f - z) * nn + z * xo, 0.f);
  float res = 0.f;
  for (int k = 0; k < 64; k++) res += __shfl(o2, k) * w2[lane * 64 + k];
  dout[lane] = res + b2[lane];
}

extern "C" void kernel_launch(void* const* d_in, const int* in_sizes, int n_in,
                              void* d_out, int out_size, void* d_ws, size_t ws_size,
                              hipStream_t stream){
  const float* na    = (const float*)d_in[0];
  const float* ea    = (const float*)d_in[1];
  const int*   ei    = (const int*)d_in[2];
  const float* w1    = (const float*)d_in[3];
  const float* b1    = (const float*)d_in[4];
  const float* wg1   = (const float*)d_in[5];
  const float* att_l = (const float*)d_in[6];
  const float* att_r = (const float*)d_in[7];
  const float* wg2   = (const float*)d_in[8];
  const float* bg    = (const float*)d_in[9];
  const float* g1wih = (const float*)d_in[10];
  const float* g1whh = (const float*)d_in[11];
  const float* g1bih = (const float*)d_in[12];
  const float* g1bhh = (const float*)d_in[13];
  const float* wm      = (const float*)d_in[14];
  const float* att_src = (const float*)d_in[15];
  const float* att_dst = (const float*)d_in[16];
  const float* bm      = (const float*)d_in[17];
  const float* g2wih = (const float*)d_in[18];
  const float* g2whh = (const float*)d_in[19];
  const float* g2bih = (const float*)d_in[20];
  const float* g2bhh = (const float*)d_in[21];
  const float* w2    = (const float*)d_in[22];
  const float* b2    = (const float*)d_in[23];

  int N = in_sizes[0];   // node_attr has IN_DIM=1
  int E = in_sizes[1];   // edge_attr has EDGE_DIM=1
  const int* srcArr = ei;
  const int* dstArr = ei + E;

  char* ws = (char*)d_ws;
  size_t cur = 0;
  auto alloc = [&](size_t nbytes) -> char* {
    char* p = ws + cur;
    cur += (nbytes + 255) & ~(size_t)255;
    return p;
  };
  float* y     = (float*)alloc((size_t)N * 64 * 4);
  float* bufC  = (float*)alloc((size_t)N * 64 * 4);   // sout -> x2 -> xs
  float* xr    = (float*)alloc((size_t)N * 4);
  float* tb    = (float*)alloc((size_t)N * 4);
  float* mb    = (float*)alloc((size_t)N * 4);
  float* db    = (float*)alloc((size_t)N * 4);
  int*   deg   = (int*)alloc((size_t)N * 4);
  int*   offA  = (int*)alloc((size_t)(N + 1) * 4);
  int*   fill  = (int*)alloc((size_t)N * 4);
  int*   part  = (int*)alloc(1024);
  int*   csr_s = (int*)alloc((size_t)E * 4);
  float* csr_e = (float*)alloc((size_t)E * 4);
  float* av    = (float*)alloc((size_t)E * 4);
  float* scal  = (float*)alloc(4096);
  if (cur > ws_size) return;  // workspace too small; fail loudly via wrong output

  hipMemsetAsync(deg,  0, (size_t)N * 4, stream);
  hipMemsetAsync(scal, 0, 4096, stream);

  int nwb = (N + 3) / 4;           // 4 waves/block, 1 node/wave
  k_node_prep<<<nwb, 256, 0, stream>>>(na, w1, b1, wg1, att_r, y, xr, N);
  k_deg<<<(E + 255) / 256, 256, 0, stream>>>(dstArr, deg, E);
  int nb = (N + 1023) / 1024;
  k_scan1<<<nb, 1024, 0, stream>>>(deg, part, N);
  k_scan2<<<1, 64, 0, stream>>>(part, nb, offA, N);
  k_scan3<<<nb, 1024, 0, stream>>>(deg, part, offA, fill, N);
  k_fill<<<(E + 255) / 256, 256, 0, stream>>>(dstArr, srcArr, ea, fill, csr_s, csr_e, E);
  k_edge_a<<<nwb, 256, 0, stream>>>(offA, csr_s, csr_e, y, xr, wg1, att_l, av, mb, db, N);
  k_edge_c<<<nwb, 256, 0, stream>>>(offA, csr_s, csr_e, y, av, mb, db, wg1, bufC, N);
  int ngb = (N + 15) / 16;         // 4 waves/block, 4 nodes/wave
  k_gru1<<<ngb, 256, 0, stream>>>(bufC, na, w1, b1, wg2, bg, g1wih, g1whh, g1bih, g1bhh, bufC, N);
  k_part2a<<<512, 256, 0, stream>>>(bufC, wm, att_src, bufC, tb, scal, N);
  k_part2b<<<1, 64, 0, stream>>>(scal, wm, att_dst);
  k_a2max<<<(N + 255) / 256, 256, 0, stream>>>(tb, scal, (unsigned*)(scal + 130), N);
  k_a2sum<<<512, 256, 0, stream>>>(tb, bufC, scal, N);
  k_final<<<1, 64, 0, stream>>>(scal, bm, g2wih, g2whh, g2bih, g2bhh, w2, b2, (float*)d_out);
  (void)n_in; (void)out_size;
}

// Round 2
// 911.889 us; speedup vs baseline: 2.1521x; 2.1521x over previous
//
#include <hip/hip_runtime.h>
#include <math.h>

#define WF 64
#define NPW 8   // nodes per wave in GRU1

__device__ __forceinline__ float lrelu(float v){ return v > 0.f ? v : 0.01f * v; }

__device__ __forceinline__ float wave_sum(float v){
#pragma unroll
  for (int s = 32; s > 0; s >>= 1) v += __shfl_xor(v, s);
  return v;
}

// wave-uniform broadcast of lane k's value via v_readlane (VALU, no LDS pipe)
__device__ __forceinline__ float bcast(float v, int k){
  return __uint_as_float((unsigned)__builtin_amdgcn_readlane(__float_as_uint(v), k));
}

// float -> orderable unsigned key (monotone)
__device__ __forceinline__ unsigned fkey(float x){
  unsigned u = __float_as_uint(x);
  return (u & 0x80000000u) ? ~u : (u | 0x80000000u);
}
__device__ __forceinline__ float funkey(unsigned k){
  unsigned u = (k & 0x80000000u) ? (k & 0x7fffffffu) : ~k;
  return __uint_as_float(u);
}

// ---------------- weight transpose to k-major (coalesced inner loops) ----------------
// wg1_t[k][r] (r<64), wg2_t[k][r], wm_t[k][r], wih_t[k][r] (r<192), whh_t[k][r]
__global__ void k_wprep(const float* __restrict__ wg1, const float* __restrict__ wg2,
                        const float* __restrict__ wih, const float* __restrict__ whh,
                        const float* __restrict__ wm,
                        float* __restrict__ wg1_t, float* __restrict__ wg2_t,
                        float* __restrict__ wih_t, float* __restrict__ whh_t,
                        float* __restrict__ wm_t){
  int k = blockIdx.x;      // 0..63
  int r = threadIdx.x;     // 0..191
  if (r < 64){
    wg1_t[k * 64 + r] = wg1[r * 65 + k];
    wg2_t[k * 64 + r] = wg2[r * 64 + k];
    wm_t [k * 64 + r] = wm [r * 64 + k];
  }
  wih_t[k * 192 + r] = wih[r * 64 + k];
  whh_t[k * 192 + r] = whh[r * 64 + k];
}

// ---------------- node prep: x = lrelu(na*w1+b1); y = x@wg1[:, :64].T ; xr = dot(x, att_r)
__global__ void k_node_prep(const float* __restrict__ na, const float* __restrict__ w1,
                            const float* __restrict__ b1, const float* __restrict__ wg1_t,
                            const float* __restrict__ att_r,
                            float* __restrict__ y, float* __restrict__ xr, int N){
  int lane = threadIdx.x & 63;
  int wid  = (blockIdx.x * blockDim.x + threadIdx.x) >> 6;
  if (wid >= N) return;
  float xv = lrelu(na[wid] * w1[lane] + b1[lane]);
  float acc = 0.f;
#pragma unroll 8
  for (int k = 0; k < 64; k++)
    acc += bcast(xv, k) * wg1_t[k * 64 + lane];
  y[(size_t)wid * 64 + lane] = acc;
  float t = wave_sum(xv * att_r[lane]);
  if (lane == 0) xr[wid] = t;
}

// ---------------- CSR build ----------------
__global__ void k_deg(const int* __restrict__ dst, int* __restrict__ deg, int E){
  int e = blockIdx.x * 256 + threadIdx.x;
  if (e >= E) return;
  atomicAdd(&deg[dst[e]], 1);
}

__global__ void k_scan1(const int* __restrict__ deg, int* __restrict__ partial, int N){
  __shared__ int lds[1024];
  int gid = blockIdx.x * 1024 + threadIdx.x;
  lds[threadIdx.x] = (gid < N) ? deg[gid] : 0;
  __syncthreads();
  for (int s = 512; s > 0; s >>= 1){
    if (threadIdx.x < s) lds[threadIdx.x] += lds[threadIdx.x + s];
    __syncthreads();
  }
  if (threadIdx.x == 0) partial[blockIdx.x] = lds[0];
}

__global__ void k_scan2(int* __restrict__ partial, int nb, int* __restrict__ off, int N){
  if (threadIdx.x == 0){
    int run = 0;
    for (int b = 0; b < nb; b++){ int t = partial[b]; partial[b] = run; run += t; }
    off[N] = run;
  }
}

__global__ void k_scan3(const int* __restrict__ deg, const int* __restrict__ partial,
                        int* __restrict__ off, int* __restrict__ fill, int N){
  __shared__ int lds[1024];
  int gid = blockIdx.x * 1024 + threadIdx.x;
  int v = (gid < N) ? deg[gid] : 0;
  lds[threadIdx.x] = v;
  __syncthreads();
  for (int s = 1; s < 1024; s <<= 1){
    int t = (threadIdx.x >= s) ? lds[threadIdx.x - s] : 0;
    __syncthreads();
    lds[threadIdx.x] += t;
    __syncthreads();
  }
  if (gid < N){
    int excl = partial[blockIdx.x] + lds[threadIdx.x] - v;
    off[gid] = excl;
    fill[gid] = excl;
  }
}

__global__ void k_fill(const int* __restrict__ dst, const int* __restrict__ src,
                       const float* __restrict__ ea, int* __restrict__ fill,
                       int* __restrict__ csr_src, float* __restrict__ csr_ea, int E){
  int e = blockIdx.x * 256 + threadIdx.x;
  if (e >= E) return;
  int d = dst[e];
  int pos = atomicAdd(&fill[d], 1);
  csr_src[pos] = src[e];
  csr_ea[pos]  = ea[e];
}

// ---------------- edge pass A: a[e], online softmax stats per node ----------------
__global__ void k_edge_a(const int* __restrict__ off, const int* __restrict__ csr_src,
                         const float* __restrict__ csr_ea, const float* __restrict__ y,
                         const float* __restrict__ xr, const float* __restrict__ wg1,
                         const float* __restrict__ att_l,
                         float* __restrict__ av, float* __restrict__ mb, float* __restrict__ db, int N){
  int lane = threadIdx.x & 63;
  int wid  = (blockIdx.x * blockDim.x + threadIdx.x) >> 6;
  if (wid >= N) return;
  float wc  = wg1[lane * 65 + 64];
  float al  = att_l[lane];
  float xrn = xr[wid];
  int i0 = off[wid], i1 = off[wid + 1];
  float m = -1e30f, s = 0.f;
  for (int i = i0; i < i1; i++){
    int   sn = csr_src[i];
    float ea = csr_ea[i];
    float he = lrelu(y[(size_t)sn * 64 + lane] + ea * wc);
    float d  = wave_sum(he * al);
    float a  = lrelu(d + xrn);
    if (lane == 0) av[i] = a;
    float nm = fmaxf(m, a);
    s = s * __expf(m - nm) + __expf(a - nm);
    m = nm;
  }
  if (lane == 0){ mb[wid] = m; db[wid] = s; }
}

// ---------------- edge pass C: sout[n] = sum alpha * h_e ----------------
__global__ void k_edge_c(const int* __restrict__ off, const int* __restrict__ csr_src,
                         const float* __restrict__ csr_ea, const float* __restrict__ y,
                         const float* __restrict__ av, const float* __restrict__ mb,
                         const float* __restrict__ db, const float* __restrict__ wg1,
                         float* __restrict__ sout, int N){
  int lane = threadIdx.x & 63;
  int wid  = (blockIdx.x * blockDim.x + threadIdx.x) >> 6;
  if (wid >= N) return;
  float wc = wg1[lane * 65 + 64];
  float m  = mb[wid];
  float dn = db[wid];
  float inv = (dn > 0.f) ? 1.f / dn : 0.f;
  int i0 = off[wid], i1 = off[wid + 1];
  float acc = 0.f;
  for (int i = i0; i < i1; i++){
    int   sn = csr_src[i];
    float ea = csr_ea[i];
    float he = lrelu(y[(size_t)sn * 64 + lane] + ea * wc);
    float alpha = __expf(av[i] - m) * inv;
    acc += alpha * he;
  }
  sout[(size_t)wid * 64 + lane] = acc;
}

// ---------------- GRU1 (NPW nodes per wave): h = sout@wg2.T+bg; x2 = relu(gru(elu(h), x)) ----------------
__global__ void k_gru1(const float* __restrict__ sout, const float* __restrict__ na,
                       const float* __restrict__ w1, const float* __restrict__ b1,
                       const float* __restrict__ wg2_t, const float* __restrict__ bg,
                       const float* __restrict__ wih_t, const float* __restrict__ whh_t,
                       const float* __restrict__ bih, const float* __restrict__ bhh,
                       float* __restrict__ x2, int N){
  int lane = threadIdx.x & 63;
  int wid  = (blockIdx.x * blockDim.x + threadIdx.x) >> 6;
  int base = wid * NPW;
  if (base >= N) return;
  float sv[NPW], xo[NPW];
#pragma unroll
  for (int p = 0; p < NPW; p++){
    int n = base + p;
    if (n < N){ sv[p] = sout[(size_t)n * 64 + lane]; xo[p] = lrelu(na[n] * w1[lane] + b1[lane]); }
    else { sv[p] = 0.f; xo[p] = 0.f; }
  }
  float bgl = bg[lane];
  float h[NPW];
#pragma unroll
  for (int p = 0; p < NPW; p++) h[p] = bgl;
#pragma unroll 4
  for (int k = 0; k < 64; k++){
    float wv = wg2_t[k * 64 + lane];
#pragma unroll
    for (int p = 0; p < NPW; p++) h[p] += bcast(sv[p], k) * wv;
  }
  float xg[NPW];
#pragma unroll
  for (int p = 0; p < NPW; p++){ float v = h[p]; xg[p] = v > 0.f ? v : __expf(v) - 1.f; }
  float gir[NPW], giz[NPW], gin[NPW], ghr[NPW], ghz[NPW], ghn[NPW];
#pragma unroll
  for (int p = 0; p < NPW; p++){
    gir[p] = bih[lane]; giz[p] = bih[64 + lane]; gin[p] = bih[128 + lane];
    ghr[p] = bhh[lane]; ghz[p] = bhh[64 + lane]; ghn[p] = bhh[128 + lane];
  }
#pragma unroll 2
  for (int k = 0; k < 64; k++){
    const float* wi = wih_t + k * 192;
    const float* wh = whh_t + k * 192;
    float wir = wi[lane], wiz = wi[64 + lane], win = wi[128 + lane];
    float whr = wh[lane], whz = wh[64 + lane], whn = wh[128 + lane];
#pragma unroll
    for (int p = 0; p < NPW; p++){
      float a = bcast(xg[p], k), b = bcast(xo[p], k);
      gir[p] += a * wir; giz[p] += a * wiz; gin[p] += a * win;
      ghr[p] += b * whr; ghz[p] += b * whz; ghn[p] += b * whn;
    }
  }
#pragma unroll
  for (int p = 0; p < NPW; p++){
    int n = base + p;
    if (n >= N) break;
    float r  = 1.f / (1.f + __expf(-(gir[p] + ghr[p])));
    float z  = 1.f / (1.f + __expf(-(giz[p] + ghz[p])));
    float nn = tanhf(gin[p] + r * ghn[p]);
    float xn = (1.f - z) * nn + z * xo[p];
    x2[(size_t)n * 64 + lane] = fmaxf(xn, 0.f);
  }
}

// ---------------- part2a: osum += x2; xs = x2@wm.T (in-place); t = dot(xs, att_src) ----------------
__global__ void k_part2a(const float* __restrict__ x2, const float* __restrict__ wm_t,
                         const float* __restrict__ att_src,
                         float* __restrict__ xs, float* __restrict__ tb,
                         float* __restrict__ scal, int N){
  int lane = threadIdx.x & 63, w = threadIdx.x >> 6;
  int gw = blockIdx.x * 4 + w, nw = gridDim.x * 4;
  float as = att_src[lane];
  float os = 0.f;
  for (int n = gw; n < N; n += nw){
    float xv = x2[(size_t)n * 64 + lane];
    os += xv;
    float acc = 0.f;
#pragma unroll 8
    for (int k = 0; k < 64; k++) acc += bcast(xv, k) * wm_t[k * 64 + lane];
    xs[(size_t)n * 64 + lane] = acc;
    float t = wave_sum(acc * as);
    if (lane == 0) tb[n] = t;
  }
  __shared__ float lds[256];
  lds[threadIdx.x] = os;
  __syncthreads();
  if (threadIdx.x < 64)
    atomicAdd(&scal[threadIdx.x],
              lds[threadIdx.x] + lds[64 + threadIdx.x] + lds[128 + threadIdx.x] + lds[192 + threadIdx.x]);
}

// ---------------- part2b (1 wave): out = relu(osum); xd = out@wm.T; c = dot(xd, att_dst) ----------------
__global__ void k_part2b(float* __restrict__ scal, const float* __restrict__ wm,
                         const float* __restrict__ att_dst){
  int lane = threadIdx.x;
  float o = fmaxf(scal[lane], 0.f);
  float acc = 0.f;
  for (int k = 0; k < 64; k++) acc += bcast(o, k) * wm[lane * 64 + k];
  float c = wave_sum(acc * att_dst[lane]);
  scal[64 + lane] = o;
  if (lane == 0) scal[128] = c;
}

// ---------------- a2 max reduction ----------------
__global__ void k_a2max(const float* __restrict__ tb, const float* __restrict__ scal,
                        unsigned* __restrict__ mkey, int N){
  int gid = blockIdx.x * 256 + threadIdx.x;
  float c = scal[128];
  float v = (gid < N) ? lrelu(tb[gid] + c) : -1e30f;
  __shared__ float lds[256];
  lds[threadIdx.x] = v;
  __syncthreads();
  for (int s = 128; s > 0; s >>= 1){
    if (threadIdx.x < s) lds[threadIdx.x] = fmaxf(lds[threadIdx.x], lds[threadIdx.x + s]);
    __syncthreads();
  }
  if (threadIdx.x == 0) atomicMax(mkey, fkey(lds[0]));
}

// ---------------- a2 weighted sums: S = sum w; h2acc = sum w*xs ----------------
__global__ void k_a2sum(const float* __restrict__ tb, const float* __restrict__ xs,
                        float* __restrict__ scal, int N){
  int lane = threadIdx.x & 63, w = threadIdx.x >> 6;
  int gw = blockIdx.x * 4 + w, nw = gridDim.x * 4;
  float c = scal[128];
  float M = funkey(__float_as_uint(scal[130]));
  float hloc = 0.f, sloc = 0.f;
  for (int n = gw; n < N; n += nw){
    float a2 = lrelu(tb[n] + c);
    float wt = __expf(a2 - M);
    sloc += wt;
    hloc += wt * xs[(size_t)n * 64 + lane];
  }
  __shared__ float lds[256];
  __shared__ float sred[4];
  lds[threadIdx.x] = hloc;
  if (lane == 0) sred[w] = sloc;
  __syncthreads();
  if (threadIdx.x < 64)
    atomicAdd(&scal[192 + threadIdx.x],
              lds[threadIdx.x] + lds[64 + threadIdx.x] + lds[128 + threadIdx.x] + lds[192 + threadIdx.x]);
  if (threadIdx.x == 0) atomicAdd(&scal[129], sred[0] + sred[1] + sred[2] + sred[3]);
}

// ---------------- final (1 wave): h2; GRU2; out@w2.T + b2 ----------------
__global__ void k_final(const float* __restrict__ scal, const float* __restrict__ bm,
                        const float* __restrict__ wih, const float* __restrict__ whh,
                        const float* __restrict__ bih, const float* __restrict__ bhh,
                        const float* __restrict__ w2, const float* __restrict__ b2,
                        float* __restrict__ dout){
  int lane = threadIdx.x;
  float S  = scal[129];
  float h2 = scal[192 + lane] / S + bm[lane];
  float xg = h2 > 0.f ? h2 : __expf(h2) - 1.f;
  float xo = scal[64 + lane];
  float gir = bih[lane], giz = bih[64 + lane], gin = bih[128 + lane];
  float ghr = bhh[lane], ghz = bhh[64 + lane], ghn = bhh[128 + lane];
  for (int k = 0; k < 64; k++){
    float a = bcast(xg, k), b = bcast(xo, k);
    gir += a * wih[lane * 64 + k]; giz += a * wih[(64 + lane) * 64 + k]; gin += a * wih[(128 + lane) * 64 + k];
    ghr += b * whh[lane * 64 + k]; ghz += b * whh[(64 + lane) * 64 + k]; ghn += b * whh[(128 + lane) * 64 + k];
  }
  float r  = 1.f / (1.f + __expf(-(gir + ghr)));
  float z  = 1.f / (1.f + __expf(-(giz + ghz)));
  float nn = tanhf(gin + r * ghn);
  float o2 = fmaxf((1.f - z) * nn + z * xo, 0.f);
  float res = 0.f;
  for (int k = 0; k < 64; k++) res += bcast(o2, k) * w2[lane * 64 + k];
  dout[lane] = res + b2[lane];
}

extern "C" void kernel_launch(void* const* d_in, const int* in_sizes, int n_in,
                              void* d_out, int out_size, void* d_ws, size_t ws_size,
                              hipStream_t stream){
  const float* na    = (const float*)d_in[0];
  const float* ea    = (const float*)d_in[1];
  const int*   ei    = (const int*)d_in[2];
  const float* w1    = (const float*)d_in[3];
  const float* b1    = (const float*)d_in[4];
  const float* wg1   = (const float*)d_in[5];
  const float* att_l = (const float*)d_in[6];
  const float* att_r = (const float*)d_in[7];
  const float* wg2   = (const float*)d_in[8];
  const float* bg    = (const float*)d_in[9];
  const float* g1wih = (const float*)d_in[10];
  const float* g1whh = (const float*)d_in[11];
  const float* g1bih = (const float*)d_in[12];
  const float* g1bhh = (const float*)d_in[13];
  const float* wm      = (const float*)d_in[14];
  const float* att_src = (const float*)d_in[15];
  const float* att_dst = (const float*)d_in[16];
  const float* bm      = (const float*)d_in[17];
  const float* g2wih = (const float*)d_in[18];
  const float* g2whh = (const float*)d_in[19];
  const float* g2bih = (const float*)d_in[20];
  const float* g2bhh = (const float*)d_in[21];
  const float* w2    = (const float*)d_in[22];
  const float* b2    = (const float*)d_in[23];

  int N = in_sizes[0];   // node_attr has IN_DIM=1
  int E = in_sizes[1];   // edge_attr has EDGE_DIM=1
  const int* srcArr = ei;
  const int* dstArr = ei + E;

  char* ws = (char*)d_ws;
  size_t cur = 0;
  auto alloc = [&](size_t nbytes) -> char* {
    char* p = ws + cur;
    cur += (nbytes + 255) & ~(size_t)255;
    return p;
  };
  float* y     = (float*)alloc((size_t)N * 64 * 4);
  float* bufC  = (float*)alloc((size_t)N * 64 * 4);   // sout -> x2 -> xs
  float* xr    = (float*)alloc((size_t)N * 4);
  float* tb    = (float*)alloc((size_t)N * 4);
  float* mb    = (float*)alloc((size_t)N * 4);
  float* db    = (float*)alloc((size_t)N * 4);
  int*   deg   = (int*)alloc((size_t)N * 4);
  int*   offA  = (int*)alloc((size_t)(N + 1) * 4);
  int*   fill  = (int*)alloc((size_t)N * 4);
  int*   part  = (int*)alloc(1024);
  int*   csr_s = (int*)alloc((size_t)E * 4);
  float* csr_e = (float*)alloc((size_t)E * 4);
  float* av    = (float*)alloc((size_t)E * 4);
  float* scal  = (float*)alloc(4096);
  float* wg1_t = (float*)alloc(64 * 64 * 4);
  float* wg2_t = (float*)alloc(64 * 64 * 4);
  float* wm_t  = (float*)alloc(64 * 64 * 4);
  float* wih_t = (float*)alloc(64 * 192 * 4);
  float* whh_t = (float*)alloc(64 * 192 * 4);
  if (cur > ws_size) return;  // workspace too small; fail loudly via wrong output

  hipMemsetAsync(deg,  0, (size_t)N * 4, stream);
  hipMemsetAsync(scal, 0, 4096, stream);

  k_wprep<<<64, 192, 0, stream>>>(wg1, wg2, g1wih, g1whh, wm, wg1_t, wg2_t, wih_t, whh_t, wm_t);

  int nwb = (N + 3) / 4;           // 4 waves/block, 1 node/wave
  k_node_prep<<<nwb, 256, 0, stream>>>(na, w1, b1, wg1_t, att_r, y, xr, N);
  k_deg<<<(E + 255) / 256, 256, 0, stream>>>(dstArr, deg, E);
  int nb = (N + 1023) / 1024;
  k_scan1<<<nb, 1024, 0, stream>>>(deg, part, N);
  k_scan2<<<1, 64, 0, stream>>>(part, nb, offA, N);
  k_scan3<<<nb, 1024, 0, stream>>>(deg, part, offA, fill, N);
  k_fill<<<(E + 255) / 256, 256, 0, stream>>>(dstArr, srcArr, ea, fill, csr_s, csr_e, E);
  k_edge_a<<<nwb, 256, 0, stream>>>(offA, csr_s, csr_e, y, xr, wg1, att_l, av, mb, db, N);
  k_edge_c<<<nwb, 256, 0, stream>>>(offA, csr_s, csr_e, y, av, mb, db, wg1, bufC, N);
  int ngb = (N + NPW * 4 - 1) / (NPW * 4);   // 4 waves/block, NPW nodes/wave
  k_gru1<<<ngb, 256, 0, stream>>>(bufC, na, w1, b1, wg2_t, bg, wih_t, whh_t, g1bih, g1bhh, bufC, N);
  k_part2a<<<512, 256, 0, stream>>>(bufC, wm_t, att_src, bufC, tb, scal, N);
  k_part2b<<<1, 64, 0, stream>>>(scal, wm, att_dst);
  k_a2max<<<(N + 255) / 256, 256, 0, stream>>>(tb, scal, (unsigned*)(scal + 130), N);
  k_a2sum<<<512, 256, 0, stream>>>(tb, bufC, scal, N);
  k_final<<<1, 64, 0, stream>>>(scal, bm, g2wih, g2whh, g2bih, g2bhh, w2, b2, (float*)d_out);
  (void)n_in; (void)out_size;
}

// Round 5
// 751.145 us; speedup vs baseline: 2.6127x; 1.2140x over previous
//
#include <hip/hip_runtime.h>
#include <math.h>

#define WF 64
#define NPW 8   // nodes per wave in GRU1

__device__ __forceinline__ float lrelu(float v){ return v > 0.f ? v : 0.01f * v; }

__device__ __forceinline__ float wave_sum(float v){
#pragma unroll
  for (int s = 32; s > 0; s >>= 1) v += __shfl_xor(v, s);
  return v;
}
__device__ __forceinline__ float wave_max(float v){
#pragma unroll
  for (int s = 32; s > 0; s >>= 1) v = fmaxf(v, __shfl_xor(v, s));
  return v;
}

// wave-uniform broadcast of lane k's value via v_readlane (VALU, no LDS pipe)
__device__ __forceinline__ float bcast(float v, int k){
  return __uint_as_float((unsigned)__builtin_amdgcn_readlane(__float_as_uint(v), k));
}

// float -> orderable unsigned key (monotone)
__device__ __forceinline__ unsigned fkey(float x){
  unsigned u = __float_as_uint(x);
  return (u & 0x80000000u) ? ~u : (u | 0x80000000u);
}
__device__ __forceinline__ float funkey(unsigned k){
  unsigned u = (k & 0x80000000u) ? (k & 0x7fffffffu) : ~k;
  return __uint_as_float(u);
}

// ---------------- weight transpose to k-major (coalesced inner loops) ----------------
__global__ void k_wprep(const float* __restrict__ wg1, const float* __restrict__ wg2,
                        const float* __restrict__ wih, const float* __restrict__ whh,
                        const float* __restrict__ wm,
                        float* __restrict__ wg1_t, float* __restrict__ wg2_t,
                        float* __restrict__ wih_t, float* __restrict__ whh_t,
                        float* __restrict__ wm_t, float* __restrict__ wgc){
  int k = blockIdx.x;      // 0..63
  int r = threadIdx.x;     // 0..191
  if (r < 64){
    wg1_t[k * 64 + r] = wg1[r * 65 + k];
    wg2_t[k * 64 + r] = wg2[r * 64 + k];
    wm_t [k * 64 + r] = wm [r * 64 + k];
    if (k == 0) wgc[r] = wg1[r * 65 + 64];   // last column of wg1
  }
  wih_t[k * 192 + r] = wih[r * 64 + k];
  whh_t[k * 192 + r] = whh[r * 64 + k];
}

// ---------------- node prep: x = lrelu(na*w1+b1); y = x@wg1[:, :64].T ; xr = dot(x, att_r)
__global__ void k_node_prep(const float* __restrict__ na, const float* __restrict__ w1,
                            const float* __restrict__ b1, const float* __restrict__ wg1_t,
                            const float* __restrict__ att_r,
                            float* __restrict__ y, float* __restrict__ xr, int N){
  int lane = threadIdx.x & 63;
  int wid  = (blockIdx.x * blockDim.x + threadIdx.x) >> 6;
  if (wid >= N) return;
  float xv = lrelu(na[wid] * w1[lane] + b1[lane]);
  float acc = 0.f;
#pragma unroll 8
  for (int k = 0; k < 64; k++)
    acc += bcast(xv, k) * wg1_t[k * 64 + lane];
  y[(size_t)wid * 64 + lane] = acc;
  float t = wave_sum(xv * att_r[lane]);
  if (lane == 0) xr[wid] = t;
}

// ---------------- CSR build ----------------
__global__ void k_deg(const int* __restrict__ dst, int* __restrict__ deg, int E){
  int e = blockIdx.x * 256 + threadIdx.x;
  if (e >= E) return;
  atomicAdd(&deg[dst[e]], 1);
}

__global__ void k_scan1(const int* __restrict__ deg, int* __restrict__ partial, int N){
  __shared__ int lds[1024];
  int gid = blockIdx.x * 1024 + threadIdx.x;
  lds[threadIdx.x] = (gid < N) ? deg[gid] : 0;
  __syncthreads();
  for (int s = 512; s > 0; s >>= 1){
    if (threadIdx.x < s) lds[threadIdx.x] += lds[threadIdx.x + s];
    __syncthreads();
  }
  if (threadIdx.x == 0) partial[blockIdx.x] = lds[0];
}

__global__ void k_scan2(int* __restrict__ partial, int nb, int* __restrict__ off, int N){
  if (threadIdx.x == 0){
    int run = 0;
    for (int b = 0; b < nb; b++){ int t = partial[b]; partial[b] = run; run += t; }
    off[N] = run;
  }
}

__global__ void k_scan3(const int* __restrict__ deg, const int* __restrict__ partial,
                        int* __restrict__ off, int* __restrict__ fill, int N){
  __shared__ int lds[1024];
  int gid = blockIdx.x * 1024 + threadIdx.x;
  int v = (gid < N) ? deg[gid] : 0;
  lds[threadIdx.x] = v;
  __syncthreads();
  for (int s = 1; s < 1024; s <<= 1){
    int t = (threadIdx.x >= s) ? lds[threadIdx.x - s] : 0;
    __syncthreads();
    lds[threadIdx.x] += t;
    __syncthreads();
  }
  if (gid < N){
    int excl = partial[blockIdx.x] + lds[threadIdx.x] - v;
    off[gid] = excl;
    fill[gid] = excl;
  }
}

__global__ void k_fill(const int* __restrict__ dst, const int* __restrict__ src,
                       const float* __restrict__ ea, int* __restrict__ fill,
                       int* __restrict__ csr_src, float* __restrict__ csr_ea,
                       int* __restrict__ csr_dst, int E){
  int e = blockIdx.x * 256 + threadIdx.x;
  if (e >= E) return;
  int d = dst[e];
  int pos = atomicAdd(&fill[d], 1);
  csr_src[pos] = src[e];
  csr_ea[pos]  = ea[e];
  csr_dst[pos] = d;
}

// ---------------- edge pass D (edge-parallel, no cross-lane):
// av[i] = lrelu( sum_j lrelu(y[sn][j] + ea*wc[j]) * att_l[j] + xr[dst] )
__global__ void k_edge_d(const int* __restrict__ csr_src, const float* __restrict__ csr_ea,
                         const int* __restrict__ csr_dst, const float* __restrict__ y,
                         const float* __restrict__ xr, const float* __restrict__ wgc,
                         const float* __restrict__ att_l,
                         float* __restrict__ av, int E){
  int i = blockIdx.x * 256 + threadIdx.x;
  if (i >= E) return;
  int   sn = csr_src[i];
  float ea = csr_ea[i];
  const float4* yr = (const float4*)(y + (size_t)sn * 64);
  const float4* wc4 = (const float4*)wgc;
  const float4* al4 = (const float4*)att_l;
  float d = 0.f;
#pragma unroll
  for (int q = 0; q < 16; q++){
    float4 yv = yr[q];
    float4 wc = wc4[q];
    float4 al = al4[q];
    d += lrelu(yv.x + ea * wc.x) * al.x + lrelu(yv.y + ea * wc.y) * al.y
       + lrelu(yv.z + ea * wc.z) * al.z + lrelu(yv.w + ea * wc.w) * al.w;
  }
  av[i] = lrelu(d + xr[csr_dst[i]]);
}

// ---------------- edge pass C2: in-wave softmax stats + sout[n] = sum alpha * h_e ----------------
__global__ void k_edge_c2(const int* __restrict__ off, const int* __restrict__ csr_src,
                          const float* __restrict__ csr_ea, const float* __restrict__ y,
                          const float* __restrict__ av, const float* __restrict__ wgc,
                          float* __restrict__ sout, int N){
  int lane = threadIdx.x & 63;
  int wid  = (blockIdx.x * blockDim.x + threadIdx.x) >> 6;
  if (wid >= N) return;
  int i0 = off[wid], i1 = off[wid + 1];
  // wave-parallel max over av[i0..i1)
  float m = -1e30f;
  for (int i = i0 + lane; i < i1; i += 64) m = fmaxf(m, av[i]);
  m = wave_max(m);
  // wave-parallel sum of exp(av - m)
  float s = 0.f;
  for (int i = i0 + lane; i < i1; i += 64) s += __expf(av[i] - m);
  s = wave_sum(s);
  float inv = (i1 > i0 && s > 0.f) ? 1.f / s : 0.f;
  float wc = wgc[lane];
  float acc = 0.f;
  for (int i = i0; i < i1; i++){
    int   sn = csr_src[i];
    float ea = csr_ea[i];
    float he = lrelu(y[(size_t)sn * 64 + lane] + ea * wc);
    acc += __expf(av[i] - m) * inv * he;
  }
  sout[(size_t)wid * 64 + lane] = acc;
}

// ---------------- GRU1 (NPW nodes per wave) ----------------
__global__ void k_gru1(const float* __restrict__ sout, const float* __restrict__ na,
                       const float* __restrict__ w1, const float* __restrict__ b1,
                       const float* __restrict__ wg2_t, const float* __restrict__ bg,
                       const float* __restrict__ wih_t, const float* __restrict__ whh_t,
                       const float* __restrict__ bih, const float* __restrict__ bhh,
                       float* __restrict__ x2, int N){
  int lane = threadIdx.x & 63;
  int wid  = (blockIdx.x * blockDim.x + threadIdx.x) >> 6;
  int base = wid * NPW;
  if (base >= N) return;
  float sv[NPW], xo[NPW];
#pragma unroll
  for (int p = 0; p < NPW; p++){
    int n = base + p;
    if (n < N){ sv[p] = sout[(size_t)n * 64 + lane]; xo[p] = lrelu(na[n] * w1[lane] + b1[lane]); }
    else { sv[p] = 0.f; xo[p] = 0.f; }
  }
  float bgl = bg[lane];
  float h[NPW];
#pragma unroll
  for (int p = 0; p < NPW; p++) h[p] = bgl;
#pragma unroll 4
  for (int k = 0; k < 64; k++){
    float wv = wg2_t[k * 64 + lane];
#pragma unroll
    for (int p = 0; p < NPW; p++) h[p] += bcast(sv[p], k) * wv;
  }
  float xg[NPW];
#pragma unroll
  for (int p = 0; p < NPW; p++){ float v = h[p]; xg[p] = v > 0.f ? v : __expf(v) - 1.f; }
  float gir[NPW], giz[NPW], gin[NPW], ghr[NPW], ghz[NPW], ghn[NPW];
#pragma unroll
  for (int p = 0; p < NPW; p++){
    gir[p] = bih[lane]; giz[p] = bih[64 + lane]; gin[p] = bih[128 + lane];
    ghr[p] = bhh[lane]; ghz[p] = bhh[64 + lane]; ghn[p] = bhh[128 + lane];
  }
#pragma unroll 2
  for (int k = 0; k < 64; k++){
    const float* wi = wih_t + k * 192;
    const float* wh = whh_t + k * 192;
    float wir = wi[lane], wiz = wi[64 + lane], win = wi[128 + lane];
    float whr = wh[lane], whz = wh[64 + lane], whn = wh[128 + lane];
#pragma unroll
    for (int p = 0; p < NPW; p++){
      float a = bcast(xg[p], k), b = bcast(xo[p], k);
      gir[p] += a * wir; giz[p] += a * wiz; gin[p] += a * win;
      ghr[p] += b * whr; ghz[p] += b * whz; ghn[p] += b * whn;
    }
  }
#pragma unroll
  for (int p = 0; p < NPW; p++){
    int n = base + p;
    if (n >= N) break;
    float r  = 1.f / (1.f + __expf(-(gir[p] + ghr[p])));
    float z  = 1.f / (1.f + __expf(-(giz[p] + ghz[p])));
    float nn = tanhf(gin[p] + r * ghn[p]);
    float xn = (1.f - z) * nn + z * xo[p];
    x2[(size_t)n * 64 + lane] = fmaxf(xn, 0.f);
  }
}

// ---------------- part2a ----------------
__global__ void k_part2a(const float* __restrict__ x2, const float* __restrict__ wm_t,
                         const float* __restrict__ att_src,
                         float* __restrict__ xs, float* __restrict__ tb,
                         float* __restrict__ scal, int N){
  int lane = threadIdx.x & 63, w = threadIdx.x >> 6;
  int gw = blockIdx.x * 4 + w, nw = gridDim.x * 4;
  float as = att_src[lane];
  float os = 0.f;
  for (int n = gw; n < N; n += nw){
    float xv = x2[(size_t)n * 64 + lane];
    os += xv;
    float acc = 0.f;
#pragma unroll 8
    for (int k = 0; k < 64; k++) acc += bcast(xv, k) * wm_t[k * 64 + lane];
    xs[(size_t)n * 64 + lane] = acc;
    float t = wave_sum(acc * as);
    if (lane == 0) tb[n] = t;
  }
  __shared__ float lds[256];
  lds[threadIdx.x] = os;
  __syncthreads();
  if (threadIdx.x < 64)
    atomicAdd(&scal[threadIdx.x],
              lds[threadIdx.x] + lds[64 + threadIdx.x] + lds[128 + threadIdx.x] + lds[192 + threadIdx.x]);
}

// ---------------- part2b (1 wave) ----------------
__global__ void k_part2b(float* __restrict__ scal, const float* __restrict__ wm,
                         const float* __restrict__ att_dst){
  int lane = threadIdx.x;
  float o = fmaxf(scal[lane], 0.f);
  float acc = 0.f;
  for (int k = 0; k < 64; k++) acc += bcast(o, k) * wm[lane * 64 + k];
  float c = wave_sum(acc * att_dst[lane]);
  scal[64 + lane] = o;
  if (lane == 0) scal[128] = c;
}

// ---------------- a2 max reduction ----------------
__global__ void k_a2max(const float* __restrict__ tb, const float* __restrict__ scal,
                        unsigned* __restrict__ mkey, int N){
  int gid = blockIdx.x * 256 + threadIdx.x;
  float c = scal[128];
  float v = (gid < N) ? lrelu(tb[gid] + c) : -1e30f;
  __shared__ float lds[256];
  lds[threadIdx.x] = v;
  __syncthreads();
  for (int s = 128; s > 0; s >>= 1){
    if (threadIdx.x < s) lds[threadIdx.x] = fmaxf(lds[threadIdx.x], lds[threadIdx.x + s]);
    __syncthreads();
  }
  if (threadIdx.x == 0) atomicMax(mkey, fkey(lds[0]));
}

// ---------------- a2 weighted sums ----------------
__global__ void k_a2sum(const float* __restrict__ tb, const float* __restrict__ xs,
                        float* __restrict__ scal, int N){
  int lane = threadIdx.x & 63, w = threadIdx.x >> 6;
  int gw = blockIdx.x * 4 + w, nw = gridDim.x * 4;
  float c = scal[128];
  float M = funkey(__float_as_uint(scal[130]));
  float hloc = 0.f, sloc = 0.f;
  for (int n = gw; n < N; n += nw){
    float a2 = lrelu(tb[n] + c);
    float wt = __expf(a2 - M);
    sloc += wt;
    hloc += wt * xs[(size_t)n * 64 + lane];
  }
  __shared__ float lds[256];
  __shared__ float sred[4];
  lds[threadIdx.x] = hloc;
  if (lane == 0) sred[w] = sloc;
  __syncthreads();
  if (threadIdx.x < 64)
    atomicAdd(&scal[192 + threadIdx.x],
              lds[threadIdx.x] + lds[64 + threadIdx.x] + lds[128 + threadIdx.x] + lds[192 + threadIdx.x]);
  if (threadIdx.x == 0) atomicAdd(&scal[129], sred[0] + sred[1] + sred[2] + sred[3]);
}

// ---------------- final (1 wave) ----------------
__global__ void k_final(const float* __restrict__ scal, const float* __restrict__ bm,
                        const float* __restrict__ wih, const float* __restrict__ whh,
                        const float* __restrict__ bih, const float* __restrict__ bhh,
                        const float* __restrict__ w2, const float* __restrict__ b2,
                        float* __restrict__ dout){
  int lane = threadIdx.x;
  float S  = scal[129];
  float h2 = scal[192 + lane] / S + bm[lane];
  float xg = h2 > 0.f ? h2 : __expf(h2) - 1.f;
  float xo = scal[64 + lane];
  float gir = bih[lane], giz = bih[64 + lane], gin = bih[128 + lane];
  float ghr = bhh[lane], ghz = bhh[64 + lane], ghn = bhh[128 + lane];
  for (int k = 0; k < 64; k++){
    float a = bcast(xg, k), b = bcast(xo, k);
    gir += a * wih[lane * 64 + k]; giz += a * wih[(64 + lane) * 64 + k]; gin += a * wih[(128 + lane) * 64 + k];
    ghr += b * whh[lane * 64 + k]; ghz += b * whh[(64 + lane) * 64 + k]; ghn += b * whh[(128 + lane) * 64 + k];
  }
  float r  = 1.f / (1.f + __expf(-(gir + ghr)));
  float z  = 1.f / (1.f + __expf(-(giz + ghz)));
  float nn = tanhf(gin + r * ghn);
  float o2 = fmaxf((1.f - z) * nn + z * xo, 0.f);
  float res = 0.f;
  for (int k = 0; k < 64; k++) res += bcast(o2, k) * w2[lane * 64 + k];
  dout[lane] = res + b2[lane];
}

extern "C" void kernel_launch(void* const* d_in, const int* in_sizes, int n_in,
                              void* d_out, int out_size, void* d_ws, size_t ws_size,
                              hipStream_t stream){
  const float* na    = (const float*)d_in[0];
  const float* ea    = (const float*)d_in[1];
  const int*   ei    = (const int*)d_in[2];
  const float* w1    = (const float*)d_in[3];
  const float* b1    = (const float*)d_in[4];
  const float* wg1   = (const float*)d_in[5];
  const float* att_l = (const float*)d_in[6];
  const float* att_r = (const float*)d_in[7];
  const float* wg2   = (const float*)d_in[8];
  const float* bg    = (const float*)d_in[9];
  const float* g1wih = (const float*)d_in[10];
  const float* g1whh = (const float*)d_in[11];
  const float* g1bih = (const float*)d_in[12];
  const float* g1bhh = (const float*)d_in[13];
  const float* wm      = (const float*)d_in[14];
  const float* att_src = (const float*)d_in[15];
  const float* att_dst = (const float*)d_in[16];
  const float* bm      = (const float*)d_in[17];
  const float* g2wih = (const float*)d_in[18];
  const float* g2whh = (const float*)d_in[19];
  const float* g2bih = (const float*)d_in[20];
  const float* g2bhh = (const float*)d_in[21];
  const float* w2    = (const float*)d_in[22];
  const float* b2    = (const float*)d_in[23];

  int N = in_sizes[0];
  int E = in_sizes[1];
  const int* srcArr = ei;
  const int* dstArr = ei + E;

  char* ws = (char*)d_ws;
  size_t cur = 0;
  auto alloc = [&](size_t nbytes) -> char* {
    char* p = ws + cur;
    cur += (nbytes + 255) & ~(size_t)255;
    return p;
  };
  float* y     = (float*)alloc((size_t)N * 64 * 4);
  float* bufC  = (float*)alloc((size_t)N * 64 * 4);   // sout -> x2 -> xs
  float* xr    = (float*)alloc((size_t)N * 4);
  float* tb    = (float*)alloc((size_t)N * 4);
  int*   deg   = (int*)alloc((size_t)N * 4);
  int*   offA  = (int*)alloc((size_t)(N + 1) * 4);
  int*   fill  = (int*)alloc((size_t)N * 4);
  int*   part  = (int*)alloc(1024);
  int*   csr_s = (int*)alloc((size_t)E * 4);
  float* csr_e = (float*)alloc((size_t)E * 4);
  int*   csr_d = (int*)alloc((size_t)E * 4);
  float* av    = (float*)alloc((size_t)E * 4);
  float* scal  = (float*)alloc(4096);
  float* wg1_t = (float*)alloc(64 * 64 * 4);
  float* wg2_t = (float*)alloc(64 * 64 * 4);
  float* wm_t  = (float*)alloc(64 * 64 * 4);
  float* wih_t = (float*)alloc(64 * 192 * 4);
  float* whh_t = (float*)alloc(64 * 192 * 4);
  float* wgc   = (float*)alloc(64 * 4);
  if (cur > ws_size) return;

  hipMemsetAsync(deg,  0, (size_t)N * 4, stream);
  hipMemsetAsync(scal, 0, 4096, stream);

  k_wprep<<<64, 192, 0, stream>>>(wg1, wg2, g1wih, g1whh, wm, wg1_t, wg2_t, wih_t, whh_t, wm_t, wgc);

  int nwb = (N + 3) / 4;           // 4 waves/block, 1 node/wave
  k_node_prep<<<nwb, 256, 0, stream>>>(na, w1, b1, wg1_t, att_r, y, xr, N);
  k_deg<<<(E + 255) / 256, 256, 0, stream>>>(dstArr, deg, E);
  int nb = (N + 1023) / 1024;
  k_scan1<<<nb, 1024, 0, stream>>>(deg, part, N);
  k_scan2<<<1, 64, 0, stream>>>(part, nb, offA, N);
  k_scan3<<<nb, 1024, 0, stream>>>(deg, part, offA, fill, N);
  k_fill<<<(E + 255) / 256, 256, 0, stream>>>(dstArr, srcArr, ea, fill, csr_s, csr_e, csr_d, E);
  k_edge_d<<<(E + 255) / 256, 256, 0, stream>>>(csr_s, csr_e, csr_d, y, xr, wgc, att_l, av, E);
  k_edge_c2<<<nwb, 256, 0, stream>>>(offA, csr_s, csr_e, y, av, wgc, bufC, N);
  int ngb = (N + NPW * 4 - 1) / (NPW * 4);   // 4 waves/block, NPW nodes/wave
  k_gru1<<<ngb, 256, 0, stream>>>(bufC, na, w1, b1, wg2_t, bg, wih_t, whh_t, g1bih, g1bhh, bufC, N);
  k_part2a<<<512, 256, 0, stream>>>(bufC, wm_t, att_src, bufC, tb, scal, N);
  k_part2b<<<1, 64, 0, stream>>>(scal, wm, att_dst);
  k_a2max<<<(N + 255) / 256, 256, 0, stream>>>(tb, scal, (unsigned*)(scal + 130), N);
  k_a2sum<<<512, 256, 0, stream>>>(tb, bufC, scal, N);
  k_final<<<1, 64, 0, stream>>>(scal, bm, g2wih, g2whh, g2bih, g2bhh, w2, b2, (float*)d_out);
  (void)n_in; (void)out_size;
}

// Round 6
// 712.924 us; speedup vs baseline: 2.7528x; 1.0536x over previous
//
#include <hip/hip_runtime.h>
#include <math.h>

#define WF 64
#define NPW 8   // nodes per wave in GRU1

__device__ __forceinline__ float lrelu(float v){ return v > 0.f ? v : 0.01f * v; }

__device__ __forceinline__ float wave_sum(float v){
#pragma unroll
  for (int s = 32; s > 0; s >>= 1) v += __shfl_xor(v, s);
  return v;
}
__device__ __forceinline__ float wave_max(float v){
#pragma unroll
  for (int s = 32; s > 0; s >>= 1) v = fmaxf(v, __shfl_xor(v, s));
  return v;
}

// wave-uniform broadcast of lane k's value via v_readlane (VALU, no LDS pipe)
__device__ __forceinline__ float bcast(float v, int k){
  return __uint_as_float((unsigned)__builtin_amdgcn_readlane(__float_as_uint(v), k));
}

// float -> orderable unsigned key (monotone)
__device__ __forceinline__ unsigned fkey(float x){
  unsigned u = __float_as_uint(x);
  return (u & 0x80000000u) ? ~u : (u | 0x80000000u);
}
__device__ __forceinline__ float funkey(unsigned k){
  unsigned u = (k & 0x80000000u) ? (k & 0x7fffffffu) : ~k;
  return __uint_as_float(u);
}

// ---------------- weight transpose to k-major (coalesced inner loops) ----------------
__global__ void k_wprep(const float* __restrict__ wg1, const float* __restrict__ wg2,
                        const float* __restrict__ wih, const float* __restrict__ whh,
                        const float* __restrict__ wm,
                        float* __restrict__ wg1_t, float* __restrict__ wg2_t,
                        float* __restrict__ wih_t, float* __restrict__ whh_t,
                        float* __restrict__ wm_t, float* __restrict__ wgc){
  int k = blockIdx.x;      // 0..63
  int r = threadIdx.x;     // 0..191
  if (r < 64){
    wg1_t[k * 64 + r] = wg1[r * 65 + k];
    wg2_t[k * 64 + r] = wg2[r * 64 + k];
    wm_t [k * 64 + r] = wm [r * 64 + k];
    if (k == 0) wgc[r] = wg1[r * 65 + 64];   // last column of wg1
  }
  wih_t[k * 192 + r] = wih[r * 64 + k];
  whh_t[k * 192 + r] = whh[r * 64 + k];
}

// ---------------- node prep: x = lrelu(na*w1+b1); y = x@wg1[:, :64].T ; xr = dot(x, att_r)
__global__ void k_node_prep(const float* __restrict__ na, const float* __restrict__ w1,
                            const float* __restrict__ b1, const float* __restrict__ wg1_t,
                            const float* __restrict__ att_r,
                            float* __restrict__ y, float* __restrict__ xr, int N){
  int lane = threadIdx.x & 63;
  int wid  = (blockIdx.x * blockDim.x + threadIdx.x) >> 6;
  if (wid >= N) return;
  float xv = lrelu(na[wid] * w1[lane] + b1[lane]);
  float acc = 0.f;
#pragma unroll 8
  for (int k = 0; k < 64; k++)
    acc += bcast(xv, k) * wg1_t[k * 64 + lane];
  y[(size_t)wid * 64 + lane] = acc;
  float t = wave_sum(xv * att_r[lane]);
  if (lane == 0) xr[wid] = t;
}

// ---------------- CSR build ----------------
__global__ void k_deg(const int* __restrict__ dst, int* __restrict__ deg, int E){
  int e = blockIdx.x * 256 + threadIdx.x;
  if (e >= E) return;
  atomicAdd(&deg[dst[e]], 1);
}

__global__ void k_scan1(const int* __restrict__ deg, int* __restrict__ partial, int N){
  __shared__ int lds[1024];
  int gid = blockIdx.x * 1024 + threadIdx.x;
  lds[threadIdx.x] = (gid < N) ? deg[gid] : 0;
  __syncthreads();
  for (int s = 512; s > 0; s >>= 1){
    if (threadIdx.x < s) lds[threadIdx.x] += lds[threadIdx.x + s];
    __syncthreads();
  }
  if (threadIdx.x == 0) partial[blockIdx.x] = lds[0];
}

__global__ void k_scan2(int* __restrict__ partial, int nb, int* __restrict__ off, int N){
  if (threadIdx.x == 0){
    int run = 0;
    for (int b = 0; b < nb; b++){ int t = partial[b]; partial[b] = run; run += t; }
    off[N] = run;
  }
}

__global__ void k_scan3(const int* __restrict__ deg, const int* __restrict__ partial,
                        int* __restrict__ off, int* __restrict__ fill, int N){
  __shared__ int lds[1024];
  int gid = blockIdx.x * 1024 + threadIdx.x;
  int v = (gid < N) ? deg[gid] : 0;
  lds[threadIdx.x] = v;
  __syncthreads();
  for (int s = 1; s < 1024; s <<= 1){
    int t = (threadIdx.x >= s) ? lds[threadIdx.x - s] : 0;
    __syncthreads();
    lds[threadIdx.x] += t;
    __syncthreads();
  }
  if (gid < N){
    int excl = partial[blockIdx.x] + lds[threadIdx.x] - v;
    off[gid] = excl;
    fill[gid] = excl;
  }
}

__global__ void k_fill(const int* __restrict__ dst, const int* __restrict__ src,
                       const float* __restrict__ ea, int* __restrict__ fill,
                       int2* __restrict__ csr_sd, float* __restrict__ csr_ea, int E){
  int e = blockIdx.x * 256 + threadIdx.x;
  if (e >= E) return;
  int d = dst[e];
  int pos = atomicAdd(&fill[d], 1);
  csr_sd[pos] = make_int2(src[e], d);
  csr_ea[pos] = ea[e];
}

// ---------------- edge pass D (edge-parallel, no cross-lane):
// av[i] = lrelu( sum_j lrelu(y[sn][j] + ea*wc[j]) * att_l[j] + xr[dst] )
__global__ void k_edge_d(const int2* __restrict__ csr_sd, const float* __restrict__ csr_ea,
                         const float* __restrict__ y,
                         const float* __restrict__ xr, const float* __restrict__ wgc,
                         const float* __restrict__ att_l,
                         float* __restrict__ av, int E){
  int i = blockIdx.x * 256 + threadIdx.x;
  if (i >= E) return;
  int2  sd = csr_sd[i];
  float ea = csr_ea[i];
  const float4* yr = (const float4*)(y + (size_t)sd.x * 64);
  const float4* wc4 = (const float4*)wgc;
  const float4* al4 = (const float4*)att_l;
  float d = 0.f;
#pragma unroll
  for (int q = 0; q < 16; q++){
    float4 yv = yr[q];
    float4 wc = wc4[q];
    float4 al = al4[q];
    d += lrelu(yv.x + ea * wc.x) * al.x + lrelu(yv.y + ea * wc.y) * al.y
       + lrelu(yv.z + ea * wc.z) * al.z + lrelu(yv.w + ea * wc.w) * al.w;
  }
  av[i] = lrelu(d + xr[sd.y]);
}

// ---------------- edge pass C2: in-wave softmax stats + sout[n] = sum alpha * h_e
// 4 edge-groups of 16 lanes; each lane holds 4 dims (float4); 4 gathers in flight
__global__ void k_edge_c2(const int* __restrict__ off, const int2* __restrict__ csr_sd,
                          const float* __restrict__ csr_e, const float* __restrict__ y,
                          const float* __restrict__ av, const float* __restrict__ wgc,
                          float* __restrict__ sout, int N){
  int lane = threadIdx.x & 63;
  int wid  = (blockIdx.x * blockDim.x + threadIdx.x) >> 6;
  if (wid >= N) return;
  int i0 = off[wid], i1 = off[wid + 1];
  // wave-parallel max over av[i0..i1)
  float m = -1e30f;
  for (int i = i0 + lane; i < i1; i += 64) m = fmaxf(m, av[i]);
  m = wave_max(m);
  // wave-parallel sum of exp(av - m)
  float s = 0.f;
  for (int i = i0 + lane; i < i1; i += 64) s += __expf(av[i] - m);
  s = wave_sum(s);
  float inv = (i1 > i0 && s > 0.f) ? 1.f / s : 0.f;
  int sub = lane >> 4, sl = lane & 15;
  float4 wc4 = ((const float4*)wgc)[sl];
  float4 acc = make_float4(0.f, 0.f, 0.f, 0.f);
  for (int i = i0 + sub; i < i1; i += 4){
    int   sn = csr_sd[i].x;
    float ea = csr_e[i];
    float w  = __expf(av[i] - m) * inv;
    float4 yv = ((const float4*)(y + (size_t)sn * 64))[sl];
    acc.x += w * lrelu(yv.x + ea * wc4.x);
    acc.y += w * lrelu(yv.y + ea * wc4.y);
    acc.z += w * lrelu(yv.z + ea * wc4.z);
    acc.w += w * lrelu(yv.w + ea * wc4.w);
  }
  // combine the 4 sub-groups (xor 16, then 32)
  acc.x += __shfl_xor(acc.x, 16); acc.y += __shfl_xor(acc.y, 16);
  acc.z += __shfl_xor(acc.z, 16); acc.w += __shfl_xor(acc.w, 16);
  acc.x += __shfl_xor(acc.x, 32); acc.y += __shfl_xor(acc.y, 32);
  acc.z += __shfl_xor(acc.z, 32); acc.w += __shfl_xor(acc.w, 32);
  if (sub == 0) ((float4*)(sout + (size_t)wid * 64))[sl] = acc;
}

// ---------------- GRU1 (NPW nodes per wave) ----------------
__global__ void k_gru1(const float* __restrict__ sout, const float* __restrict__ na,
                       const float* __restrict__ w1, const float* __restrict__ b1,
                       const float* __restrict__ wg2_t, const float* __restrict__ bg,
                       const float* __restrict__ wih_t, const float* __restrict__ whh_t,
                       const float* __restrict__ bih, const float* __restrict__ bhh,
                       float* __restrict__ x2, int N){
  int lane = threadIdx.x & 63;
  int wid  = (blockIdx.x * blockDim.x + threadIdx.x) >> 6;
  int base = wid * NPW;
  if (base >= N) return;
  float sv[NPW], xo[NPW];
#pragma unroll
  for (int p = 0; p < NPW; p++){
    int n = base + p;
    if (n < N){ sv[p] = sout[(size_t)n * 64 + lane]; xo[p] = lrelu(na[n] * w1[lane] + b1[lane]); }
    else { sv[p] = 0.f; xo[p] = 0.f; }
  }
  float bgl = bg[lane];
  float h[NPW];
#pragma unroll
  for (int p = 0; p < NPW; p++) h[p] = bgl;
#pragma unroll 4
  for (int k = 0; k < 64; k++){
    float wv = wg2_t[k * 64 + lane];
#pragma unroll
    for (int p = 0; p < NPW; p++) h[p] += bcast(sv[p], k) * wv;
  }
  float xg[NPW];
#pragma unroll
  for (int p = 0; p < NPW; p++){ float v = h[p]; xg[p] = v > 0.f ? v : __expf(v) - 1.f; }
  float gir[NPW], giz[NPW], gin[NPW], ghr[NPW], ghz[NPW], ghn[NPW];
#pragma unroll
  for (int p = 0; p < NPW; p++){
    gir[p] = bih[lane]; giz[p] = bih[64 + lane]; gin[p] = bih[128 + lane];
    ghr[p] = bhh[lane]; ghz[p] = bhh[64 + lane]; ghn[p] = bhh[128 + lane];
  }
#pragma unroll 2
  for (int k = 0; k < 64; k++){
    const float* wi = wih_t + k * 192;
    const float* wh = whh_t + k * 192;
    float wir = wi[lane], wiz = wi[64 + lane], win = wi[128 + lane];
    float whr = wh[lane], whz = wh[64 + lane], whn = wh[128 + lane];
#pragma unroll
    for (int p = 0; p < NPW; p++){
      float a = bcast(xg[p], k), b = bcast(xo[p], k);
      gir[p] += a * wir; giz[p] += a * wiz; gin[p] += a * win;
      ghr[p] += b * whr; ghz[p] += b * whz; ghn[p] += b * whn;
    }
  }
#pragma unroll
  for (int p = 0; p < NPW; p++){
    int n = base + p;
    if (n >= N) break;
    float r  = 1.f / (1.f + __expf(-(gir[p] + ghr[p])));
    float z  = 1.f / (1.f + __expf(-(giz[p] + ghz[p])));
    float nn = tanhf(gin[p] + r * ghn[p]);
    float xn = (1.f - z) * nn + z * xo[p];
    x2[(size_t)n * 64 + lane] = fmaxf(xn, 0.f);
  }
}

// ---------------- part2a: osum += x2; xs = x2@wm.T; tb = dot(xs,att_src); track max(tb) ----------------
__global__ void k_part2a(const float* __restrict__ x2, const float* __restrict__ wm_t,
                         const float* __restrict__ att_src,
                         float* __restrict__ xs, float* __restrict__ tb,
                         float* __restrict__ scal, int N){
  int lane = threadIdx.x & 63, w = threadIdx.x >> 6;
  int gw = blockIdx.x * 4 + w, nw = gridDim.x * 4;
  float as = att_src[lane];
  float os = 0.f;
  float tmax = -1e30f;
  for (int n = gw; n < N; n += nw){
    float xv = x2[(size_t)n * 64 + lane];
    os += xv;
    float acc = 0.f;
#pragma unroll 8
    for (int k = 0; k < 64; k++) acc += bcast(xv, k) * wm_t[k * 64 + lane];
    xs[(size_t)n * 64 + lane] = acc;
    float t = wave_sum(acc * as);
    tmax = fmaxf(tmax, t);
    if (lane == 0) tb[n] = t;
  }
  if (lane == 0) atomicMax((unsigned*)(scal + 131), fkey(tmax));
  __shared__ float lds[256];
  lds[threadIdx.x] = os;
  __syncthreads();
  if (threadIdx.x < 64)
    atomicAdd(&scal[threadIdx.x],
              lds[threadIdx.x] + lds[64 + threadIdx.x] + lds[128 + threadIdx.x] + lds[192 + threadIdx.x]);
}

// ---------------- part2b (1 wave): out=relu(osum); xd=out@wm.T; c=dot(xd,att_dst); M=lrelu(maxtb+c)
__global__ void k_part2b(float* __restrict__ scal, const float* __restrict__ wm,
                         const float* __restrict__ att_dst){
  int lane = threadIdx.x;
  float o = fmaxf(scal[lane], 0.f);
  float acc = 0.f;
  for (int k = 0; k < 64; k++) acc += bcast(o, k) * wm[lane * 64 + k];
  float c = wave_sum(acc * att_dst[lane]);
  scal[64 + lane] = o;
  if (lane == 0){
    scal[128] = c;
    float maxtb = funkey(*(unsigned*)(scal + 131));
    scal[130] = lrelu(maxtb + c);   // M = max_n lrelu(tb[n]+c)  (lrelu monotone)
  }
}

// ---------------- a2 weighted sums: S = sum w; h2acc = sum w*xs ----------------
__global__ void k_a2sum(const float* __restrict__ tb, const float* __restrict__ xs,
                        float* __restrict__ scal, int N){
  int lane = threadIdx.x & 63, w = threadIdx.x >> 6;
  int gw = blockIdx.x * 4 + w, nw = gridDim.x * 4;
  float c = scal[128];
  float M = scal[130];
  float hloc = 0.f, sloc = 0.f;
  for (int n = gw; n < N; n += nw){
    float a2 = lrelu(tb[n] + c);
    float wt = __expf(a2 - M);
    sloc += wt;
    hloc += wt * xs[(size_t)n * 64 + lane];
  }
  __shared__ float lds[256];
  __shared__ float sred[4];
  lds[threadIdx.x] = hloc;
  if (lane == 0) sred[w] = sloc;
  __syncthreads();
  if (threadIdx.x < 64)
    atomicAdd(&scal[192 + threadIdx.x],
              lds[threadIdx.x] + lds[64 + threadIdx.x] + lds[128 + threadIdx.x] + lds[192 + threadIdx.x]);
  if (threadIdx.x == 0) atomicAdd(&scal[129], sred[0] + sred[1] + sred[2] + sred[3]);
}

// ---------------- final (1 wave) ----------------
__global__ void k_final(const float* __restrict__ scal, const float* __restrict__ bm,
                        const float* __restrict__ wih, const float* __restrict__ whh,
                        const float* __restrict__ bih, const float* __restrict__ bhh,
                        const float* __restrict__ w2, const float* __restrict__ b2,
                        float* __restrict__ dout){
  int lane = threadIdx.x;
  float S  = scal[129];
  float h2 = scal[192 + lane] / S + bm[lane];
  float xg = h2 > 0.f ? h2 : __expf(h2) - 1.f;
  float xo = scal[64 + lane];
  float gir = bih[lane], giz = bih[64 + lane], gin = bih[128 + lane];
  float ghr = bhh[lane], ghz = bhh[64 + lane], ghn = bhh[128 + lane];
  for (int k = 0; k < 64; k++){
    float a = bcast(xg, k), b = bcast(xo, k);
    gir += a * wih[lane * 64 + k]; giz += a * wih[(64 + lane) * 64 + k]; gin += a * wih[(128 + lane) * 64 + k];
    ghr += b * whh[lane * 64 + k]; ghz += b * whh[(64 + lane) * 64 + k]; ghn += b * whh[(128 + lane) * 64 + k];
  }
  float r  = 1.f / (1.f + __expf(-(gir + ghr)));
  float z  = 1.f / (1.f + __expf(-(giz + ghz)));
  float nn = tanhf(gin + r * ghn);
  float o2 = fmaxf((1.f - z) * nn + z * xo, 0.f);
  float res = 0.f;
  for (int k = 0; k < 64; k++) res += bcast(o2, k) * w2[lane * 64 + k];
  dout[lane] = res + b2[lane];
}

extern "C" void kernel_launch(void* const* d_in, const int* in_sizes, int n_in,
                              void* d_out, int out_size, void* d_ws, size_t ws_size,
                              hipStream_t stream){
  const float* na    = (const float*)d_in[0];
  const float* ea    = (const float*)d_in[1];
  const int*   ei    = (const int*)d_in[2];
  const float* w1    = (const float*)d_in[3];
  const float* b1    = (const float*)d_in[4];
  const float* wg1   = (const float*)d_in[5];
  const float* att_l = (const float*)d_in[6];
  const float* att_r = (const float*)d_in[7];
  const float* wg2   = (const float*)d_in[8];
  const float* bg    = (const float*)d_in[9];
  const float* g1wih = (const float*)d_in[10];
  const float* g1whh = (const float*)d_in[11];
  const float* g1bih = (const float*)d_in[12];
  const float* g1bhh = (const float*)d_in[13];
  const float* wm      = (const float*)d_in[14];
  const float* att_src = (const float*)d_in[15];
  const float* att_dst = (const float*)d_in[16];
  const float* bm      = (const float*)d_in[17];
  const float* g2wih = (const float*)d_in[18];
  const float* g2whh = (const float*)d_in[19];
  const float* g2bih = (const float*)d_in[20];
  const float* g2bhh = (const float*)d_in[21];
  const float* w2    = (const float*)d_in[22];
  const float* b2    = (const float*)d_in[23];

  int N = in_sizes[0];
  int E = in_sizes[1];
  const int* srcArr = ei;
  const int* dstArr = ei + E;

  char* ws = (char*)d_ws;
  size_t cur = 0;
  auto alloc = [&](size_t nbytes) -> char* {
    char* p = ws + cur;
    cur += (nbytes + 255) & ~(size_t)255;
    return p;
  };
  float* y     = (float*)alloc((size_t)N * 64 * 4);
  float* bufC  = (float*)alloc((size_t)N * 64 * 4);   // sout -> x2 -> xs
  float* xr    = (float*)alloc((size_t)N * 4);
  float* tb    = (float*)alloc((size_t)N * 4);
  int*   deg   = (int*)alloc((size_t)N * 4);
  int*   offA  = (int*)alloc((size_t)(N + 1) * 4);
  int*   fill  = (int*)alloc((size_t)N * 4);
  int*   part  = (int*)alloc(1024);
  int2*  csr_sd= (int2*)alloc((size_t)E * 8);
  float* csr_e = (float*)alloc((size_t)E * 4);
  float* av    = (float*)alloc((size_t)E * 4);
  float* scal  = (float*)alloc(4096);
  float* wg1_t = (float*)alloc(64 * 64 * 4);
  float* wg2_t = (float*)alloc(64 * 64 * 4);
  float* wm_t  = (float*)alloc(64 * 64 * 4);
  float* wih_t = (float*)alloc(64 * 192 * 4);
  float* whh_t = (float*)alloc(64 * 192 * 4);
  float* wgc   = (float*)alloc(64 * 4);
  if (cur > ws_size) return;

  hipMemsetAsync(deg,  0, (size_t)N * 4, stream);
  hipMemsetAsync(scal, 0, 4096, stream);

  k_wprep<<<64, 192, 0, stream>>>(wg1, wg2, g1wih, g1whh, wm, wg1_t, wg2_t, wih_t, whh_t, wm_t, wgc);

  int nwb = (N + 3) / 4;           // 4 waves/block, 1 node/wave
  k_node_prep<<<nwb, 256, 0, stream>>>(na, w1, b1, wg1_t, att_r, y, xr, N);
  k_deg<<<(E + 255) / 256, 256, 0, stream>>>(dstArr, deg, E);
  int nb = (N + 1023) / 1024;
  k_scan1<<<nb, 1024, 0, stream>>>(deg, part, N);
  k_scan2<<<1, 64, 0, stream>>>(part, nb, offA, N);
  k_scan3<<<nb, 1024, 0, stream>>>(deg, part, offA, fill, N);
  k_fill<<<(E + 255) / 256, 256, 0, stream>>>(dstArr, srcArr, ea, fill, csr_sd, csr_e, E);
  k_edge_d<<<(E + 255) / 256, 256, 0, stream>>>(csr_sd, csr_e, y, xr, wgc, att_l, av, E);
  k_edge_c2<<<nwb, 256, 0, stream>>>(offA, csr_sd, csr_e, y, av, wgc, bufC, N);
  int ngb = (N + NPW * 4 - 1) / (NPW * 4);   // 4 waves/block, NPW nodes/wave
  k_gru1<<<ngb, 256, 0, stream>>>(bufC, na, w1, b1, wg2_t, bg, wih_t, whh_t, g1bih, g1bhh, bufC, N);
  k_part2a<<<512, 256, 0, stream>>>(bufC, wm_t, att_src, bufC, tb, scal, N);
  k_part2b<<<1, 64, 0, stream>>>(scal, wm, att_dst);
  k_a2sum<<<512, 256, 0, stream>>>(tb, bufC, scal, N);
  k_final<<<1, 64, 0, stream>>>(scal, bm, g2wih, g2whh, g2bih, g2bhh, w2, b2, (float*)d_out);
  (void)n_in; (void)out_size;
}

// Round 7
// 592.755 us; speedup vs baseline: 3.3108x; 1.2027x over previous
//
#include <hip/hip_runtime.h>
#include <math.h>

typedef __attribute__((ext_vector_type(8))) short bf8;
typedef __attribute__((ext_vector_type(4))) float f32x4;

__device__ __forceinline__ float lrelu(float v){ return v > 0.f ? v : 0.01f * v; }

__device__ __forceinline__ float wave_sum(float v){
#pragma unroll
  for (int s = 32; s > 0; s >>= 1) v += __shfl_xor(v, s);
  return v;
}
__device__ __forceinline__ float wave_max(float v){
#pragma unroll
  for (int s = 32; s > 0; s >>= 1) v = fmaxf(v, __shfl_xor(v, s));
  return v;
}

__device__ __forceinline__ float bcast(float v, int k){
  return __uint_as_float((unsigned)__builtin_amdgcn_readlane(__float_as_uint(v), k));
}

// float -> orderable unsigned key (monotone)
__device__ __forceinline__ unsigned fkey(float x){
  unsigned u = __float_as_uint(x);
  return (u & 0x80000000u) ? ~u : (u | 0x80000000u);
}
__device__ __forceinline__ float funkey(unsigned k){
  unsigned u = (k & 0x80000000u) ? (k & 0x7fffffffu) : ~k;
  return __uint_as_float(u);
}

// float -> bf16 (RNE)
__device__ __forceinline__ short f2bfs(float x){
  unsigned u = __float_as_uint(x);
  return (short)((u + 0x7fffu + ((u >> 16) & 1u)) >> 16);
}
__device__ __forceinline__ bf8 pack8(float4 a, float4 b){
  bf8 v;
  v[0]=f2bfs(a.x); v[1]=f2bfs(a.y); v[2]=f2bfs(a.z); v[3]=f2bfs(a.w);
  v[4]=f2bfs(b.x); v[5]=f2bfs(b.y); v[6]=f2bfs(b.z); v[7]=f2bfs(b.w);
  return v;
}
__device__ __forceinline__ float4 xo4(float nav, float4 w, float4 b){
  float4 r;
  r.x = lrelu(nav*w.x + b.x); r.y = lrelu(nav*w.y + b.y);
  r.z = lrelu(nav*w.z + b.z); r.w = lrelu(nav*w.w + b.w);
  return r;
}

// ---------------- weight transpose to k-major ----------------
__global__ void k_wprep(const float* __restrict__ wg1, const float* __restrict__ wm,
                        const float* __restrict__ w2,
                        const float* __restrict__ g2wih, const float* __restrict__ g2whh,
                        float* __restrict__ wg1_t, float* __restrict__ wm_t,
                        float* __restrict__ w2_t,
                        float* __restrict__ g2ih_t, float* __restrict__ g2hh_t,
                        float* __restrict__ wgc){
  int k = blockIdx.x;      // 0..63
  int r = threadIdx.x;     // 0..191
  if (r < 64){
    wg1_t[k * 64 + r] = wg1[r * 65 + k];
    wm_t [k * 64 + r] = wm [r * 64 + k];
    w2_t [k * 64 + r] = w2 [r * 64 + k];
    if (k == 0) wgc[r] = wg1[r * 65 + 64];
  }
  g2ih_t[k * 192 + r] = g2wih[r * 64 + k];
  g2hh_t[k * 192 + r] = g2whh[r * 64 + k];
}

// ---------------- pack GRU1/wg2 weights into bf16 MFMA B-fragments ----------------
// B-frag slot (c, t, lane l, j) <- W[16t + (l&15)][32c + (l>>4)*8 + j]
__global__ void k_wfrag(const float* __restrict__ wg2, const float* __restrict__ wih,
                        const float* __restrict__ whh,
                        ushort* __restrict__ wg2f, ushort* __restrict__ wihf,
                        ushort* __restrict__ whhf){
  int tid = blockIdx.x * 256 + threadIdx.x;  // 0..3583
  const float* W; ushort* F; int T, base;
  if (tid < 512)      { W = wg2; F = wg2f; T = 4;  base = tid; }
  else if (tid < 2048){ W = wih; F = wihf; T = 12; base = tid - 512; }
  else                { W = whh; F = whhf; T = 12; base = tid - 2048; }
  int l  = base & 63;
  int ct = base >> 6;
  int c  = ct / T, t = ct - c * T;
  int row = 16 * t + (l & 15);
  int k0  = 32 * c + (l >> 4) * 8;
  const float* src = W + row * 64 + k0;
  unsigned o0 = (unsigned)(ushort)f2bfs(src[0]) | ((unsigned)(ushort)f2bfs(src[1]) << 16);
  unsigned o1 = (unsigned)(ushort)f2bfs(src[2]) | ((unsigned)(ushort)f2bfs(src[3]) << 16);
  unsigned o2 = (unsigned)(ushort)f2bfs(src[4]) | ((unsigned)(ushort)f2bfs(src[5]) << 16);
  unsigned o3 = (unsigned)(ushort)f2bfs(src[6]) | ((unsigned)(ushort)f2bfs(src[7]) << 16);
  ((uint4*)F)[base] = make_uint4(o0, o1, o2, o3);
}

// ---------------- node prep ----------------
__global__ void k_node_prep(const float* __restrict__ na, const float* __restrict__ w1,
                            const float* __restrict__ b1, const float* __restrict__ wg1_t,
                            const float* __restrict__ att_r,
                            float* __restrict__ y, float* __restrict__ xr, int N){
  int lane = threadIdx.x & 63;
  int wid  = (blockIdx.x * blockDim.x + threadIdx.x) >> 6;
  if (wid >= N) return;
  float xv = lrelu(na[wid] * w1[lane] + b1[lane]);
  float acc = 0.f;
#pragma unroll 8
  for (int k = 0; k < 64; k++)
    acc += bcast(xv, k) * wg1_t[k * 64 + lane];
  y[(size_t)wid * 64 + lane] = acc;
  float t = wave_sum(xv * att_r[lane]);
  if (lane == 0) xr[wid] = t;
}

// ---------------- CSR build ----------------
__global__ void k_deg(const int* __restrict__ dst, int* __restrict__ deg, int E){
  int e = blockIdx.x * 256 + threadIdx.x;
  if (e >= E) return;
  atomicAdd(&deg[dst[e]], 1);
}

__global__ void k_scan1(const int* __restrict__ deg, int* __restrict__ partial, int N){
  __shared__ int lds[1024];
  int gid = blockIdx.x * 1024 + threadIdx.x;
  lds[threadIdx.x] = (gid < N) ? deg[gid] : 0;
  __syncthreads();
  for (int s = 512; s > 0; s >>= 1){
    if (threadIdx.x < s) lds[threadIdx.x] += lds[threadIdx.x + s];
    __syncthreads();
  }
  if (threadIdx.x == 0) partial[blockIdx.x] = lds[0];
}

// parallel scan over block partials (nb <= 1024)
__global__ void k_scan2(int* __restrict__ partial, int nb, int* __restrict__ off, int N){
  __shared__ int lds[1024];
  int t = threadIdx.x;
  int v = (t < nb) ? partial[t] : 0;
  lds[t] = v;
  __syncthreads();
  for (int s = 1; s < 1024; s <<= 1){
    int tv = (t >= s) ? lds[t - s] : 0;
    __syncthreads();
    lds[t] += tv;
    __syncthreads();
  }
  if (t < nb) partial[t] = lds[t] - v;    // exclusive prefix
  if (t == 1023) off[N] = lds[1023];      // total = E
}

__global__ void k_scan3(const int* __restrict__ deg, const int* __restrict__ partial,
                        int* __restrict__ off, int* __restrict__ fill, int N){
  __shared__ int lds[1024];
  int gid = blockIdx.x * 1024 + threadIdx.x;
  int v = (gid < N) ? deg[gid] : 0;
  lds[threadIdx.x] = v;
  __syncthreads();
  for (int s = 1; s < 1024; s <<= 1){
    int t = (threadIdx.x >= s) ? lds[threadIdx.x - s] : 0;
    __syncthreads();
    lds[threadIdx.x] += t;
    __syncthreads();
  }
  if (gid < N){
    int excl = partial[blockIdx.x] + lds[threadIdx.x] - v;
    off[gid] = excl;
    fill[gid] = excl;
  }
}

__global__ void k_fill(const int* __restrict__ dst, const int* __restrict__ src,
                       const float* __restrict__ ea, int* __restrict__ fill,
                       int2* __restrict__ csr_sd, float* __restrict__ csr_ea, int E){
  int e = blockIdx.x * 256 + threadIdx.x;
  if (e >= E) return;
  int d = dst[e];
  int pos = atomicAdd(&fill[d], 1);
  csr_sd[pos] = make_int2(src[e], d);
  csr_ea[pos] = ea[e];
}

// ---------------- edge pass D (edge-parallel) ----------------
__global__ void k_edge_d(const int2* __restrict__ csr_sd, const float* __restrict__ csr_ea,
                         const float* __restrict__ y,
                         const float* __restrict__ xr, const float* __restrict__ wgc,
                         const float* __restrict__ att_l,
                         float* __restrict__ av, int E){
  int i = blockIdx.x * 256 + threadIdx.x;
  if (i >= E) return;
  int2  sd = csr_sd[i];
  float ea = csr_ea[i];
  const float4* yr = (const float4*)(y + (size_t)sd.x * 64);
  const float4* wc4 = (const float4*)wgc;
  const float4* al4 = (const float4*)att_l;
  float d = 0.f;
#pragma unroll
  for (int q = 0; q < 16; q++){
    float4 yv = yr[q];
    float4 wc = wc4[q];
    float4 al = al4[q];
    d += lrelu(yv.x + ea * wc.x) * al.x + lrelu(yv.y + ea * wc.y) * al.y
       + lrelu(yv.z + ea * wc.z) * al.z + lrelu(yv.w + ea * wc.w) * al.w;
  }
  av[i] = lrelu(d + xr[sd.y]);
}

// ---------------- edge pass C2 (4 edge-groups of 16 lanes) ----------------
__global__ void k_edge_c2(const int* __restrict__ off, const int2* __restrict__ csr_sd,
                          const float* __restrict__ csr_e, const float* __restrict__ y,
                          const float* __restrict__ av, const float* __restrict__ wgc,
                          float* __restrict__ sout, int N){
  int lane = threadIdx.x & 63;
  int wid  = (blockIdx.x * blockDim.x + threadIdx.x) >> 6;
  if (wid >= N) return;
  int i0 = off[wid], i1 = off[wid + 1];
  float m = -1e30f;
  for (int i = i0 + lane; i < i1; i += 64) m = fmaxf(m, av[i]);
  m = wave_max(m);
  float s = 0.f;
  for (int i = i0 + lane; i < i1; i += 64) s += __expf(av[i] - m);
  s = wave_sum(s);
  float inv = (i1 > i0 && s > 0.f) ? 1.f / s : 0.f;
  int sub = lane >> 4, sl = lane & 15;
  float4 wc4 = ((const float4*)wgc)[sl];
  float4 acc = make_float4(0.f, 0.f, 0.f, 0.f);
  for (int i = i0 + sub; i < i1; i += 4){
    int   sn = csr_sd[i].x;
    float ea = csr_e[i];
    float w  = __expf(av[i] - m) * inv;
    float4 yv = ((const float4*)(y + (size_t)sn * 64))[sl];
    acc.x += w * lrelu(yv.x + ea * wc4.x);
    acc.y += w * lrelu(yv.y + ea * wc4.y);
    acc.z += w * lrelu(yv.z + ea * wc4.z);
    acc.w += w * lrelu(yv.w + ea * wc4.w);
  }
  acc.x += __shfl_xor(acc.x, 16); acc.y += __shfl_xor(acc.y, 16);
  acc.z += __shfl_xor(acc.z, 16); acc.w += __shfl_xor(acc.w, 16);
  acc.x += __shfl_xor(acc.x, 32); acc.y += __shfl_xor(acc.y, 32);
  acc.z += __shfl_xor(acc.z, 32); acc.w += __shfl_xor(acc.w, 32);
  if (sub == 0) ((float4*)(sout + (size_t)wid * 64))[sl] = acc;
}

// ---------------- GRU1 via MFMA: block = 64 nodes, wave = 16-node M-tile ----------------
__global__ __launch_bounds__(256) void k_gru1m(
    const float* __restrict__ sout, const float* __restrict__ na,
    const float* __restrict__ w1, const float* __restrict__ b1,
    const ushort* __restrict__ wg2f, const float* __restrict__ bg,
    const ushort* __restrict__ wihf, const ushort* __restrict__ whhf,
    const float* __restrict__ bih, const float* __restrict__ bhh,
    float* __restrict__ x2, int N){
  __shared__ ushort xgl[4][16][72];   // per-wave elu(h) tile, bf16, padded rows
  int lane = threadIdx.x & 63;
  int wid  = threadIdx.x >> 6;
  int m = lane & 15, g = lane >> 4;
  int n0 = blockIdx.x * 64 + wid * 16;
  if (n0 >= N) return;                 // no barriers used -> safe early exit
  int rowc = min(n0 + m, N - 1);
  const float* srow = sout + (size_t)rowc * 64;
  // A-fragments of sout (k-chunks c=0,1)
  bf8 sa0 = pack8(*(const float4*)(srow + g * 8),      *(const float4*)(srow + g * 8 + 4));
  bf8 sa1 = pack8(*(const float4*)(srow + 32 + g * 8), *(const float4*)(srow + 32 + g * 8 + 4));
  const bf8* WG = (const bf8*)wg2f;
  // H = sout @ wg2^T  (4 col-tiles)
  f32x4 h[4];
#pragma unroll
  for (int t = 0; t < 4; t++){
    f32x4 acc = {0.f, 0.f, 0.f, 0.f};
    acc = __builtin_amdgcn_mfma_f32_16x16x32_bf16(sa0, WG[t * 64 + lane], acc, 0, 0, 0);
    acc = __builtin_amdgcn_mfma_f32_16x16x32_bf16(sa1, WG[(4 + t) * 64 + lane], acc, 0, 0, 0);
    h[t] = acc;
  }
  // xg = elu(h + bg) -> LDS (C-layout -> A-layout transpose)
#pragma unroll
  for (int t = 0; t < 4; t++){
    float bgc = bg[m + 16 * t];
#pragma unroll
    for (int r = 0; r < 4; r++){
      float hv = h[t][r] + bgc;
      float xg = hv > 0.f ? hv : __expf(hv) - 1.f;
      xgl[wid][g * 4 + r][m + 16 * t] = (ushort)f2bfs(xg);
    }
  }
  // xo A-fragments computed directly
  float nav = na[rowc];
  bf8 xoa0 = pack8(xo4(nav, *(const float4*)(w1 + g * 8),      *(const float4*)(b1 + g * 8)),
                   xo4(nav, *(const float4*)(w1 + g * 8 + 4),  *(const float4*)(b1 + g * 8 + 4)));
  bf8 xoa1 = pack8(xo4(nav, *(const float4*)(w1 + 32 + g * 8),     *(const float4*)(b1 + 32 + g * 8)),
                   xo4(nav, *(const float4*)(w1 + 32 + g * 8 + 4), *(const float4*)(b1 + 32 + g * 8 + 4)));
  // read back xg A-fragments (same wave's LDS slice; compiler inserts lgkmcnt)
  bf8 xga0 = *(const bf8*)&xgl[wid][m][g * 8];
  bf8 xga1 = *(const bf8*)&xgl[wid][m][32 + g * 8];
  const bf8* WI = (const bf8*)wihf;
  const bf8* WH = (const bf8*)whhf;
#pragma unroll
  for (int t = 0; t < 4; t++){
    f32x4 iR = {0.f,0.f,0.f,0.f}, iZ = iR, iN = iR, hR = iR, hZ = iR, hN = iR;
    iR = __builtin_amdgcn_mfma_f32_16x16x32_bf16(xga0, WI[(t     ) * 64 + lane], iR, 0,0,0);
    iR = __builtin_amdgcn_mfma_f32_16x16x32_bf16(xga1, WI[(12 + t) * 64 + lane], iR, 0,0,0);
    iZ = __builtin_amdgcn_mfma_f32_16x16x32_bf16(xga0, WI[(t +  4) * 64 + lane], iZ, 0,0,0);
    iZ = __builtin_amdgcn_mfma_f32_16x16x32_bf16(xga1, WI[(16 + t) * 64 + lane], iZ, 0,0,0);
    iN = __builtin_amdgcn_mfma_f32_16x16x32_bf16(xga0, WI[(t +  8) * 64 + lane], iN, 0,0,0);
    iN = __builtin_amdgcn_mfma_f32_16x16x32_bf16(xga1, WI[(20 + t) * 64 + lane], iN, 0,0,0);
    hR = __builtin_amdgcn_mfma_f32_16x16x32_bf16(xoa0, WH[(t     ) * 64 + lane], hR, 0,0,0);
    hR = __builtin_amdgcn_mfma_f32_16x16x32_bf16(xoa1, WH[(12 + t) * 64 + lane], hR, 0,0,0);
    hZ = __builtin_amdgcn_mfma_f32_16x16x32_bf16(xoa0, WH[(t +  4) * 64 + lane], hZ, 0,0,0);
    hZ = __builtin_amdgcn_mfma_f32_16x16x32_bf16(xoa1, WH[(16 + t) * 64 + lane], hZ, 0,0,0);
    hN = __builtin_amdgcn_mfma_f32_16x16x32_bf16(xoa0, WH[(t +  8) * 64 + lane], hN, 0,0,0);
    hN = __builtin_amdgcn_mfma_f32_16x16x32_bf16(xoa1, WH[(20 + t) * 64 + lane], hN, 0,0,0);
    int col = m + 16 * t;
    float biR = bih[col], biZ = bih[64 + col], biN = bih[128 + col];
    float bhR = bhh[col], bhZ = bhh[64 + col], bhN = bhh[128 + col];
    float w1c = w1[col], b1c = b1[col];
#pragma unroll
    for (int r = 0; r < 4; r++){
      int node = n0 + g * 4 + r;
      if (node < N){
        float xon = lrelu(na[node] * w1c + b1c);
        float rg = 1.f / (1.f + __expf(-(iR[r] + biR + hR[r] + bhR)));
        float zg = 1.f / (1.f + __expf(-(iZ[r] + biZ + hZ[r] + bhZ)));
        float nn = tanhf(iN[r] + biN + rg * (hN[r] + bhN));
        float xn = (1.f - zg) * nn + zg * xon;
        x2[(size_t)node * 64 + col] = fmaxf(xn, 0.f);
      }
    }
  }
}

// ---------------- part2a ----------------
__global__ void k_part2a(const float* __restrict__ x2, const float* __restrict__ wm_t,
                         const float* __restrict__ att_src,
                         float* __restrict__ xs, float* __restrict__ tb,
                         float* __restrict__ scal, int N){
  int lane = threadIdx.x & 63, w = threadIdx.x >> 6;
  int gw = blockIdx.x * 4 + w, nw = gridDim.x * 4;
  float as = att_src[lane];
  float os = 0.f;
  float tmax = -1e30f;
  for (int n = gw; n < N; n += nw){
    float xv = x2[(size_t)n * 64 + lane];
    os += xv;
    float acc = 0.f;
#pragma unroll 8
    for (int k = 0; k < 64; k++) acc += bcast(xv, k) * wm_t[k * 64 + lane];
    xs[(size_t)n * 64 + lane] = acc;
    float t = wave_sum(acc * as);
    tmax = fmaxf(tmax, t);
    if (lane == 0) tb[n] = t;
  }
  if (lane == 0) atomicMax((unsigned*)(scal + 131), fkey(tmax));
  __shared__ float lds[256];
  lds[threadIdx.x] = os;
  __syncthreads();
  if (threadIdx.x < 64)
    atomicAdd(&scal[threadIdx.x],
              lds[threadIdx.x] + lds[64 + threadIdx.x] + lds[128 + threadIdx.x] + lds[192 + threadIdx.x]);
}

// ---------------- part2b (1 wave) ----------------
__global__ void k_part2b(float* __restrict__ scal, const float* __restrict__ wm_t,
                         const float* __restrict__ att_dst){
  int lane = threadIdx.x;
  float o = fmaxf(scal[lane], 0.f);
  float acc = 0.f;
  for (int k = 0; k < 64; k++) acc += bcast(o, k) * wm_t[k * 64 + lane];
  float c = wave_sum(acc * att_dst[lane]);
  scal[64 + lane] = o;
  if (lane == 0){
    scal[128] = c;
    float maxtb = funkey(*(unsigned*)(scal + 131));
    scal[130] = lrelu(maxtb + c);   // M = max_n lrelu(tb[n]+c)
  }
}

// ---------------- a2 weighted sums ----------------
__global__ void k_a2sum(const float* __restrict__ tb, const float* __restrict__ xs,
                        float* __restrict__ scal, int N){
  int lane = threadIdx.x & 63, w = threadIdx.x >> 6;
  int gw = blockIdx.x * 4 + w, nw = gridDim.x * 4;
  float c = scal[128];
  float M = scal[130];
  float hloc = 0.f, sloc = 0.f;
  for (int n = gw; n < N; n += nw){
    float a2 = lrelu(tb[n] + c);
    float wt = __expf(a2 - M);
    sloc += wt;
    hloc += wt * xs[(size_t)n * 64 + lane];
  }
  __shared__ float lds[256];
  __shared__ float sred[4];
  lds[threadIdx.x] = hloc;
  if (lane == 0) sred[w] = sloc;
  __syncthreads();
  if (threadIdx.x < 64)
    atomicAdd(&scal[192 + threadIdx.x],
              lds[threadIdx.x] + lds[64 + threadIdx.x] + lds[128 + threadIdx.x] + lds[192 + threadIdx.x]);
  if (threadIdx.x == 0) atomicAdd(&scal[129], sred[0] + sred[1] + sred[2] + sred[3]);
}

// ---------------- final (1 wave, coalesced transposed weights) ----------------
__global__ void k_final(const float* __restrict__ scal, const float* __restrict__ bm,
                        const float* __restrict__ g2ih_t, const float* __restrict__ g2hh_t,
                        const float* __restrict__ bih, const float* __restrict__ bhh,
                        const float* __restrict__ w2_t, const float* __restrict__ b2,
                        float* __restrict__ dout){
  int lane = threadIdx.x;
  float S  = scal[129];
  float h2 = scal[192 + lane] / S + bm[lane];
  float xg = h2 > 0.f ? h2 : __expf(h2) - 1.f;
  float xo = scal[64 + lane];
  float gir = bih[lane], giz = bih[64 + lane], gin = bih[128 + lane];
  float ghr = bhh[lane], ghz = bhh[64 + lane], ghn = bhh[128 + lane];
  for (int k = 0; k < 64; k++){
    float a = bcast(xg, k), b = bcast(xo, k);
    const float* gi = g2ih_t + k * 192;
    const float* gh = g2hh_t + k * 192;
    gir += a * gi[lane]; giz += a * gi[64 + lane]; gin += a * gi[128 + lane];
    ghr += b * gh[lane]; ghz += b * gh[64 + lane]; ghn += b * gh[128 + lane];
  }
  float r  = 1.f / (1.f + __expf(-(gir + ghr)));
  float z  = 1.f / (1.f + __expf(-(giz + ghz)));
  float nn = tanhf(gin + r * ghn);
  float o2 = fmaxf((1.f - z) * nn + z * xo, 0.f);
  float res = 0.f;
  for (int k = 0; k < 64; k++) res += bcast(o2, k) * w2_t[k * 64 + lane];
  dout[lane] = res + b2[lane];
}

extern "C" void kernel_launch(void* const* d_in, const int* in_sizes, int n_in,
                              void* d_out, int out_size, void* d_ws, size_t ws_size,
                              hipStream_t stream){
  const float* na    = (const float*)d_in[0];
  const float* ea    = (const float*)d_in[1];
  const int*   ei    = (const int*)d_in[2];
  const float* w1    = (const float*)d_in[3];
  const float* b1    = (const float*)d_in[4];
  const float* wg1   = (const float*)d_in[5];
  const float* att_l = (const float*)d_in[6];
  const float* att_r = (const float*)d_in[7];
  const float* wg2   = (const float*)d_in[8];
  const float* bg    = (const float*)d_in[9];
  const float* g1wih = (const float*)d_in[10];
  const float* g1whh = (const float*)d_in[11];
  const float* g1bih = (const float*)d_in[12];
  const float* g1bhh = (const float*)d_in[13];
  const float* wm      = (const float*)d_in[14];
  const float* att_src = (const float*)d_in[15];
  const float* att_dst = (const float*)d_in[16];
  const float* bm      = (const float*)d_in[17];
  const float* g2wih = (const float*)d_in[18];
  const float* g2whh = (const float*)d_in[19];
  const float* g2bih = (const float*)d_in[20];
  const float* g2bhh = (const float*)d_in[21];
  const float* w2    = (const float*)d_in[22];
  const float* b2    = (const float*)d_in[23];

  int N = in_sizes[0];
  int E = in_sizes[1];
  const int* srcArr = ei;
  const int* dstArr = ei + E;

  char* ws = (char*)d_ws;
  size_t cur = 0;
  auto alloc = [&](size_t nbytes) -> char* {
    char* p = ws + cur;
    cur += (nbytes + 255) & ~(size_t)255;
    return p;
  };
  float* y     = (float*)alloc((size_t)N * 64 * 4);
  float* bufC  = (float*)alloc((size_t)N * 64 * 4);   // sout -> x2 -> xs
  float* xr    = (float*)alloc((size_t)N * 4);
  float* tb    = (float*)alloc((size_t)N * 4);
  int*   deg   = (int*)alloc((size_t)N * 4);
  int*   offA  = (int*)alloc((size_t)(N + 1) * 4);
  int*   fill  = (int*)alloc((size_t)N * 4);
  int*   part  = (int*)alloc(4096);
  int2*  csr_sd= (int2*)alloc((size_t)E * 8);
  float* csr_e = (float*)alloc((size_t)E * 4);
  float* av    = (float*)alloc((size_t)E * 4);
  float* scal  = (float*)alloc(4096);
  float* wg1_t = (float*)alloc(64 * 64 * 4);
  float* wm_t  = (float*)alloc(64 * 64 * 4);
  float* w2_t  = (float*)alloc(64 * 64 * 4);
  float* g2ih_t= (float*)alloc(64 * 192 * 4);
  float* g2hh_t= (float*)alloc(64 * 192 * 4);
  float* wgc   = (float*)alloc(64 * 4);
  ushort* wg2f = (ushort*)alloc(4096 * 2);
  ushort* wihf = (ushort*)alloc(12288 * 2);
  ushort* whhf = (ushort*)alloc(12288 * 2);
  if (cur > ws_size) return;

  hipMemsetAsync(deg,  0, (size_t)N * 4, stream);
  hipMemsetAsync(scal, 0, 4096, stream);

  k_wprep<<<64, 192, 0, stream>>>(wg1, wm, w2, g2wih, g2whh,
                                  wg1_t, wm_t, w2_t, g2ih_t, g2hh_t, wgc);
  k_wfrag<<<14, 256, 0, stream>>>(wg2, g1wih, g1whh, wg2f, wihf, whhf);

  int nwb = (N + 3) / 4;           // 4 waves/block, 1 node/wave
  k_node_prep<<<nwb, 256, 0, stream>>>(na, w1, b1, wg1_t, att_r, y, xr, N);
  k_deg<<<(E + 255) / 256, 256, 0, stream>>>(dstArr, deg, E);
  int nb = (N + 1023) / 1024;
  k_scan1<<<nb, 1024, 0, stream>>>(deg, part, N);
  k_scan2<<<1, 1024, 0, stream>>>(part, nb, offA, N);
  k_scan3<<<nb, 1024, 0, stream>>>(deg, part, offA, fill, N);
  k_fill<<<(E + 255) / 256, 256, 0, stream>>>(dstArr, srcArr, ea, fill, csr_sd, csr_e, E);
  k_edge_d<<<(E + 255) / 256, 256, 0, stream>>>(csr_sd, csr_e, y, xr, wgc, att_l, av, E);
  k_edge_c2<<<nwb, 256, 0, stream>>>(offA, csr_sd, csr_e, y, av, wgc, bufC, N);
  int ngb = (N + 63) / 64;         // 4 waves/block, 16 nodes/wave (MFMA)
  k_gru1m<<<ngb, 256, 0, stream>>>(bufC, na, w1, b1, wg2f, bg, wihf, whhf,
                                   g1bih, g1bhh, bufC, N);
  k_part2a<<<512, 256, 0, stream>>>(bufC, wm_t, att_src, bufC, tb, scal, N);
  k_part2b<<<1, 64, 0, stream>>>(scal, wm_t, att_dst);
  k_a2sum<<<512, 256, 0, stream>>>(tb, bufC, scal, N);
  k_final<<<1, 64, 0, stream>>>(scal, bm, g2ih_t, g2hh_t, g2bih, g2bhh, w2_t, b2, (float*)d_out);
  (void)n_in; (void)out_size;
}

// Round 8
// 429.781 us; speedup vs baseline: 4.5663x; 1.3792x over previous
//
#include <hip/hip_runtime.h>
#include <math.h>

typedef __attribute__((ext_vector_type(8))) short bf8;
typedef __attribute__((ext_vector_type(4))) float f32x4;

__device__ __forceinline__ float lrelu(float v){ return v > 0.f ? v : 0.01f * v; }

__device__ __forceinline__ float wave_sum(float v){
#pragma unroll
  for (int s = 32; s > 0; s >>= 1) v += __shfl_xor(v, s);
  return v;
}
__device__ __forceinline__ float wave_max(float v){
#pragma unroll
  for (int s = 32; s > 0; s >>= 1) v = fmaxf(v, __shfl_xor(v, s));
  return v;
}

__device__ __forceinline__ float bcast(float v, int k){
  return __uint_as_float((unsigned)__builtin_amdgcn_readlane(__float_as_uint(v), k));
}

// float -> orderable unsigned key (monotone)
__device__ __forceinline__ unsigned fkey(float x){
  unsigned u = __float_as_uint(x);
  return (u & 0x80000000u) ? ~u : (u | 0x80000000u);
}
__device__ __forceinline__ float funkey(unsigned k){
  unsigned u = (k & 0x80000000u) ? (k & 0x7fffffffu) : ~k;
  return __uint_as_float(u);
}

// float -> bf16 (RNE)
__device__ __forceinline__ short f2bfs(float x){
  unsigned u = __float_as_uint(x);
  return (short)((u + 0x7fffu + ((u >> 16) & 1u)) >> 16);
}
__device__ __forceinline__ bf8 pack8(float4 a, float4 b){
  bf8 v;
  v[0]=f2bfs(a.x); v[1]=f2bfs(a.y); v[2]=f2bfs(a.z); v[3]=f2bfs(a.w);
  v[4]=f2bfs(b.x); v[5]=f2bfs(b.y); v[6]=f2bfs(b.z); v[7]=f2bfs(b.w);
  return v;
}
__device__ __forceinline__ float4 xo4(float nav, float4 w, float4 b){
  float4 r;
  r.x = lrelu(nav*w.x + b.x); r.y = lrelu(nav*w.y + b.y);
  r.z = lrelu(nav*w.z + b.z); r.w = lrelu(nav*w.w + b.w);
  return r;
}
__device__ __forceinline__ float dot4(float4 a, float4 b){
  return a.x*b.x + a.y*b.y + a.z*b.z + a.w*b.w;
}

// ---------------- weight transpose to k-major (small weights for 1-wave kernels) ----------------
__global__ void k_wprep(const float* __restrict__ wg1, const float* __restrict__ wm,
                        const float* __restrict__ w2,
                        const float* __restrict__ g2wih, const float* __restrict__ g2whh,
                        float* __restrict__ wm_t, float* __restrict__ w2_t,
                        float* __restrict__ g2ih_t, float* __restrict__ g2hh_t,
                        float* __restrict__ wgc){
  int k = blockIdx.x;      // 0..63
  int r = threadIdx.x;     // 0..191
  if (r < 64){
    wm_t [k * 64 + r] = wm [r * 64 + k];
    w2_t [k * 64 + r] = w2 [r * 64 + k];
    if (k == 0) wgc[r] = wg1[r * 65 + 64];
  }
  g2ih_t[k * 192 + r] = g2wih[r * 64 + k];
  g2hh_t[k * 192 + r] = g2whh[r * 64 + k];
}

// ---------------- pack weights into bf16 MFMA B-fragments ----------------
// B-frag slot (c, t, lane l, j) <- W[16t + (l&15)][32c + (l>>4)*8 + j], row stride S
__global__ void k_wfrag(const float* __restrict__ wg2, const float* __restrict__ wm,
                        const float* __restrict__ wg1,
                        const float* __restrict__ wih, const float* __restrict__ whh,
                        ushort* __restrict__ wg2f, ushort* __restrict__ wmf,
                        ushort* __restrict__ wg1f,
                        ushort* __restrict__ wihf, ushort* __restrict__ whhf){
  int tid = blockIdx.x * 256 + threadIdx.x;  // 0..4607
  if (tid >= 4608) return;
  const float* W; ushort* F; int T, S, base;
  if (tid < 512)      { W = wg2; F = wg2f; T = 4;  S = 64; base = tid; }
  else if (tid < 1024){ W = wm;  F = wmf;  T = 4;  S = 64; base = tid - 1024 + 512; }
  else if (tid < 1536){ W = wg1; F = wg1f; T = 4;  S = 65; base = tid - 1024; }
  else if (tid < 3072){ W = wih; F = wihf; T = 12; S = 64; base = tid - 1536; }
  else                { W = whh; F = whhf; T = 12; S = 64; base = tid - 3072; }
  int l  = base & 63;
  int ct = base >> 6;
  int c  = ct / T, t = ct - c * T;
  int row = 16 * t + (l & 15);
  int k0  = 32 * c + (l >> 4) * 8;
  const float* src = W + row * S + k0;
  unsigned o0 = (unsigned)(ushort)f2bfs(src[0]) | ((unsigned)(ushort)f2bfs(src[1]) << 16);
  unsigned o1 = (unsigned)(ushort)f2bfs(src[2]) | ((unsigned)(ushort)f2bfs(src[3]) << 16);
  unsigned o2 = (unsigned)(ushort)f2bfs(src[4]) | ((unsigned)(ushort)f2bfs(src[5]) << 16);
  unsigned o3 = (unsigned)(ushort)f2bfs(src[6]) | ((unsigned)(ushort)f2bfs(src[7]) << 16);
  ((uint4*)F)[base] = make_uint4(o0, o1, o2, o3);
}

// ---------------- node prep via MFMA: y = x@wg1[:,:64].T, xr = dot(x, att_r) ----------------
__global__ __launch_bounds__(256) void k_node_m(
    const float* __restrict__ na, const float* __restrict__ w1,
    const float* __restrict__ b1, const ushort* __restrict__ wg1f,
    const float* __restrict__ att_r,
    float* __restrict__ y, float* __restrict__ xr, int N){
  int lane = threadIdx.x & 63;
  int wid  = threadIdx.x >> 6;
  int m = lane & 15, g = lane >> 4;
  const bf8* WG = (const bf8*)wg1f;
  float4 w1a = *(const float4*)(w1 + g*8),      w1b = *(const float4*)(w1 + g*8 + 4);
  float4 w1c = *(const float4*)(w1 + 32 + g*8), w1d = *(const float4*)(w1 + 32 + g*8 + 4);
  float4 b1a = *(const float4*)(b1 + g*8),      b1b = *(const float4*)(b1 + g*8 + 4);
  float4 b1c = *(const float4*)(b1 + 32 + g*8), b1d = *(const float4*)(b1 + 32 + g*8 + 4);
  float4 ara = *(const float4*)(att_r + g*8),      arb = *(const float4*)(att_r + g*8 + 4);
  float4 arc = *(const float4*)(att_r + 32 + g*8), ard = *(const float4*)(att_r + 32 + g*8 + 4);
  int ntiles = (N + 15) >> 4;
  for (int tile = blockIdx.x * 4 + wid; tile < ntiles; tile += gridDim.x * 4){
    int n0 = tile * 16;
    int row = n0 + m;
    bool valid = row < N;
    float nav = valid ? na[row] : 0.f;
    float4 x0 = xo4(nav, w1a, b1a), x1 = xo4(nav, w1b, b1b);
    float4 x2 = xo4(nav, w1c, b1c), x3 = xo4(nav, w1d, b1d);
    // xr = row-dot with att_r (reduce across g: lanes m, m+16, m+32, m+48)
    float xa = dot4(x0, ara) + dot4(x1, arb) + dot4(x2, arc) + dot4(x3, ard);
    xa += __shfl_xor(xa, 16); xa += __shfl_xor(xa, 32);
    if (g == 0 && valid) xr[row] = xa;
    bf8 fa0 = pack8(x0, x1), fa1 = pack8(x2, x3);
    f32x4 yt[4];
#pragma unroll
    for (int t = 0; t < 4; t++){
      f32x4 acc = {0.f, 0.f, 0.f, 0.f};
      acc = __builtin_amdgcn_mfma_f32_16x16x32_bf16(fa0, WG[t * 64 + lane], acc, 0, 0, 0);
      acc = __builtin_amdgcn_mfma_f32_16x16x32_bf16(fa1, WG[(4 + t) * 64 + lane], acc, 0, 0, 0);
      yt[t] = acc;
    }
#pragma unroll
    for (int t = 0; t < 4; t++){
#pragma unroll
      for (int r = 0; r < 4; r++){
        int rw = n0 + g * 4 + r;
        if (rw < N) y[(size_t)rw * 64 + m + 16 * t] = yt[t][r];
      }
    }
  }
}

// ---------------- CSR build ----------------
__global__ void k_deg(const int* __restrict__ dst, int* __restrict__ deg, int E){
  int e = blockIdx.x * 256 + threadIdx.x;
  if (e >= E) return;
  atomicAdd(&deg[dst[e]], 1);
}

__global__ void k_scan1(const int* __restrict__ deg, int* __restrict__ partial, int N){
  __shared__ int lds[1024];
  int gid = blockIdx.x * 1024 + threadIdx.x;
  lds[threadIdx.x] = (gid < N) ? deg[gid] : 0;
  __syncthreads();
  for (int s = 512; s > 0; s >>= 1){
    if (threadIdx.x < s) lds[threadIdx.x] += lds[threadIdx.x + s];
    __syncthreads();
  }
  if (threadIdx.x == 0) partial[blockIdx.x] = lds[0];
}

__global__ void k_scan2(int* __restrict__ partial, int nb, int* __restrict__ off, int N){
  __shared__ int lds[1024];
  int t = threadIdx.x;
  int v = (t < nb) ? partial[t] : 0;
  lds[t] = v;
  __syncthreads();
  for (int s = 1; s < 1024; s <<= 1){
    int tv = (t >= s) ? lds[t - s] : 0;
    __syncthreads();
    lds[t] += tv;
    __syncthreads();
  }
  if (t < nb) partial[t] = lds[t] - v;    // exclusive prefix
  if (t == 1023) off[N] = lds[1023];      // total = E
}

__global__ void k_scan3(const int* __restrict__ deg, const int* __restrict__ partial,
                        int* __restrict__ off, int* __restrict__ fill, int N){
  __shared__ int lds[1024];
  int gid = blockIdx.x * 1024 + threadIdx.x;
  int v = (gid < N) ? deg[gid] : 0;
  lds[threadIdx.x] = v;
  __syncthreads();
  for (int s = 1; s < 1024; s <<= 1){
    int t = (threadIdx.x >= s) ? lds[threadIdx.x - s] : 0;
    __syncthreads();
    lds[threadIdx.x] += t;
    __syncthreads();
  }
  if (gid < N){
    int excl = partial[blockIdx.x] + lds[threadIdx.x] - v;
    off[gid] = excl;
    fill[gid] = excl;
  }
}

// single 8 B scattered record per edge: {src, ea-bits}
__global__ void k_fill(const int* __restrict__ dst, const int* __restrict__ src,
                       const float* __restrict__ ea, int* __restrict__ fill,
                       int2* __restrict__ csr, int E){
  int e = blockIdx.x * 256 + threadIdx.x;
  if (e >= E) return;
  int d = dst[e];
  int pos = atomicAdd(&fill[d], 1);
  csr[pos] = make_int2(src[e], __float_as_int(ea[e]));
}

// ---------------- fused edge kernel: softmax stats (pass 1) + weighted sum (pass 2)
// wave per node; 4 groups of 16 lanes, each group owns every 4th edge; lane holds 4 dims
__global__ void k_edge_f(const int* __restrict__ off, const int2* __restrict__ csr,
                         const float* __restrict__ y, const float* __restrict__ xr,
                         const float* __restrict__ wgc, const float* __restrict__ att_l,
                         float* __restrict__ sout, int N){
  int lane = threadIdx.x & 63;
  int wid  = (blockIdx.x * blockDim.x + threadIdx.x) >> 6;
  if (wid >= N) return;
  int i0 = off[wid], i1 = off[wid + 1];
  int sub = lane >> 4, sl = lane & 15;
  float4 wc4 = ((const float4*)wgc)[sl];
  float4 al4 = ((const float4*)att_l)[sl];
  float xrn = xr[wid];
  // pass 1: online (m, s) per group
  float mg = -1e30f, sg = 0.f;
  for (int i = i0 + sub; i < i1; i += 4){
    int2 rec = csr[i];
    float ea = __int_as_float(rec.y);
    float4 yv = ((const float4*)(y + (size_t)rec.x * 64))[sl];
    float p = lrelu(yv.x + ea*wc4.x)*al4.x + lrelu(yv.y + ea*wc4.y)*al4.y
            + lrelu(yv.z + ea*wc4.z)*al4.z + lrelu(yv.w + ea*wc4.w)*al4.w;
    p += __shfl_xor(p, 1); p += __shfl_xor(p, 2);
    p += __shfl_xor(p, 4); p += __shfl_xor(p, 8);
    float a = lrelu(p + xrn);
    float nm = fmaxf(mg, a);
    sg = sg * __expf(mg - nm) + __expf(a - nm);
    mg = nm;
  }
  // merge 4 group stats
#pragma unroll
  for (int s = 16; s <= 32; s <<= 1){
    float m2 = __shfl_xor(mg, s), s2 = __shfl_xor(sg, s);
    float nm = fmaxf(mg, m2);
    sg = sg * __expf(mg - nm) + s2 * __expf(m2 - nm);
    mg = nm;
  }
  float inv = (i1 > i0 && sg > 0.f) ? 1.f / sg : 0.f;
  // pass 2: recompute h_e and a, accumulate alpha * h_e
  float4 acc = make_float4(0.f, 0.f, 0.f, 0.f);
  for (int i = i0 + sub; i < i1; i += 4){
    int2 rec = csr[i];
    float ea = __int_as_float(rec.y);
    float4 yv = ((const float4*)(y + (size_t)rec.x * 64))[sl];
    float4 he;
    he.x = lrelu(yv.x + ea*wc4.x); he.y = lrelu(yv.y + ea*wc4.y);
    he.z = lrelu(yv.z + ea*wc4.z); he.w = lrelu(yv.w + ea*wc4.w);
    float p = dot4(he, al4);
    p += __shfl_xor(p, 1); p += __shfl_xor(p, 2);
    p += __shfl_xor(p, 4); p += __shfl_xor(p, 8);
    float w = __expf(lrelu(p + xrn) - mg) * inv;
    acc.x += w * he.x; acc.y += w * he.y; acc.z += w * he.z; acc.w += w * he.w;
  }
  acc.x += __shfl_xor(acc.x, 16); acc.y += __shfl_xor(acc.y, 16);
  acc.z += __shfl_xor(acc.z, 16); acc.w += __shfl_xor(acc.w, 16);
  acc.x += __shfl_xor(acc.x, 32); acc.y += __shfl_xor(acc.y, 32);
  acc.z += __shfl_xor(acc.z, 32); acc.w += __shfl_xor(acc.w, 32);
  if (sub == 0) ((float4*)(sout + (size_t)wid * 64))[sl] = acc;
}

// ---------------- GRU1 via MFMA: block = 64 nodes, wave = 16-node M-tile ----------------
__global__ __launch_bounds__(256) void k_gru1m(
    const float* __restrict__ sout, const float* __restrict__ na,
    const float* __restrict__ w1, const float* __restrict__ b1,
    const ushort* __restrict__ wg2f, const float* __restrict__ bg,
    const ushort* __restrict__ wihf, const ushort* __restrict__ whhf,
    const float* __restrict__ bih, const float* __restrict__ bhh,
    float* __restrict__ x2, int N){
  __shared__ ushort xgl[4][16][72];   // per-wave elu(h) tile, bf16, padded rows
  int lane = threadIdx.x & 63;
  int wid  = threadIdx.x >> 6;
  int m = lane & 15, g = lane >> 4;
  int n0 = blockIdx.x * 64 + wid * 16;
  if (n0 >= N) return;                 // no barriers used -> safe early exit
  int rowc = min(n0 + m, N - 1);
  const float* srow = sout + (size_t)rowc * 64;
  bf8 sa0 = pack8(*(const float4*)(srow + g * 8),      *(const float4*)(srow + g * 8 + 4));
  bf8 sa1 = pack8(*(const float4*)(srow + 32 + g * 8), *(const float4*)(srow + 32 + g * 8 + 4));
  const bf8* WG = (const bf8*)wg2f;
  f32x4 h[4];
#pragma unroll
  for (int t = 0; t < 4; t++){
    f32x4 acc = {0.f, 0.f, 0.f, 0.f};
    acc = __builtin_amdgcn_mfma_f32_16x16x32_bf16(sa0, WG[t * 64 + lane], acc, 0, 0, 0);
    acc = __builtin_amdgcn_mfma_f32_16x16x32_bf16(sa1, WG[(4 + t) * 64 + lane], acc, 0, 0, 0);
    h[t] = acc;
  }
#pragma unroll
  for (int t = 0; t < 4; t++){
    float bgc = bg[m + 16 * t];
#pragma unroll
    for (int r = 0; r < 4; r++){
      float hv = h[t][r] + bgc;
      float xg = hv > 0.f ? hv : __expf(hv) - 1.f;
      xgl[wid][g * 4 + r][m + 16 * t] = (ushort)f2bfs(xg);
    }
  }
  float nav = na[rowc];
  bf8 xoa0 = pack8(xo4(nav, *(const float4*)(w1 + g * 8),      *(const float4*)(b1 + g * 8)),
                   xo4(nav, *(const float4*)(w1 + g * 8 + 4),  *(const float4*)(b1 + g * 8 + 4)));
  bf8 xoa1 = pack8(xo4(nav, *(const float4*)(w1 + 32 + g * 8),     *(const float4*)(b1 + 32 + g * 8)),
                   xo4(nav, *(const float4*)(w1 + 32 + g * 8 + 4), *(const float4*)(b1 + 32 + g * 8 + 4)));
  bf8 xga0 = *(const bf8*)&xgl[wid][m][g * 8];
  bf8 xga1 = *(const bf8*)&xgl[wid][m][32 + g * 8];
  const bf8* WI = (const bf8*)wihf;
  const bf8* WH = (const bf8*)whhf;
#pragma unroll
  for (int t = 0; t < 4; t++){
    f32x4 iR = {0.f,0.f,0.f,0.f}, iZ = iR, iN = iR, hR = iR, hZ = iR, hN = iR;
    iR = __builtin_amdgcn_mfma_f32_16x16x32_bf16(xga0, WI[(t     ) * 64 + lane], iR, 0,0,0);
    iR = __builtin_amdgcn_mfma_f32_16x16x32_bf16(xga1, WI[(12 + t) * 64 + lane], iR, 0,0,0);
    iZ = __builtin_amdgcn_mfma_f32_16x16x32_bf16(xga0, WI[(t +  4) * 64 + lane], iZ, 0,0,0);
    iZ = __builtin_amdgcn_mfma_f32_16x16x32_bf16(xga1, WI[(16 + t) * 64 + lane], iZ, 0,0,0);
    iN = __builtin_amdgcn_mfma_f32_16x16x32_bf16(xga0, WI[(t +  8) * 64 + lane], iN, 0,0,0);
    iN = __builtin_amdgcn_mfma_f32_16x16x32_bf16(xga1, WI[(20 + t) * 64 + lane], iN, 0,0,0);
    hR = __builtin_amdgcn_mfma_f32_16x16x32_bf16(xoa0, WH[(t     ) * 64 + lane], hR, 0,0,0);
    hR = __builtin_amdgcn_mfma_f32_16x16x32_bf16(xoa1, WH[(12 + t) * 64 + lane], hR, 0,0,0);
    hZ = __builtin_amdgcn_mfma_f32_16x16x32_bf16(xoa0, WH[(t +  4) * 64 + lane], hZ, 0,0,0);
    hZ = __builtin_amdgcn_mfma_f32_16x16x32_bf16(xoa1, WH[(16 + t) * 64 + lane], hZ, 0,0,0);
    hN = __builtin_amdgcn_mfma_f32_16x16x32_bf16(xoa0, WH[(t +  8) * 64 + lane], hN, 0,0,0);
    hN = __builtin_amdgcn_mfma_f32_16x16x32_bf16(xoa1, WH[(20 + t) * 64 + lane], hN, 0,0,0);
    int col = m + 16 * t;
    float biR = bih[col], biZ = bih[64 + col], biN = bih[128 + col];
    float bhR = bhh[col], bhZ = bhh[64 + col], bhN = bhh[128 + col];
    float w1c = w1[col], b1c = b1[col];
#pragma unroll
    for (int r = 0; r < 4; r++){
      int node = n0 + g * 4 + r;
      if (node < N){
        float xon = lrelu(na[node] * w1c + b1c);
        float rg = 1.f / (1.f + __expf(-(iR[r] + biR + hR[r] + bhR)));
        float zg = 1.f / (1.f + __expf(-(iZ[r] + biZ + hZ[r] + bhZ)));
        float nn = tanhf(iN[r] + biN + rg * (hN[r] + bhN));
        float xn = (1.f - zg) * nn + zg * xon;
        x2[(size_t)node * 64 + col] = fmaxf(xn, 0.f);
      }
    }
  }
}

// ---------------- part2 via MFMA: xs = x2@wm.T (in-place), tb, osum, max(tb) ----------------
__global__ __launch_bounds__(256) void k_part2m(
    float* __restrict__ xb,            // in: x2 rows; out: xs rows (in-place per tile)
    const ushort* __restrict__ wmf, const float* __restrict__ att_src,
    float* __restrict__ tb, float* __restrict__ scal, int N){
  int lane = threadIdx.x & 63;
  int wid  = threadIdx.x >> 6;
  int m = lane & 15, g = lane >> 4;
  const bf8* WM = (const bf8*)wmf;
  float as_t[4];
#pragma unroll
  for (int t = 0; t < 4; t++) as_t[t] = att_src[m + 16 * t];
  float os[16];
#pragma unroll
  for (int j = 0; j < 16; j++) os[j] = 0.f;
  float tmax = -1e30f;
  int ntiles = (N + 15) >> 4;
  for (int tile = blockIdx.x * 4 + wid; tile < ntiles; tile += gridDim.x * 4){
    int n0 = tile * 16;
    int row = n0 + m;
    bool valid = row < N;
    int rowc = valid ? row : (N - 1);
    const float* xrow = xb + (size_t)rowc * 64;
    float4 a0 = *(const float4*)(xrow + g * 8);
    float4 a1 = *(const float4*)(xrow + g * 8 + 4);
    float4 a2 = *(const float4*)(xrow + 32 + g * 8);
    float4 a3 = *(const float4*)(xrow + 32 + g * 8 + 4);
    if (!valid){ a0 = make_float4(0,0,0,0); a1 = a0; a2 = a0; a3 = a0; }
    os[0]+=a0.x; os[1]+=a0.y; os[2]+=a0.z; os[3]+=a0.w;
    os[4]+=a1.x; os[5]+=a1.y; os[6]+=a1.z; os[7]+=a1.w;
    os[8]+=a2.x; os[9]+=a2.y; os[10]+=a2.z; os[11]+=a2.w;
    os[12]+=a3.x; os[13]+=a3.y; os[14]+=a3.z; os[15]+=a3.w;
    bf8 fa0 = pack8(a0, a1), fa1 = pack8(a2, a3);
    f32x4 xs_t[4];
#pragma unroll
    for (int t = 0; t < 4; t++){
      f32x4 acc = {0.f, 0.f, 0.f, 0.f};
      acc = __builtin_amdgcn_mfma_f32_16x16x32_bf16(fa0, WM[t * 64 + lane], acc, 0, 0, 0);
      acc = __builtin_amdgcn_mfma_f32_16x16x32_bf16(fa1, WM[(4 + t) * 64 + lane], acc, 0, 0, 0);
      xs_t[t] = acc;
    }
    float tpart[4] = {0.f, 0.f, 0.f, 0.f};
#pragma unroll
    for (int t = 0; t < 4; t++){
#pragma unroll
      for (int r = 0; r < 4; r++){
        int rw = n0 + g * 4 + r;
        if (rw < N) xb[(size_t)rw * 64 + m + 16 * t] = xs_t[t][r];
        tpart[r] += xs_t[t][r] * as_t[t];
      }
    }
#pragma unroll
    for (int r = 0; r < 4; r++){
      float v = tpart[r];
      v += __shfl_xor(v, 1); v += __shfl_xor(v, 2);
      v += __shfl_xor(v, 4); v += __shfl_xor(v, 8);
      if (m == 0){
        int rw = n0 + g * 4 + r;
        if (rw < N){ tb[rw] = v; tmax = fmaxf(tmax, v); }
      }
    }
  }
  tmax = wave_max(tmax);
  if (lane == 0) atomicMax((unsigned*)(scal + 131), fkey(tmax));
#pragma unroll
  for (int j = 0; j < 16; j++){
    float v = os[j];
    v += __shfl_xor(v, 1); v += __shfl_xor(v, 2);
    v += __shfl_xor(v, 4); v += __shfl_xor(v, 8);
    os[j] = v;
  }
  __shared__ float osm[4][64];
  if (m == 0){
#pragma unroll
    for (int j = 0; j < 8; j++){
      osm[wid][g * 8 + j]      = os[j];
      osm[wid][32 + g * 8 + j] = os[8 + j];
    }
  }
  __syncthreads();
  if (threadIdx.x < 64)
    atomicAdd(&scal[threadIdx.x],
              osm[0][threadIdx.x] + osm[1][threadIdx.x] + osm[2][threadIdx.x] + osm[3][threadIdx.x]);
}

// ---------------- part2b (1 wave) ----------------
__global__ void k_part2b(float* __restrict__ scal, const float* __restrict__ wm_t,
                         const float* __restrict__ att_dst){
  int lane = threadIdx.x;
  float o = fmaxf(scal[lane], 0.f);
  float acc = 0.f;
  for (int k = 0; k < 64; k++) acc += bcast(o, k) * wm_t[k * 64 + lane];
  float c = wave_sum(acc * att_dst[lane]);
  scal[64 + lane] = o;
  if (lane == 0){
    scal[128] = c;
    float maxtb = funkey(*(unsigned*)(scal + 131));
    scal[130] = lrelu(maxtb + c);   // M = max_n lrelu(tb[n]+c)  (lrelu monotone)
  }
}

// ---------------- a2 weighted sums ----------------
__global__ void k_a2sum(const float* __restrict__ tb, const float* __restrict__ xs,
                        float* __restrict__ scal, int N){
  int lane = threadIdx.x & 63, w = threadIdx.x >> 6;
  int gw = blockIdx.x * 4 + w, nw = gridDim.x * 4;
  float c = scal[128];
  float M = scal[130];
  float hloc = 0.f, sloc = 0.f;
  for (int n = gw; n < N; n += nw){
    float a2 = lrelu(tb[n] + c);
    float wt = __expf(a2 - M);
    sloc += wt;
    hloc += wt * xs[(size_t)n * 64 + lane];
  }
  __shared__ float lds[256];
  __shared__ float sred[4];
  lds[threadIdx.x] = hloc;
  if (lane == 0) sred[w] = sloc;
  __syncthreads();
  if (threadIdx.x < 64)
    atomicAdd(&scal[192 + threadIdx.x],
              lds[threadIdx.x] + lds[64 + threadIdx.x] + lds[128 + threadIdx.x] + lds[192 + threadIdx.x]);
  if (threadIdx.x == 0) atomicAdd(&scal[129], sred[0] + sred[1] + sred[2] + sred[3]);
}

// ---------------- final (1 wave, coalesced transposed weights) ----------------
__global__ void k_final(const float* __restrict__ scal, const float* __restrict__ bm,
                        const float* __restrict__ g2ih_t, const float* __restrict__ g2hh_t,
                        const float* __restrict__ bih, const float* __restrict__ bhh,
                        const float* __restrict__ w2_t, const float* __restrict__ b2,
                        float* __restrict__ dout){
  int lane = threadIdx.x;
  float S  = scal[129];
  float h2 = scal[192 + lane] / S + bm[lane];
  float xg = h2 > 0.f ? h2 : __expf(h2) - 1.f;
  float xo = scal[64 + lane];
  float gir = bih[lane], giz = bih[64 + lane], gin = bih[128 + lane];
  float ghr = bhh[lane], ghz = bhh[64 + lane], ghn = bhh[128 + lane];
  for (int k = 0; k < 64; k++){
    float a = bcast(xg, k), b = bcast(xo, k);
    const float* gi = g2ih_t + k * 192;
    const float* gh = g2hh_t + k * 192;
    gir += a * gi[lane]; giz += a * gi[64 + lane]; gin += a * gi[128 + lane];
    ghr += b * gh[lane]; ghz += b * gh[64 + lane]; ghn += b * gh[128 + lane];
  }
  float r  = 1.f / (1.f + __expf(-(gir + ghr)));
  float z  = 1.f / (1.f + __expf(-(giz + ghz)));
  float nn = tanhf(gin + r * ghn);
  float o2 = fmaxf((1.f - z) * nn + z * xo, 0.f);
  float res = 0.f;
  for (int k = 0; k < 64; k++) res += bcast(o2, k) * w2_t[k * 64 + lane];
  dout[lane] = res + b2[lane];
}

extern "C" void kernel_launch(void* const* d_in, const int* in_sizes, int n_in,
                              void* d_out, int out_size, void* d_ws, size_t ws_size,
                              hipStream_t stream){
  const float* na    = (const float*)d_in[0];
  const float* ea    = (const float*)d_in[1];
  const int*   ei    = (const int*)d_in[2];
  const float* w1    = (const float*)d_in[3];
  const float* b1    = (const float*)d_in[4];
  const float* wg1   = (const float*)d_in[5];
  const float* att_l = (const float*)d_in[6];
  const float* att_r = (const float*)d_in[7];
  const float* wg2   = (const float*)d_in[8];
  const float* bg    = (const float*)d_in[9];
  const float* g1wih = (const float*)d_in[10];
  const float* g1whh = (const float*)d_in[11];
  const float* g1bih = (const float*)d_in[12];
  const float* g1bhh = (const float*)d_in[13];
  const float* wm      = (const float*)d_in[14];
  const float* att_src = (const float*)d_in[15];
  const float* att_dst = (const float*)d_in[16];
  const float* bm      = (const float*)d_in[17];
  const float* g2wih = (const float*)d_in[18];
  const float* g2whh = (const float*)d_in[19];
  const float* g2bih = (const float*)d_in[20];
  const float* g2bhh = (const float*)d_in[21];
  const float* w2    = (const float*)d_in[22];
  const float* b2    = (const float*)d_in[23];

  int N = in_sizes[0];
  int E = in_sizes[1];
  const int* srcArr = ei;
  const int* dstArr = ei + E;

  char* ws = (char*)d_ws;
  size_t cur = 0;
  auto alloc = [&](size_t nbytes) -> char* {
    char* p = ws + cur;
    cur += (nbytes + 255) & ~(size_t)255;
    return p;
  };
  float* y     = (float*)alloc((size_t)N * 64 * 4);
  float* bufC  = (float*)alloc((size_t)N * 64 * 4);   // sout -> x2 -> xs
  float* xr    = (float*)alloc((size_t)N * 4);
  float* tb    = (float*)alloc((size_t)N * 4);
  int*   deg   = (int*)alloc((size_t)N * 4);
  int*   offA  = (int*)alloc((size_t)(N + 1) * 4);
  int*   fill  = (int*)alloc((size_t)N * 4);
  int*   part  = (int*)alloc(4096);
  int2*  csr   = (int2*)alloc((size_t)E * 8);
  float* scal  = (float*)alloc(4096);
  float* wm_t  = (float*)alloc(64 * 64 * 4);
  float* w2_t  = (float*)alloc(64 * 64 * 4);
  float* g2ih_t= (float*)alloc(64 * 192 * 4);
  float* g2hh_t= (float*)alloc(64 * 192 * 4);
  float* wgc   = (float*)alloc(64 * 4);
  ushort* wg2f = (ushort*)alloc(4096 * 2);
  ushort* wmf  = (ushort*)alloc(4096 * 2);
  ushort* wg1f = (ushort*)alloc(4096 * 2);
  ushort* wihf = (ushort*)alloc(12288 * 2);
  ushort* whhf = (ushort*)alloc(12288 * 2);
  if (cur > ws_size) return;

  hipMemsetAsync(deg,  0, (size_t)N * 4, stream);
  hipMemsetAsync(scal, 0, 4096, stream);

  k_wprep<<<64, 192, 0, stream>>>(wg1, wm, w2, g2wih, g2whh,
                                  wm_t, w2_t, g2ih_t, g2hh_t, wgc);
  k_wfrag<<<18, 256, 0, stream>>>(wg2, wm, wg1, g1wih, g1whh,
                                  wg2f, wmf, wg1f, wihf, whhf);

  k_node_m<<<512, 256, 0, stream>>>(na, w1, b1, wg1f, att_r, y, xr, N);
  k_deg<<<(E + 255) / 256, 256, 0, stream>>>(dstArr, deg, E);
  int nb = (N + 1023) / 1024;
  k_scan1<<<nb, 1024, 0, stream>>>(deg, part, N);
  k_scan2<<<1, 1024, 0, stream>>>(part, nb, offA, N);
  k_scan3<<<nb, 1024, 0, stream>>>(deg, part, offA, fill, N);
  k_fill<<<(E + 255) / 256, 256, 0, stream>>>(dstArr, srcArr, ea, fill, csr, E);
  int nwb = (N + 3) / 4;           // 4 waves/block, 1 node/wave
  k_edge_f<<<nwb, 256, 0, stream>>>(offA, csr, y, xr, wgc, att_l, bufC, N);
  int ngb = (N + 63) / 64;         // 4 waves/block, 16 nodes/wave (MFMA)
  k_gru1m<<<ngb, 256, 0, stream>>>(bufC, na, w1, b1, wg2f, bg, wihf, whhf,
                                   g1bih, g1bhh, bufC, N);
  k_part2m<<<512, 256, 0, stream>>>(bufC, wmf, att_src, tb, scal, N);
  k_part2b<<<1, 64, 0, stream>>>(scal, wm_t, att_dst);
  k_a2sum<<<512, 256, 0, stream>>>(tb, bufC, scal, N);
  k_final<<<1, 64, 0, stream>>>(scal, bm, g2ih_t, g2hh_t, g2bih, g2bhh, w2_t, b2, (float*)d_out);
  (void)n_in; (void)out_size;
}

// Round 9
// 381.747 us; speedup vs baseline: 5.1409x; 1.1258x over previous
//
#include <hip/hip_runtime.h>
#include <math.h>

typedef __attribute__((ext_vector_type(8))) short bf8;
typedef __attribute__((ext_vector_type(4))) float f32x4;

__device__ __forceinline__ float lrelu(float v){ return v > 0.f ? v : 0.01f * v; }

__device__ __forceinline__ float wave_sum(float v){
#pragma unroll
  for (int s = 32; s > 0; s >>= 1) v += __shfl_xor(v, s);
  return v;
}
__device__ __forceinline__ float wave_max(float v){
#pragma unroll
  for (int s = 32; s > 0; s >>= 1) v = fmaxf(v, __shfl_xor(v, s));
  return v;
}

__device__ __forceinline__ float bcast(float v, int k){
  return __uint_as_float((unsigned)__builtin_amdgcn_readlane(__float_as_uint(v), k));
}

// float -> orderable unsigned key (monotone)
__device__ __forceinline__ unsigned fkey(float x){
  unsigned u = __float_as_uint(x);
  return (u & 0x80000000u) ? ~u : (u | 0x80000000u);
}
__device__ __forceinline__ float funkey(unsigned k){
  unsigned u = (k & 0x80000000u) ? (k & 0x7fffffffu) : ~k;
  return __uint_as_float(u);
}

// float -> bf16 (RNE)
__device__ __forceinline__ short f2bfs(float x){
  unsigned u = __float_as_uint(x);
  return (short)((u + 0x7fffu + ((u >> 16) & 1u)) >> 16);
}
__device__ __forceinline__ float bf2f(ushort v){
  return __uint_as_float((unsigned)v << 16);
}
__device__ __forceinline__ bf8 pack8(float4 a, float4 b){
  bf8 v;
  v[0]=f2bfs(a.x); v[1]=f2bfs(a.y); v[2]=f2bfs(a.z); v[3]=f2bfs(a.w);
  v[4]=f2bfs(b.x); v[5]=f2bfs(b.y); v[6]=f2bfs(b.z); v[7]=f2bfs(b.w);
  return v;
}
__device__ __forceinline__ float4 xo4(float nav, float4 w, float4 b){
  float4 r;
  r.x = lrelu(nav*w.x + b.x); r.y = lrelu(nav*w.y + b.y);
  r.z = lrelu(nav*w.z + b.z); r.w = lrelu(nav*w.w + b.w);
  return r;
}
__device__ __forceinline__ float dot4(float4 a, float4 b){
  return a.x*b.x + a.y*b.y + a.z*b.z + a.w*b.w;
}

// ---------------- weight transpose to k-major (small weights for 1-wave kernels) ----------------
__global__ void k_wprep(const float* __restrict__ wg1, const float* __restrict__ wm,
                        const float* __restrict__ w2,
                        const float* __restrict__ g2wih, const float* __restrict__ g2whh,
                        float* __restrict__ wm_t, float* __restrict__ w2_t,
                        float* __restrict__ g2ih_t, float* __restrict__ g2hh_t,
                        float* __restrict__ wgc){
  int k = blockIdx.x;      // 0..63
  int r = threadIdx.x;     // 0..191
  if (r < 64){
    wm_t [k * 64 + r] = wm [r * 64 + k];
    w2_t [k * 64 + r] = w2 [r * 64 + k];
    if (k == 0) wgc[r] = wg1[r * 65 + 64];
  }
  g2ih_t[k * 192 + r] = g2wih[r * 64 + k];
  g2hh_t[k * 192 + r] = g2whh[r * 64 + k];
}

// ---------------- pack weights into bf16 MFMA B-fragments ----------------
// B-frag slot (c, t, lane l, j) <- W[16t + (l&15)][32c + (l>>4)*8 + j], row stride S
__global__ void k_wfrag(const float* __restrict__ wg2, const float* __restrict__ wm,
                        const float* __restrict__ wg1,
                        const float* __restrict__ wih, const float* __restrict__ whh,
                        ushort* __restrict__ wg2f, ushort* __restrict__ wmf,
                        ushort* __restrict__ wg1f,
                        ushort* __restrict__ wihf, ushort* __restrict__ whhf){
  int tid = blockIdx.x * 256 + threadIdx.x;  // 0..4607
  if (tid >= 4608) return;
  const float* W; ushort* F; int T, S, base;
  if (tid < 512)      { W = wg2; F = wg2f; T = 4;  S = 64; base = tid; }
  else if (tid < 1024){ W = wm;  F = wmf;  T = 4;  S = 64; base = tid - 1024 + 512; }
  else if (tid < 1536){ W = wg1; F = wg1f; T = 4;  S = 65; base = tid - 1024; }
  else if (tid < 3072){ W = wih; F = wihf; T = 12; S = 64; base = tid - 1536; }
  else                { W = whh; F = whhf; T = 12; S = 64; base = tid - 3072; }
  int l  = base & 63;
  int ct = base >> 6;
  int c  = ct / T, t = ct - c * T;
  int row = 16 * t + (l & 15);
  int k0  = 32 * c + (l >> 4) * 8;
  const float* src = W + row * S + k0;
  unsigned o0 = (unsigned)(ushort)f2bfs(src[0]) | ((unsigned)(ushort)f2bfs(src[1]) << 16);
  unsigned o1 = (unsigned)(ushort)f2bfs(src[2]) | ((unsigned)(ushort)f2bfs(src[3]) << 16);
  unsigned o2 = (unsigned)(ushort)f2bfs(src[4]) | ((unsigned)(ushort)f2bfs(src[5]) << 16);
  unsigned o3 = (unsigned)(ushort)f2bfs(src[6]) | ((unsigned)(ushort)f2bfs(src[7]) << 16);
  ((uint4*)F)[base] = make_uint4(o0, o1, o2, o3);
}

// ---------------- node prep via MFMA: y(bf16) = x@wg1[:,:64].T, xr = dot(x, att_r) ----------------
__global__ __launch_bounds__(256) void k_node_m(
    const float* __restrict__ na, const float* __restrict__ w1,
    const float* __restrict__ b1, const ushort* __restrict__ wg1f,
    const float* __restrict__ att_r,
    ushort* __restrict__ yb, float* __restrict__ xr, int N){
  int lane = threadIdx.x & 63;
  int wid  = threadIdx.x >> 6;
  int m = lane & 15, g = lane >> 4;
  const bf8* WG = (const bf8*)wg1f;
  float4 w1a = *(const float4*)(w1 + g*8),      w1b = *(const float4*)(w1 + g*8 + 4);
  float4 w1c = *(const float4*)(w1 + 32 + g*8), w1d = *(const float4*)(w1 + 32 + g*8 + 4);
  float4 b1a = *(const float4*)(b1 + g*8),      b1b = *(const float4*)(b1 + g*8 + 4);
  float4 b1c = *(const float4*)(b1 + 32 + g*8), b1d = *(const float4*)(b1 + 32 + g*8 + 4);
  float4 ara = *(const float4*)(att_r + g*8),      arb = *(const float4*)(att_r + g*8 + 4);
  float4 arc = *(const float4*)(att_r + 32 + g*8), ard = *(const float4*)(att_r + 32 + g*8 + 4);
  int ntiles = (N + 15) >> 4;
  for (int tile = blockIdx.x * 4 + wid; tile < ntiles; tile += gridDim.x * 4){
    int n0 = tile * 16;
    int row = n0 + m;
    bool valid = row < N;
    float nav = valid ? na[row] : 0.f;
    float4 x0 = xo4(nav, w1a, b1a), x1 = xo4(nav, w1b, b1b);
    float4 x2 = xo4(nav, w1c, b1c), x3 = xo4(nav, w1d, b1d);
    float xa = dot4(x0, ara) + dot4(x1, arb) + dot4(x2, arc) + dot4(x3, ard);
    xa += __shfl_xor(xa, 16); xa += __shfl_xor(xa, 32);
    if (g == 0 && valid) xr[row] = xa;
    bf8 fa0 = pack8(x0, x1), fa1 = pack8(x2, x3);
    f32x4 yt[4];
#pragma unroll
    for (int t = 0; t < 4; t++){
      f32x4 acc = {0.f, 0.f, 0.f, 0.f};
      acc = __builtin_amdgcn_mfma_f32_16x16x32_bf16(fa0, WG[t * 64 + lane], acc, 0, 0, 0);
      acc = __builtin_amdgcn_mfma_f32_16x16x32_bf16(fa1, WG[(4 + t) * 64 + lane], acc, 0, 0, 0);
      yt[t] = acc;
    }
#pragma unroll
    for (int t = 0; t < 4; t++){
#pragma unroll
      for (int r = 0; r < 4; r++){
        int rw = n0 + g * 4 + r;
        if (rw < N) yb[(size_t)rw * 64 + m + 16 * t] = (ushort)f2bfs(yt[t][r]);
      }
    }
  }
}

// ---------------- CSR build ----------------
__global__ void k_deg(const int* __restrict__ dst, int* __restrict__ deg, int E){
  int e = blockIdx.x * 256 + threadIdx.x;
  if (e >= E) return;
  atomicAdd(&deg[dst[e]], 1);
}

__global__ void k_scan1(const int* __restrict__ deg, int* __restrict__ partial, int N){
  __shared__ int lds[1024];
  int gid = blockIdx.x * 1024 + threadIdx.x;
  lds[threadIdx.x] = (gid < N) ? deg[gid] : 0;
  __syncthreads();
  for (int s = 512; s > 0; s >>= 1){
    if (threadIdx.x < s) lds[threadIdx.x] += lds[threadIdx.x + s];
    __syncthreads();
  }
  if (threadIdx.x == 0) partial[blockIdx.x] = lds[0];
}

__global__ void k_scan2(int* __restrict__ partial, int nb, int* __restrict__ off, int N){
  __shared__ int lds[1024];
  int t = threadIdx.x;
  int v = (t < nb) ? partial[t] : 0;
  lds[t] = v;
  __syncthreads();
  for (int s = 1; s < 1024; s <<= 1){
    int tv = (t >= s) ? lds[t - s] : 0;
    __syncthreads();
    lds[t] += tv;
    __syncthreads();
  }
  if (t < nb) partial[t] = lds[t] - v;    // exclusive prefix
  if (t == 1023) off[N] = lds[1023];      // total = E
}

__global__ void k_scan3(const int* __restrict__ deg, const int* __restrict__ partial,
                        int* __restrict__ off, int* __restrict__ fill, int N){
  __shared__ int lds[1024];
  int gid = blockIdx.x * 1024 + threadIdx.x;
  int v = (gid < N) ? deg[gid] : 0;
  lds[threadIdx.x] = v;
  __syncthreads();
  for (int s = 1; s < 1024; s <<= 1){
    int t = (threadIdx.x >= s) ? lds[threadIdx.x - s] : 0;
    __syncthreads();
    lds[threadIdx.x] += t;
    __syncthreads();
  }
  if (gid < N){
    int excl = partial[blockIdx.x] + lds[threadIdx.x] - v;
    off[gid] = excl;
    fill[gid] = excl;
  }
}

// single 8 B scattered record per edge: {src, ea-bits}
__global__ void k_fill(const int* __restrict__ dst, const int* __restrict__ src,
                       const float* __restrict__ ea, int* __restrict__ fill,
                       int2* __restrict__ csr, int E){
  int e = blockIdx.x * 256 + threadIdx.x;
  if (e >= E) return;
  int d = dst[e];
  int pos = atomicAdd(&fill[d], 1);
  csr[pos] = make_int2(src[e], __float_as_int(ea[e]));
}

// ---------------- fused edge kernel, SINGLE PASS (flash-style online softmax)
// wave per node; 4 groups of 16 lanes, each group owns every 4th edge; lane holds 4 dims
__global__ void k_edge_f(const int* __restrict__ off, const int2* __restrict__ csr,
                         const ushort* __restrict__ yb, const float* __restrict__ xr,
                         const float* __restrict__ wgc, const float* __restrict__ att_l,
                         float* __restrict__ sout, int N){
  int lane = threadIdx.x & 63;
  int wid  = (blockIdx.x * blockDim.x + threadIdx.x) >> 6;
  if (wid >= N) return;
  int i0 = off[wid], i1 = off[wid + 1];
  int sub = lane >> 4, sl = lane & 15;
  float4 wc4 = ((const float4*)wgc)[sl];
  float4 al4 = ((const float4*)att_l)[sl];
  float xrn = xr[wid];
  float m = -1e30f, sg = 0.f;
  float4 acc = make_float4(0.f, 0.f, 0.f, 0.f);
  for (int i = i0 + sub; i < i1; i += 4){
    int2 rec = csr[i];
    float ea = __int_as_float(rec.y);
    ushort4 yv16 = ((const ushort4*)(yb + (size_t)rec.x * 64))[sl];
    float4 he;
    he.x = lrelu(bf2f(yv16.x) + ea*wc4.x);
    he.y = lrelu(bf2f(yv16.y) + ea*wc4.y);
    he.z = lrelu(bf2f(yv16.z) + ea*wc4.z);
    he.w = lrelu(bf2f(yv16.w) + ea*wc4.w);
    float p = dot4(he, al4);
    p += __shfl_xor(p, 1); p += __shfl_xor(p, 2);
    p += __shfl_xor(p, 4); p += __shfl_xor(p, 8);
    float a = lrelu(p + xrn);
    float nm = fmaxf(m, a);
    float sc = __expf(m - nm);
    float w  = __expf(a - nm);
    sg = sg * sc + w;
    acc.x = acc.x*sc + w*he.x; acc.y = acc.y*sc + w*he.y;
    acc.z = acc.z*sc + w*he.z; acc.w = acc.w*sc + w*he.w;
    m = nm;
  }
  // merge the 4 group states (m, s, acc)
#pragma unroll
  for (int st = 16; st <= 32; st <<= 1){
    float m2 = __shfl_xor(m, st);
    float s2 = __shfl_xor(sg, st);
    float ax = __shfl_xor(acc.x, st), ay = __shfl_xor(acc.y, st);
    float az = __shfl_xor(acc.z, st), aw = __shfl_xor(acc.w, st);
    float nm = fmaxf(m, m2);
    float c1 = __expf(m - nm), c2 = __expf(m2 - nm);
    sg = sg * c1 + s2 * c2;
    acc.x = acc.x*c1 + ax*c2; acc.y = acc.y*c1 + ay*c2;
    acc.z = acc.z*c1 + az*c2; acc.w = acc.w*c1 + aw*c2;
    m = nm;
  }
  float inv = (i1 > i0 && sg > 0.f) ? 1.f / sg : 0.f;
  acc.x *= inv; acc.y *= inv; acc.z *= inv; acc.w *= inv;
  if (sub == 0) ((float4*)(sout + (size_t)wid * 64))[sl] = acc;
}

// ---------------- GRU1 via MFMA: block = 64 nodes, wave = 16-node M-tile ----------------
__global__ __launch_bounds__(256) void k_gru1m(
    const float* __restrict__ sout, const float* __restrict__ na,
    const float* __restrict__ w1, const float* __restrict__ b1,
    const ushort* __restrict__ wg2f, const float* __restrict__ bg,
    const ushort* __restrict__ wihf, const ushort* __restrict__ whhf,
    const float* __restrict__ bih, const float* __restrict__ bhh,
    float* __restrict__ x2, int N){
  __shared__ ushort xgl[4][16][72];   // per-wave elu(h) tile, bf16, padded rows
  int lane = threadIdx.x & 63;
  int wid  = threadIdx.x >> 6;
  int m = lane & 15, g = lane >> 4;
  int n0 = blockIdx.x * 64 + wid * 16;
  if (n0 >= N) return;                 // no barriers used -> safe early exit
  int rowc = min(n0 + m, N - 1);
  const float* srow = sout + (size_t)rowc * 64;
  bf8 sa0 = pack8(*(const float4*)(srow + g * 8),      *(const float4*)(srow + g * 8 + 4));
  bf8 sa1 = pack8(*(const float4*)(srow + 32 + g * 8), *(const float4*)(srow + 32 + g * 8 + 4));
  const bf8* WG = (const bf8*)wg2f;
  f32x4 h[4];
#pragma unroll
  for (int t = 0; t < 4; t++){
    f32x4 acc = {0.f, 0.f, 0.f, 0.f};
    acc = __builtin_amdgcn_mfma_f32_16x16x32_bf16(sa0, WG[t * 64 + lane], acc, 0, 0, 0);
    acc = __builtin_amdgcn_mfma_f32_16x16x32_bf16(sa1, WG[(4 + t) * 64 + lane], acc, 0, 0, 0);
    h[t] = acc;
  }
#pragma unroll
  for (int t = 0; t < 4; t++){
    float bgc = bg[m + 16 * t];
#pragma unroll
    for (int r = 0; r < 4; r++){
      float hv = h[t][r] + bgc;
      float xg = hv > 0.f ? hv : __expf(hv) - 1.f;
      xgl[wid][g * 4 + r][m + 16 * t] = (ushort)f2bfs(xg);
    }
  }
  float nav = na[rowc];
  bf8 xoa0 = pack8(xo4(nav, *(const float4*)(w1 + g * 8),      *(const float4*)(b1 + g * 8)),
                   xo4(nav, *(const float4*)(w1 + g * 8 + 4),  *(const float4*)(b1 + g * 8 + 4)));
  bf8 xoa1 = pack8(xo4(nav, *(const float4*)(w1 + 32 + g * 8),     *(const float4*)(b1 + 32 + g * 8)),
                   xo4(nav, *(const float4*)(w1 + 32 + g * 8 + 4), *(const float4*)(b1 + 32 + g * 8 + 4)));
  bf8 xga0 = *(const bf8*)&xgl[wid][m][g * 8];
  bf8 xga1 = *(const bf8*)&xgl[wid][m][32 + g * 8];
  const bf8* WI = (const bf8*)wihf;
  const bf8* WH = (const bf8*)whhf;
#pragma unroll
  for (int t = 0; t < 4; t++){
    f32x4 iR = {0.f,0.f,0.f,0.f}, iZ = iR, iN = iR, hR = iR, hZ = iR, hN = iR;
    iR = __builtin_amdgcn_mfma_f32_16x16x32_bf16(xga0, WI[(t     ) * 64 + lane], iR, 0,0,0);
    iR = __builtin_amdgcn_mfma_f32_16x16x32_bf16(xga1, WI[(12 + t) * 64 + lane], iR, 0,0,0);
    iZ = __builtin_amdgcn_mfma_f32_16x16x32_bf16(xga0, WI[(t +  4) * 64 + lane], iZ, 0,0,0);
    iZ = __builtin_amdgcn_mfma_f32_16x16x32_bf16(xga1, WI[(16 + t) * 64 + lane], iZ, 0,0,0);
    iN = __builtin_amdgcn_mfma_f32_16x16x32_bf16(xga0, WI[(t +  8) * 64 + lane], iN, 0,0,0);
    iN = __builtin_amdgcn_mfma_f32_16x16x32_bf16(xga1, WI[(20 + t) * 64 + lane], iN, 0,0,0);
    hR = __builtin_amdgcn_mfma_f32_16x16x32_bf16(xoa0, WH[(t     ) * 64 + lane], hR, 0,0,0);
    hR = __builtin_amdgcn_mfma_f32_16x16x32_bf16(xoa1, WH[(12 + t) * 64 + lane], hR, 0,0,0);
    hZ = __builtin_amdgcn_mfma_f32_16x16x32_bf16(xoa0, WH[(t +  4) * 64 + lane], hZ, 0,0,0);
    hZ = __builtin_amdgcn_mfma_f32_16x16x32_bf16(xoa1, WH[(16 + t) * 64 + lane], hZ, 0,0,0);
    hN = __builtin_amdgcn_mfma_f32_16x16x32_bf16(xoa0, WH[(t +  8) * 64 + lane], hN, 0,0,0);
    hN = __builtin_amdgcn_mfma_f32_16x16x32_bf16(xoa1, WH[(20 + t) * 64 + lane], hN, 0,0,0);
    int col = m + 16 * t;
    float biR = bih[col], biZ = bih[64 + col], biN = bih[128 + col];
    float bhR = bhh[col], bhZ = bhh[64 + col], bhN = bhh[128 + col];
    float w1c = w1[col], b1c = b1[col];
#pragma unroll
    for (int r = 0; r < 4; r++){
      int node = n0 + g * 4 + r;
      if (node < N){
        float xon = lrelu(na[node] * w1c + b1c);
        float rg = 1.f / (1.f + __expf(-(iR[r] + biR + hR[r] + bhR)));
        float zg = 1.f / (1.f + __expf(-(iZ[r] + biZ + hZ[r] + bhZ)));
        float nn = tanhf(iN[r] + biN + rg * (hN[r] + bhN));
        float xn = (1.f - zg) * nn + zg * xon;
        x2[(size_t)node * 64 + col] = fmaxf(xn, 0.f);
      }
    }
  }
}

// ---------------- part2 via MFMA: xs = x2@wm.T (in-place), tb, osum, max(tb) ----------------
__global__ __launch_bounds__(256) void k_part2m(
    float* __restrict__ xb,            // in: x2 rows; out: xs rows (in-place per tile)
    const ushort* __restrict__ wmf, const float* __restrict__ att_src,
    float* __restrict__ tb, float* __restrict__ scal, int N){
  int lane = threadIdx.x & 63;
  int wid  = threadIdx.x >> 6;
  int m = lane & 15, g = lane >> 4;
  const bf8* WM = (const bf8*)wmf;
  float as_t[4];
#pragma unroll
  for (int t = 0; t < 4; t++) as_t[t] = att_src[m + 16 * t];
  float os[16];
#pragma unroll
  for (int j = 0; j < 16; j++) os[j] = 0.f;
  float tmax = -1e30f;
  int ntiles = (N + 15) >> 4;
  for (int tile = blockIdx.x * 4 + wid; tile < ntiles; tile += gridDim.x * 4){
    int n0 = tile * 16;
    int row = n0 + m;
    bool valid = row < N;
    int rowc = valid ? row : (N - 1);
    const float* xrow = xb + (size_t)rowc * 64;
    float4 a0 = *(const float4*)(xrow + g * 8);
    float4 a1 = *(const float4*)(xrow + g * 8 + 4);
    float4 a2 = *(const float4*)(xrow + 32 + g * 8);
    float4 a3 = *(const float4*)(xrow + 32 + g * 8 + 4);
    if (!valid){ a0 = make_float4(0,0,0,0); a1 = a0; a2 = a0; a3 = a0; }
    os[0]+=a0.x; os[1]+=a0.y; os[2]+=a0.z; os[3]+=a0.w;
    os[4]+=a1.x; os[5]+=a1.y; os[6]+=a1.z; os[7]+=a1.w;
    os[8]+=a2.x; os[9]+=a2.y; os[10]+=a2.z; os[11]+=a2.w;
    os[12]+=a3.x; os[13]+=a3.y; os[14]+=a3.z; os[15]+=a3.w;
    bf8 fa0 = pack8(a0, a1), fa1 = pack8(a2, a3);
    f32x4 xs_t[4];
#pragma unroll
    for (int t = 0; t < 4; t++){
      f32x4 acc = {0.f, 0.f, 0.f, 0.f};
      acc = __builtin_amdgcn_mfma_f32_16x16x32_bf16(fa0, WM[t * 64 + lane], acc, 0, 0, 0);
      acc = __builtin_amdgcn_mfma_f32_16x16x32_bf16(fa1, WM[(4 + t) * 64 + lane], acc, 0, 0, 0);
      xs_t[t] = acc;
    }
    float tpart[4] = {0.f, 0.f, 0.f, 0.f};
#pragma unroll
    for (int t = 0; t < 4; t++){
#pragma unroll
      for (int r = 0; r < 4; r++){
        int rw = n0 + g * 4 + r;
        if (rw < N) xb[(size_t)rw * 64 + m + 16 * t] = xs_t[t][r];
        tpart[r] += xs_t[t][r] * as_t[t];
      }
    }
#pragma unroll
    for (int r = 0; r < 4; r++){
      float v = tpart[r];
      v += __shfl_xor(v, 1); v += __shfl_xor(v, 2);
      v += __shfl_xor(v, 4); v += __shfl_xor(v, 8);
      if (m == 0){
        int rw = n0 + g * 4 + r;
        if (rw < N){ tb[rw] = v; tmax = fmaxf(tmax, v); }
      }
    }
  }
  tmax = wave_max(tmax);
  if (lane == 0) atomicMax((unsigned*)(scal + 131), fkey(tmax));
#pragma unroll
  for (int j = 0; j < 16; j++){
    float v = os[j];
    v += __shfl_xor(v, 1); v += __shfl_xor(v, 2);
    v += __shfl_xor(v, 4); v += __shfl_xor(v, 8);
    os[j] = v;
  }
  __shared__ float osm[4][64];
  if (m == 0){
#pragma unroll
    for (int j = 0; j < 8; j++){
      osm[wid][g * 8 + j]      = os[j];
      osm[wid][32 + g * 8 + j] = os[8 + j];
    }
  }
  __syncthreads();
  if (threadIdx.x < 64)
    atomicAdd(&scal[threadIdx.x],
              osm[0][threadIdx.x] + osm[1][threadIdx.x] + osm[2][threadIdx.x] + osm[3][threadIdx.x]);
}

// ---------------- part2b (1 wave) ----------------
__global__ void k_part2b(float* __restrict__ scal, const float* __restrict__ wm_t,
                         const float* __restrict__ att_dst){
  int lane = threadIdx.x;
  float o = fmaxf(scal[lane], 0.f);
  float acc = 0.f;
  for (int k = 0; k < 64; k++) acc += bcast(o, k) * wm_t[k * 64 + lane];
  float c = wave_sum(acc * att_dst[lane]);
  scal[64 + lane] = o;
  if (lane == 0){
    scal[128] = c;
    float maxtb = funkey(*(unsigned*)(scal + 131));
    scal[130] = lrelu(maxtb + c);   // M = max_n lrelu(tb[n]+c)  (lrelu monotone)
  }
}

// ---------------- a2 weighted sums ----------------
__global__ void k_a2sum(const float* __restrict__ tb, const float* __restrict__ xs,
                        float* __restrict__ scal, int N){
  int lane = threadIdx.x & 63, w = threadIdx.x >> 6;
  int gw = blockIdx.x * 4 + w, nw = gridDim.x * 4;
  float c = scal[128];
  float M = scal[130];
  float hloc = 0.f, sloc = 0.f;
  for (int n = gw; n < N; n += nw){
    float a2 = lrelu(tb[n] + c);
    float wt = __expf(a2 - M);
    sloc += wt;
    hloc += wt * xs[(size_t)n * 64 + lane];
  }
  __shared__ float lds[256];
  __shared__ float sred[4];
  lds[threadIdx.x] = hloc;
  if (lane == 0) sred[w] = sloc;
  __syncthreads();
  if (threadIdx.x < 64)
    atomicAdd(&scal[192 + threadIdx.x],
              lds[threadIdx.x] + lds[64 + threadIdx.x] + lds[128 + threadIdx.x] + lds[192 + threadIdx.x]);
  if (threadIdx.x == 0) atomicAdd(&scal[129], sred[0] + sred[1] + sred[2] + sred[3]);
}

// ---------------- final (1 wave, coalesced transposed weights) ----------------
__global__ void k_final(const float* __restrict__ scal, const float* __restrict__ bm,
                        const float* __restrict__ g2ih_t, const float* __restrict__ g2hh_t,
                        const float* __restrict__ bih, const float* __restrict__ bhh,
                        const float* __restrict__ w2_t, const float* __restrict__ b2,
                        float* __restrict__ dout){
  int lane = threadIdx.x;
  float S  = scal[129];
  float h2 = scal[192 + lane] / S + bm[lane];
  float xg = h2 > 0.f ? h2 : __expf(h2) - 1.f;
  float xo = scal[64 + lane];
  float gir = bih[lane], giz = bih[64 + lane], gin = bih[128 + lane];
  float ghr = bhh[lane], ghz = bhh[64 + lane], ghn = bhh[128 + lane];
  for (int k = 0; k < 64; k++){
    float a = bcast(xg, k), b = bcast(xo, k);
    const float* gi = g2ih_t + k * 192;
    const float* gh = g2hh_t + k * 192;
    gir += a * gi[lane]; giz += a * gi[64 + lane]; gin += a * gi[128 + lane];
    ghr += b * gh[lane]; ghz += b * gh[64 + lane]; ghn += b * gh[128 + lane];
  }
  float r  = 1.f / (1.f + __expf(-(gir + ghr)));
  float z  = 1.f / (1.f + __expf(-(giz + ghz)));
  float nn = tanhf(gin + r * ghn);
  float o2 = fmaxf((1.f - z) * nn + z * xo, 0.f);
  float res = 0.f;
  for (int k = 0; k < 64; k++) res += bcast(o2, k) * w2_t[k * 64 + lane];
  dout[lane] = res + b2[lane];
}

extern "C" void kernel_launch(void* const* d_in, const int* in_sizes, int n_in,
                              void* d_out, int out_size, void* d_ws, size_t ws_size,
                              hipStream_t stream){
  const float* na    = (const float*)d_in[0];
  const float* ea    = (const float*)d_in[1];
  const int*   ei    = (const int*)d_in[2];
  const float* w1    = (const float*)d_in[3];
  const float* b1    = (const float*)d_in[4];
  const float* wg1   = (const float*)d_in[5];
  const float* att_l = (const float*)d_in[6];
  const float* att_r = (const float*)d_in[7];
  const float* wg2   = (const float*)d_in[8];
  const float* bg    = (const float*)d_in[9];
  const float* g1wih = (const float*)d_in[10];
  const float* g1whh = (const float*)d_in[11];
  const float* g1bih = (const float*)d_in[12];
  const float* g1bhh = (const float*)d_in[13];
  const float* wm      = (const float*)d_in[14];
  const float* att_src = (const float*)d_in[15];
  const float* att_dst = (const float*)d_in[16];
  const float* bm      = (const float*)d_in[17];
  const float* g2wih = (const float*)d_in[18];
  const float* g2whh = (const float*)d_in[19];
  const float* g2bih = (const float*)d_in[20];
  const float* g2bhh = (const float*)d_in[21];
  const float* w2    = (const float*)d_in[22];
  const float* b2    = (const float*)d_in[23];

  int N = in_sizes[0];
  int E = in_sizes[1];
  const int* srcArr = ei;
  const int* dstArr = ei + E;

  char* ws = (char*)d_ws;
  size_t cur = 0;
  auto alloc = [&](size_t nbytes) -> char* {
    char* p = ws + cur;
    cur += (nbytes + 255) & ~(size_t)255;
    return p;
  };
  ushort* yb   = (ushort*)alloc((size_t)N * 64 * 2);   // bf16 y
  float* bufC  = (float*)alloc((size_t)N * 64 * 4);    // sout -> x2 -> xs
  float* xr    = (float*)alloc((size_t)N * 4);
  float* tb    = (float*)alloc((size_t)N * 4);
  int*   deg   = (int*)alloc((size_t)N * 4);
  int*   offA  = (int*)alloc((size_t)(N + 1) * 4);
  int*   fill  = (int*)alloc((size_t)N * 4);
  int*   part  = (int*)alloc(4096);
  int2*  csr   = (int2*)alloc((size_t)E * 8);
  float* scal  = (float*)alloc(4096);
  float* wm_t  = (float*)alloc(64 * 64 * 4);
  float* w2_t  = (float*)alloc(64 * 64 * 4);
  float* g2ih_t= (float*)alloc(64 * 192 * 4);
  float* g2hh_t= (float*)alloc(64 * 192 * 4);
  float* wgc   = (float*)alloc(64 * 4);
  ushort* wg2f = (ushort*)alloc(4096 * 2);
  ushort* wmf  = (ushort*)alloc(4096 * 2);
  ushort* wg1f = (ushort*)alloc(4096 * 2);
  ushort* wihf = (ushort*)alloc(12288 * 2);
  ushort* whhf = (ushort*)alloc(12288 * 2);
  if (cur > ws_size) return;

  hipMemsetAsync(deg,  0, (size_t)N * 4, stream);
  hipMemsetAsync(scal, 0, 4096, stream);

  k_wprep<<<64, 192, 0, stream>>>(wg1, wm, w2, g2wih, g2whh,
                                  wm_t, w2_t, g2ih_t, g2hh_t, wgc);
  k_wfrag<<<18, 256, 0, stream>>>(wg2, wm, wg1, g1wih, g1whh,
                                  wg2f, wmf, wg1f, wihf, whhf);

  k_node_m<<<512, 256, 0, stream>>>(na, w1, b1, wg1f, att_r, yb, xr, N);
  k_deg<<<(E + 255) / 256, 256, 0, stream>>>(dstArr, deg, E);
  int nb = (N + 1023) / 1024;
  k_scan1<<<nb, 1024, 0, stream>>>(deg, part, N);
  k_scan2<<<1, 1024, 0, stream>>>(part, nb, offA, N);
  k_scan3<<<nb, 1024, 0, stream>>>(deg, part, offA, fill, N);
  k_fill<<<(E + 255) / 256, 256, 0, stream>>>(dstArr, srcArr, ea, fill, csr, E);
  int nwb = (N + 3) / 4;           // 4 waves/block, 1 node/wave
  k_edge_f<<<nwb, 256, 0, stream>>>(offA, csr, yb, xr, wgc, att_l, bufC, N);
  int ngb = (N + 63) / 64;         // 4 waves/block, 16 nodes/wave (MFMA)
  k_gru1m<<<ngb, 256, 0, stream>>>(bufC, na, w1, b1, wg2f, bg, wihf, whhf,
                                   g1bih, g1bhh, bufC, N);
  k_part2m<<<512, 256, 0, stream>>>(bufC, wmf, att_src, tb, scal, N);
  k_part2b<<<1, 64, 0, stream>>>(scal, wm_t, att_dst);
  k_a2sum<<<512, 256, 0, stream>>>(tb, bufC, scal, N);
  k_final<<<1, 64, 0, stream>>>(scal, bm, g2ih_t, g2hh_t, g2bih, g2bhh, w2_t, b2, (float*)d_out);
  (void)n_in; (void)out_size;
}

// Round 10
// 326.167 us; speedup vs baseline: 6.0169x; 1.1704x over previous
//
#include <hip/hip_runtime.h>
#include <math.h>

typedef __attribute__((ext_vector_type(8))) short bf8;
typedef __attribute__((ext_vector_type(4))) float f32x4;

#define BSHIFT 9   // 512 nodes per bucket

__device__ __forceinline__ float lrelu(float v){ return v > 0.f ? v : 0.01f * v; }

__device__ __forceinline__ float wave_sum(float v){
#pragma unroll
  for (int s = 32; s > 0; s >>= 1) v += __shfl_xor(v, s);
  return v;
}
__device__ __forceinline__ float wave_max(float v){
#pragma unroll
  for (int s = 32; s > 0; s >>= 1) v = fmaxf(v, __shfl_xor(v, s));
  return v;
}

__device__ __forceinline__ float bcast(float v, int k){
  return __uint_as_float((unsigned)__builtin_amdgcn_readlane(__float_as_uint(v), k));
}

// float -> orderable unsigned key (monotone)
__device__ __forceinline__ unsigned fkey(float x){
  unsigned u = __float_as_uint(x);
  return (u & 0x80000000u) ? ~u : (u | 0x80000000u);
}
__device__ __forceinline__ float funkey(unsigned k){
  unsigned u = (k & 0x80000000u) ? (k & 0x7fffffffu) : ~k;
  return __uint_as_float(u);
}

// float -> bf16 (RNE)
__device__ __forceinline__ short f2bfs(float x){
  unsigned u = __float_as_uint(x);
  return (short)((u + 0x7fffu + ((u >> 16) & 1u)) >> 16);
}
__device__ __forceinline__ float bf2f(ushort v){
  return __uint_as_float((unsigned)v << 16);
}
__device__ __forceinline__ bf8 pack8(float4 a, float4 b){
  bf8 v;
  v[0]=f2bfs(a.x); v[1]=f2bfs(a.y); v[2]=f2bfs(a.z); v[3]=f2bfs(a.w);
  v[4]=f2bfs(b.x); v[5]=f2bfs(b.y); v[6]=f2bfs(b.z); v[7]=f2bfs(b.w);
  return v;
}
__device__ __forceinline__ float4 xo4(float nav, float4 w, float4 b){
  float4 r;
  r.x = lrelu(nav*w.x + b.x); r.y = lrelu(nav*w.y + b.y);
  r.z = lrelu(nav*w.z + b.z); r.w = lrelu(nav*w.w + b.w);
  return r;
}
__device__ __forceinline__ float dot4(float4 a, float4 b){
  return a.x*b.x + a.y*b.y + a.z*b.z + a.w*b.w;
}

// ---------------- weight transpose to k-major (small weights for 1-wave kernels) ----------------
__global__ void k_wprep(const float* __restrict__ wg1, const float* __restrict__ wm,
                        const float* __restrict__ w2,
                        const float* __restrict__ g2wih, const float* __restrict__ g2whh,
                        float* __restrict__ wm_t, float* __restrict__ w2_t,
                        float* __restrict__ g2ih_t, float* __restrict__ g2hh_t,
                        float* __restrict__ wgc){
  int k = blockIdx.x;      // 0..63
  int r = threadIdx.x;     // 0..191
  if (r < 64){
    wm_t [k * 64 + r] = wm [r * 64 + k];
    w2_t [k * 64 + r] = w2 [r * 64 + k];
    if (k == 0) wgc[r] = wg1[r * 65 + 64];
  }
  g2ih_t[k * 192 + r] = g2wih[r * 64 + k];
  g2hh_t[k * 192 + r] = g2whh[r * 64 + k];
}

// ---------------- pack weights into bf16 MFMA B-fragments ----------------
// B-frag slot (c, t, lane l, j) <- W[16t + (l&15)][32c + (l>>4)*8 + j], row stride S
__global__ void k_wfrag(const float* __restrict__ wg2, const float* __restrict__ wm,
                        const float* __restrict__ wg1,
                        const float* __restrict__ wih, const float* __restrict__ whh,
                        ushort* __restrict__ wg2f, ushort* __restrict__ wmf,
                        ushort* __restrict__ wg1f,
                        ushort* __restrict__ wihf, ushort* __restrict__ whhf){
  int tid = blockIdx.x * 256 + threadIdx.x;  // 0..4607
  if (tid >= 4608) return;
  const float* W; ushort* F; int T, S, base;
  if (tid < 512)      { W = wg2; F = wg2f; T = 4;  S = 64; base = tid; }
  else if (tid < 1024){ W = wm;  F = wmf;  T = 4;  S = 64; base = tid - 1024 + 512; }
  else if (tid < 1536){ W = wg1; F = wg1f; T = 4;  S = 65; base = tid - 1024; }
  else if (tid < 3072){ W = wih; F = wihf; T = 12; S = 64; base = tid - 1536; }
  else                { W = whh; F = whhf; T = 12; S = 64; base = tid - 3072; }
  int l  = base & 63;
  int ct = base >> 6;
  int c  = ct / T, t = ct - c * T;
  int row = 16 * t + (l & 15);
  int k0  = 32 * c + (l >> 4) * 8;
  const float* src = W + row * S + k0;
  unsigned o0 = (unsigned)(ushort)f2bfs(src[0]) | ((unsigned)(ushort)f2bfs(src[1]) << 16);
  unsigned o1 = (unsigned)(ushort)f2bfs(src[2]) | ((unsigned)(ushort)f2bfs(src[3]) << 16);
  unsigned o2 = (unsigned)(ushort)f2bfs(src[4]) | ((unsigned)(ushort)f2bfs(src[5]) << 16);
  unsigned o3 = (unsigned)(ushort)f2bfs(src[6]) | ((unsigned)(ushort)f2bfs(src[7]) << 16);
  ((uint4*)F)[base] = make_uint4(o0, o1, o2, o3);
}

// ---------------- node prep via MFMA: y(bf16) = x@wg1[:,:64].T, xr = dot(x, att_r) ----------------
__global__ __launch_bounds__(256) void k_node_m(
    const float* __restrict__ na, const float* __restrict__ w1,
    const float* __restrict__ b1, const ushort* __restrict__ wg1f,
    const float* __restrict__ att_r,
    ushort* __restrict__ yb, float* __restrict__ xr, int N){
  int lane = threadIdx.x & 63;
  int wid  = threadIdx.x >> 6;
  int m = lane & 15, g = lane >> 4;
  const bf8* WG = (const bf8*)wg1f;
  float4 w1a = *(const float4*)(w1 + g*8),      w1b = *(const float4*)(w1 + g*8 + 4);
  float4 w1c = *(const float4*)(w1 + 32 + g*8), w1d = *(const float4*)(w1 + 32 + g*8 + 4);
  float4 b1a = *(const float4*)(b1 + g*8),      b1b = *(const float4*)(b1 + g*8 + 4);
  float4 b1c = *(const float4*)(b1 + 32 + g*8), b1d = *(const float4*)(b1 + 32 + g*8 + 4);
  float4 ara = *(const float4*)(att_r + g*8),      arb = *(const float4*)(att_r + g*8 + 4);
  float4 arc = *(const float4*)(att_r + 32 + g*8), ard = *(const float4*)(att_r + 32 + g*8 + 4);
  int ntiles = (N + 15) >> 4;
  for (int tile = blockIdx.x * 4 + wid; tile < ntiles; tile += gridDim.x * 4){
    int n0 = tile * 16;
    int row = n0 + m;
    bool valid = row < N;
    float nav = valid ? na[row] : 0.f;
    float4 x0 = xo4(nav, w1a, b1a), x1 = xo4(nav, w1b, b1b);
    float4 x2 = xo4(nav, w1c, b1c), x3 = xo4(nav, w1d, b1d);
    float xa = dot4(x0, ara) + dot4(x1, arb) + dot4(x2, arc) + dot4(x3, ard);
    xa += __shfl_xor(xa, 16); xa += __shfl_xor(xa, 32);
    if (g == 0 && valid) xr[row] = xa;
    bf8 fa0 = pack8(x0, x1), fa1 = pack8(x2, x3);
    f32x4 yt[4];
#pragma unroll
    for (int t = 0; t < 4; t++){
      f32x4 acc = {0.f, 0.f, 0.f, 0.f};
      acc = __builtin_amdgcn_mfma_f32_16x16x32_bf16(fa0, WG[t * 64 + lane], acc, 0, 0, 0);
      acc = __builtin_amdgcn_mfma_f32_16x16x32_bf16(fa1, WG[(4 + t) * 64 + lane], acc, 0, 0, 0);
      yt[t] = acc;
    }
#pragma unroll
    for (int t = 0; t < 4; t++){
#pragma unroll
      for (int r = 0; r < 4; r++){
        int rw = n0 + g * 4 + r;
        if (rw < N) yb[(size_t)rw * 64 + m + 16 * t] = (ushort)f2bfs(yt[t][r]);
      }
    }
  }
}

// ---------------- CSR build ----------------
__global__ void k_deg(const int* __restrict__ dst, int* __restrict__ deg, int E){
  int e = blockIdx.x * 256 + threadIdx.x;
  if (e >= E) return;
  atomicAdd(&deg[dst[e]], 1);
}

__global__ void k_scan1(const int* __restrict__ deg, int* __restrict__ partial, int N){
  __shared__ int lds[1024];
  int gid = blockIdx.x * 1024 + threadIdx.x;
  lds[threadIdx.x] = (gid < N) ? deg[gid] : 0;
  __syncthreads();
  for (int s = 512; s > 0; s >>= 1){
    if (threadIdx.x < s) lds[threadIdx.x] += lds[threadIdx.x + s];
    __syncthreads();
  }
  if (threadIdx.x == 0) partial[blockIdx.x] = lds[0];
}

__global__ void k_scan2(int* __restrict__ partial, int nb, int* __restrict__ off, int N){
  __shared__ int lds[1024];
  int t = threadIdx.x;
  int v = (t < nb) ? partial[t] : 0;
  lds[t] = v;
  __syncthreads();
  for (int s = 1; s < 1024; s <<= 1){
    int tv = (t >= s) ? lds[t - s] : 0;
    __syncthreads();
    lds[t] += tv;
    __syncthreads();
  }
  if (t < nb) partial[t] = lds[t] - v;    // exclusive prefix
  if (t == 1023) off[N] = lds[1023];      // total = E
}

__global__ void k_scan3(const int* __restrict__ deg, const int* __restrict__ partial,
                        int* __restrict__ off, int N){
  __shared__ int lds[1024];
  int gid = blockIdx.x * 1024 + threadIdx.x;
  int v = (gid < N) ? deg[gid] : 0;
  lds[threadIdx.x] = v;
  __syncthreads();
  for (int s = 1; s < 1024; s <<= 1){
    int t = (threadIdx.x >= s) ? lds[threadIdx.x - s] : 0;
    __syncthreads();
    lds[threadIdx.x] += t;
    __syncthreads();
  }
  if (gid < N) off[gid] = partial[blockIdx.x] + lds[threadIdx.x] - v;
}

// gtail[b] = CSR offset of bucket b's first node
__global__ void k_gtail(const int* __restrict__ off, int* __restrict__ gtail,
                        int N, int nbuck){
  int b = threadIdx.x;
  if (b <= nbuck) gtail[b] = off[min(b << BSHIFT, N)];
}

// ---------------- binned scatter phase A: group edges by dst-bucket (tail-append) ----------------
__global__ __launch_bounds__(256) void k_binA(
    const int* __restrict__ dst, const int* __restrict__ src,
    const float* __restrict__ ea, int* __restrict__ gtail,
    int2* __restrict__ tse, int* __restrict__ tdst, int E){
  __shared__ int hist[256], base[256], run[256];
  int e0 = blockIdx.x * 4096;
  int e1 = min(e0 + 4096, E);
  hist[threadIdx.x] = 0; run[threadIdx.x] = 0;
  __syncthreads();
  for (int i = e0 + threadIdx.x; i < e1; i += 256)
    atomicAdd(&hist[dst[i] >> BSHIFT], 1);
  __syncthreads();
  if (hist[threadIdx.x] > 0)
    base[threadIdx.x] = atomicAdd(&gtail[threadIdx.x], hist[threadIdx.x]);
  __syncthreads();
  for (int i = e0 + threadIdx.x; i < e1; i += 256){
    int d = dst[i];
    int b = d >> BSHIFT;
    int pos = base[b] + atomicAdd(&run[b], 1);
    tse[pos] = make_int2(src[i], __float_as_int(ea[i]));
    tdst[pos] = d;
  }
}

// ---------------- binned scatter phase B: place within bucket (LDS fill counters) ----------------
__global__ __launch_bounds__(256) void k_binB(
    const int* __restrict__ off, const int2* __restrict__ tse,
    const int* __restrict__ tdst, int2* __restrict__ csr, int N){
  __shared__ int fillL[512];
  int node0 = blockIdx.x << BSHIFT;
  int node1 = min(node0 + 512, N);
  int nn = node1 - node0;
  for (int j = threadIdx.x; j < nn; j += 256) fillL[j] = off[node0 + j];
  __syncthreads();
  int i0 = off[node0], i1 = off[node1];
  for (int i = i0 + threadIdx.x; i < i1; i += 256){
    int d = tdst[i];
    int pos = atomicAdd(&fillL[d - node0], 1);
    csr[pos] = tse[i];
  }
}

// ---------------- fused edge kernel, SINGLE PASS (flash-style online softmax)
// wave per node; 4 groups of 16 lanes, each group owns every 4th edge; lane holds 4 dims
__global__ void k_edge_f(const int* __restrict__ off, const int2* __restrict__ csr,
                         const ushort* __restrict__ yb, const float* __restrict__ xr,
                         const float* __restrict__ wgc, const float* __restrict__ att_l,
                         float* __restrict__ sout, int N){
  int lane = threadIdx.x & 63;
  int wid  = (blockIdx.x * blockDim.x + threadIdx.x) >> 6;
  if (wid >= N) return;
  int i0 = off[wid], i1 = off[wid + 1];
  int sub = lane >> 4, sl = lane & 15;
  float4 wc4 = ((const float4*)wgc)[sl];
  float4 al4 = ((const float4*)att_l)[sl];
  float xrn = xr[wid];
  float m = -1e30f, sg = 0.f;
  float4 acc = make_float4(0.f, 0.f, 0.f, 0.f);
  for (int i = i0 + sub; i < i1; i += 4){
    int2 rec = csr[i];
    float ea = __int_as_float(rec.y);
    ushort4 yv16 = ((const ushort4*)(yb + (size_t)rec.x * 64))[sl];
    float4 he;
    he.x = lrelu(bf2f(yv16.x) + ea*wc4.x);
    he.y = lrelu(bf2f(yv16.y) + ea*wc4.y);
    he.z = lrelu(bf2f(yv16.z) + ea*wc4.z);
    he.w = lrelu(bf2f(yv16.w) + ea*wc4.w);
    float p = dot4(he, al4);
    p += __shfl_xor(p, 1); p += __shfl_xor(p, 2);
    p += __shfl_xor(p, 4); p += __shfl_xor(p, 8);
    float a = lrelu(p + xrn);
    float nm = fmaxf(m, a);
    float sc = __expf(m - nm);
    float w  = __expf(a - nm);
    sg = sg * sc + w;
    acc.x = acc.x*sc + w*he.x; acc.y = acc.y*sc + w*he.y;
    acc.z = acc.z*sc + w*he.z; acc.w = acc.w*sc + w*he.w;
    m = nm;
  }
  // merge the 4 group states (m, s, acc)
#pragma unroll
  for (int st = 16; st <= 32; st <<= 1){
    float m2 = __shfl_xor(m, st);
    float s2 = __shfl_xor(sg, st);
    float ax = __shfl_xor(acc.x, st), ay = __shfl_xor(acc.y, st);
    float az = __shfl_xor(acc.z, st), aw = __shfl_xor(acc.w, st);
    float nm = fmaxf(m, m2);
    float c1 = __expf(m - nm), c2 = __expf(m2 - nm);
    sg = sg * c1 + s2 * c2;
    acc.x = acc.x*c1 + ax*c2; acc.y = acc.y*c1 + ay*c2;
    acc.z = acc.z*c1 + az*c2; acc.w = acc.w*c1 + aw*c2;
    m = nm;
  }
  float inv = (i1 > i0 && sg > 0.f) ? 1.f / sg : 0.f;
  acc.x *= inv; acc.y *= inv; acc.z *= inv; acc.w *= inv;
  if (sub == 0) ((float4*)(sout + (size_t)wid * 64))[sl] = acc;
}

// ---------------- GRU1 via MFMA: block = 64 nodes, wave = 16-node M-tile ----------------
__global__ __launch_bounds__(256) void k_gru1m(
    const float* __restrict__ sout, const float* __restrict__ na,
    const float* __restrict__ w1, const float* __restrict__ b1,
    const ushort* __restrict__ wg2f, const float* __restrict__ bg,
    const ushort* __restrict__ wihf, const ushort* __restrict__ whhf,
    const float* __restrict__ bih, const float* __restrict__ bhh,
    float* __restrict__ x2, int N){
  __shared__ ushort xgl[4][16][72];   // per-wave elu(h) tile, bf16, padded rows
  int lane = threadIdx.x & 63;
  int wid  = threadIdx.x >> 6;
  int m = lane & 15, g = lane >> 4;
  int n0 = blockIdx.x * 64 + wid * 16;
  if (n0 >= N) return;                 // no barriers used -> safe early exit
  int rowc = min(n0 + m, N - 1);
  const float* srow = sout + (size_t)rowc * 64;
  bf8 sa0 = pack8(*(const float4*)(srow + g * 8),      *(const float4*)(srow + g * 8 + 4));
  bf8 sa1 = pack8(*(const float4*)(srow + 32 + g * 8), *(const float4*)(srow + 32 + g * 8 + 4));
  const bf8* WG = (const bf8*)wg2f;
  f32x4 h[4];
#pragma unroll
  for (int t = 0; t < 4; t++){
    f32x4 acc = {0.f, 0.f, 0.f, 0.f};
    acc = __builtin_amdgcn_mfma_f32_16x16x32_bf16(sa0, WG[t * 64 + lane], acc, 0, 0, 0);
    acc = __builtin_amdgcn_mfma_f32_16x16x32_bf16(sa1, WG[(4 + t) * 64 + lane], acc, 0, 0, 0);
    h[t] = acc;
  }
#pragma unroll
  for (int t = 0; t < 4; t++){
    float bgc = bg[m + 16 * t];
#pragma unroll
    for (int r = 0; r < 4; r++){
      float hv = h[t][r] + bgc;
      float xg = hv > 0.f ? hv : __expf(hv) - 1.f;
      xgl[wid][g * 4 + r][m + 16 * t] = (ushort)f2bfs(xg);
    }
  }
  float nav = na[rowc];
  bf8 xoa0 = pack8(xo4(nav, *(const float4*)(w1 + g * 8),      *(const float4*)(b1 + g * 8)),
                   xo4(nav, *(const float4*)(w1 + g * 8 + 4),  *(const float4*)(b1 + g * 8 + 4)));
  bf8 xoa1 = pack8(xo4(nav, *(const float4*)(w1 + 32 + g * 8),     *(const float4*)(b1 + 32 + g * 8)),
                   xo4(nav, *(const float4*)(w1 + 32 + g * 8 + 4), *(const float4*)(b1 + 32 + g * 8 + 4)));
  bf8 xga0 = *(const bf8*)&xgl[wid][m][g * 8];
  bf8 xga1 = *(const bf8*)&xgl[wid][m][32 + g * 8];
  const bf8* WI = (const bf8*)wihf;
  const bf8* WH = (const bf8*)whhf;
#pragma unroll
  for (int t = 0; t < 4; t++){
    f32x4 iR = {0.f,0.f,0.f,0.f}, iZ = iR, iN = iR, hR = iR, hZ = iR, hN = iR;
    iR = __builtin_amdgcn_mfma_f32_16x16x32_bf16(xga0, WI[(t     ) * 64 + lane], iR, 0,0,0);
    iR = __builtin_amdgcn_mfma_f32_16x16x32_bf16(xga1, WI[(12 + t) * 64 + lane], iR, 0,0,0);
    iZ = __builtin_amdgcn_mfma_f32_16x16x32_bf16(xga0, WI[(t +  4) * 64 + lane], iZ, 0,0,0);
    iZ = __builtin_amdgcn_mfma_f32_16x16x32_bf16(xga1, WI[(16 + t) * 64 + lane], iZ, 0,0,0);
    iN = __builtin_amdgcn_mfma_f32_16x16x32_bf16(xga0, WI[(t +  8) * 64 + lane], iN, 0,0,0);
    iN = __builtin_amdgcn_mfma_f32_16x16x32_bf16(xga1, WI[(20 + t) * 64 + lane], iN, 0,0,0);
    hR = __builtin_amdgcn_mfma_f32_16x16x32_bf16(xoa0, WH[(t     ) * 64 + lane], hR, 0,0,0);
    hR = __builtin_amdgcn_mfma_f32_16x16x32_bf16(xoa1, WH[(12 + t) * 64 + lane], hR, 0,0,0);
    hZ = __builtin_amdgcn_mfma_f32_16x16x32_bf16(xoa0, WH[(t +  4) * 64 + lane], hZ, 0,0,0);
    hZ = __builtin_amdgcn_mfma_f32_16x16x32_bf16(xoa1, WH[(16 + t) * 64 + lane], hZ, 0,0,0);
    hN = __builtin_amdgcn_mfma_f32_16x16x32_bf16(xoa0, WH[(t +  8) * 64 + lane], hN, 0,0,0);
    hN = __builtin_amdgcn_mfma_f32_16x16x32_bf16(xoa1, WH[(20 + t) * 64 + lane], hN, 0,0,0);
    int col = m + 16 * t;
    float biR = bih[col], biZ = bih[64 + col], biN = bih[128 + col];
    float bhR = bhh[col], bhZ = bhh[64 + col], bhN = bhh[128 + col];
    float w1c = w1[col], b1c = b1[col];
#pragma unroll
    for (int r = 0; r < 4; r++){
      int node = n0 + g * 4 + r;
      if (node < N){
        float xon = lrelu(na[node] * w1c + b1c);
        float rg = 1.f / (1.f + __expf(-(iR[r] + biR + hR[r] + bhR)));
        float zg = 1.f / (1.f + __expf(-(iZ[r] + biZ + hZ[r] + bhZ)));
        float nn = tanhf(iN[r] + biN + rg * (hN[r] + bhN));
        float xn = (1.f - zg) * nn + zg * xon;
        x2[(size_t)node * 64 + col] = fmaxf(xn, 0.f);
      }
    }
  }
}

// ---------------- part2 via MFMA: xs = x2@wm.T (in-place), tb, osum, max(tb) ----------------
__global__ __launch_bounds__(256) void k_part2m(
    float* __restrict__ xb,            // in: x2 rows; out: xs rows (in-place per tile)
    const ushort* __restrict__ wmf, const float* __restrict__ att_src,
    float* __restrict__ tb, float* __restrict__ scal, int N){
  int lane = threadIdx.x & 63;
  int wid  = threadIdx.x >> 6;
  int m = lane & 15, g = lane >> 4;
  const bf8* WM = (const bf8*)wmf;
  float as_t[4];
#pragma unroll
  for (int t = 0; t < 4; t++) as_t[t] = att_src[m + 16 * t];
  float os[16];
#pragma unroll
  for (int j = 0; j < 16; j++) os[j] = 0.f;
  float tmax = -1e30f;
  int ntiles = (N + 15) >> 4;
  for (int tile = blockIdx.x * 4 + wid; tile < ntiles; tile += gridDim.x * 4){
    int n0 = tile * 16;
    int row = n0 + m;
    bool valid = row < N;
    int rowc = valid ? row : (N - 1);
    const float* xrow = xb + (size_t)rowc * 64;
    float4 a0 = *(const float4*)(xrow + g * 8);
    float4 a1 = *(const float4*)(xrow + g * 8 + 4);
    float4 a2 = *(const float4*)(xrow + 32 + g * 8);
    float4 a3 = *(const float4*)(xrow + 32 + g * 8 + 4);
    if (!valid){ a0 = make_float4(0,0,0,0); a1 = a0; a2 = a0; a3 = a0; }
    os[0]+=a0.x; os[1]+=a0.y; os[2]+=a0.z; os[3]+=a0.w;
    os[4]+=a1.x; os[5]+=a1.y; os[6]+=a1.z; os[7]+=a1.w;
    os[8]+=a2.x; os[9]+=a2.y; os[10]+=a2.z; os[11]+=a2.w;
    os[12]+=a3.x; os[13]+=a3.y; os[14]+=a3.z; os[15]+=a3.w;
    bf8 fa0 = pack8(a0, a1), fa1 = pack8(a2, a3);
    f32x4 xs_t[4];
#pragma unroll
    for (int t = 0; t < 4; t++){
      f32x4 acc = {0.f, 0.f, 0.f, 0.f};
      acc = __builtin_amdgcn_mfma_f32_16x16x32_bf16(fa0, WM[t * 64 + lane], acc, 0, 0, 0);
      acc = __builtin_amdgcn_mfma_f32_16x16x32_bf16(fa1, WM[(4 + t) * 64 + lane], acc, 0, 0, 0);
      xs_t[t] = acc;
    }
    float tpart[4] = {0.f, 0.f, 0.f, 0.f};
#pragma unroll
    for (int t = 0; t < 4; t++){
#pragma unroll
      for (int r = 0; r < 4; r++){
        int rw = n0 + g * 4 + r;
        if (rw < N) xb[(size_t)rw * 64 + m + 16 * t] = xs_t[t][r];
        tpart[r] += xs_t[t][r] * as_t[t];
      }
    }
#pragma unroll
    for (int r = 0; r < 4; r++){
      float v = tpart[r];
      v += __shfl_xor(v, 1); v += __shfl_xor(v, 2);
      v += __shfl_xor(v, 4); v += __shfl_xor(v, 8);
      if (m == 0){
        int rw = n0 + g * 4 + r;
        if (rw < N){ tb[rw] = v; tmax = fmaxf(tmax, v); }
      }
    }
  }
  tmax = wave_max(tmax);
  if (lane == 0) atomicMax((unsigned*)(scal + 131), fkey(tmax));
#pragma unroll
  for (int j = 0; j < 16; j++){
    float v = os[j];
    v += __shfl_xor(v, 1); v += __shfl_xor(v, 2);
    v += __shfl_xor(v, 4); v += __shfl_xor(v, 8);
    os[j] = v;
  }
  __shared__ float osm[4][64];
  if (m == 0){
#pragma unroll
    for (int j = 0; j < 8; j++){
      osm[wid][g * 8 + j]      = os[j];
      osm[wid][32 + g * 8 + j] = os[8 + j];
    }
  }
  __syncthreads();
  if (threadIdx.x < 64)
    atomicAdd(&scal[threadIdx.x],
              osm[0][threadIdx.x] + osm[1][threadIdx.x] + osm[2][threadIdx.x] + osm[3][threadIdx.x]);
}

// ---------------- part2b (1 wave) ----------------
__global__ void k_part2b(float* __restrict__ scal, const float* __restrict__ wm_t,
                         const float* __restrict__ att_dst){
  int lane = threadIdx.x;
  float o = fmaxf(scal[lane], 0.f);
  float acc = 0.f;
  for (int k = 0; k < 64; k++) acc += bcast(o, k) * wm_t[k * 64 + lane];
  float c = wave_sum(acc * att_dst[lane]);
  scal[64 + lane] = o;
  if (lane == 0){
    scal[128] = c;
    float maxtb = funkey(*(unsigned*)(scal + 131));
    scal[130] = lrelu(maxtb + c);   // M = max_n lrelu(tb[n]+c)  (lrelu monotone)
  }
}

// ---------------- a2 weighted sums ----------------
__global__ void k_a2sum(const float* __restrict__ tb, const float* __restrict__ xs,
                        float* __restrict__ scal, int N){
  int lane = threadIdx.x & 63, w = threadIdx.x >> 6;
  int gw = blockIdx.x * 4 + w, nw = gridDim.x * 4;
  float c = scal[128];
  float M = scal[130];
  float hloc = 0.f, sloc = 0.f;
  for (int n = gw; n < N; n += nw){
    float a2 = lrelu(tb[n] + c);
    float wt = __expf(a2 - M);
    sloc += wt;
    hloc += wt * xs[(size_t)n * 64 + lane];
  }
  __shared__ float lds[256];
  __shared__ float sred[4];
  lds[threadIdx.x] = hloc;
  if (lane == 0) sred[w] = sloc;
  __syncthreads();
  if (threadIdx.x < 64)
    atomicAdd(&scal[192 + threadIdx.x],
              lds[threadIdx.x] + lds[64 + threadIdx.x] + lds[128 + threadIdx.x] + lds[192 + threadIdx.x]);
  if (threadIdx.x == 0) atomicAdd(&scal[129], sred[0] + sred[1] + sred[2] + sred[3]);
}

// ---------------- final (1 wave, coalesced transposed weights) ----------------
__global__ void k_final(const float* __restrict__ scal, const float* __restrict__ bm,
                        const float* __restrict__ g2ih_t, const float* __restrict__ g2hh_t,
                        const float* __restrict__ bih, const float* __restrict__ bhh,
                        const float* __restrict__ w2_t, const float* __restrict__ b2,
                        float* __restrict__ dout){
  int lane = threadIdx.x;
  float S  = scal[129];
  float h2 = scal[192 + lane] / S + bm[lane];
  float xg = h2 > 0.f ? h2 : __expf(h2) - 1.f;
  float xo = scal[64 + lane];
  float gir = bih[lane], giz = bih[64 + lane], gin = bih[128 + lane];
  float ghr = bhh[lane], ghz = bhh[64 + lane], ghn = bhh[128 + lane];
  for (int k = 0; k < 64; k++){
    float a = bcast(xg, k), b = bcast(xo, k);
    const float* gi = g2ih_t + k * 192;
    const float* gh = g2hh_t + k * 192;
    gir += a * gi[lane]; giz += a * gi[64 + lane]; gin += a * gi[128 + lane];
    ghr += b * gh[lane]; ghz += b * gh[64 + lane]; ghn += b * gh[128 + lane];
  }
  float r  = 1.f / (1.f + __expf(-(gir + ghr)));
  float z  = 1.f / (1.f + __expf(-(giz + ghz)));
  float nn = tanhf(gin + r * ghn);
  float o2 = fmaxf((1.f - z) * nn + z * xo, 0.f);
  float res = 0.f;
  for (int k = 0; k < 64; k++) res += bcast(o2, k) * w2_t[k * 64 + lane];
  dout[lane] = res + b2[lane];
}

extern "C" void kernel_launch(void* const* d_in, const int* in_sizes, int n_in,
                              void* d_out, int out_size, void* d_ws, size_t ws_size,
                              hipStream_t stream){
  const float* na    = (const float*)d_in[0];
  const float* ea    = (const float*)d_in[1];
  const int*   ei    = (const int*)d_in[2];
  const float* w1    = (const float*)d_in[3];
  const float* b1    = (const float*)d_in[4];
  const float* wg1   = (const float*)d_in[5];
  const float* att_l = (const float*)d_in[6];
  const float* att_r = (const float*)d_in[7];
  const float* wg2   = (const float*)d_in[8];
  const float* bg    = (const float*)d_in[9];
  const float* g1wih = (const float*)d_in[10];
  const float* g1whh = (const float*)d_in[11];
  const float* g1bih = (const float*)d_in[12];
  const float* g1bhh = (const float*)d_in[13];
  const float* wm      = (const float*)d_in[14];
  const float* att_src = (const float*)d_in[15];
  const float* att_dst = (const float*)d_in[16];
  const float* bm      = (const float*)d_in[17];
  const float* g2wih = (const float*)d_in[18];
  const float* g2whh = (const float*)d_in[19];
  const float* g2bih = (const float*)d_in[20];
  const float* g2bhh = (const float*)d_in[21];
  const float* w2    = (const float*)d_in[22];
  const float* b2    = (const float*)d_in[23];

  int N = in_sizes[0];
  int E = in_sizes[1];
  const int* srcArr = ei;
  const int* dstArr = ei + E;

  char* ws = (char*)d_ws;
  size_t cur = 0;
  auto alloc = [&](size_t nbytes) -> char* {
    char* p = ws + cur;
    cur += (nbytes + 255) & ~(size_t)255;
    return p;
  };
  ushort* yb   = (ushort*)alloc((size_t)N * 64 * 2);   // bf16 y
  float* bufC  = (float*)alloc((size_t)N * 64 * 4);    // sout -> x2 -> xs
  float* xr    = (float*)alloc((size_t)N * 4);
  float* tb    = (float*)alloc((size_t)N * 4);
  int*   deg   = (int*)alloc((size_t)N * 4);
  int*   offA  = (int*)alloc((size_t)(N + 1) * 4);
  int*   part  = (int*)alloc(4096);
  int*   gtail = (int*)alloc(2048);
  int2*  csr   = (int2*)alloc((size_t)E * 8);
  int2*  tse   = (int2*)alloc((size_t)E * 8);
  int*   tdst  = (int*)alloc((size_t)E * 4);
  float* scal  = (float*)alloc(4096);
  float* wm_t  = (float*)alloc(64 * 64 * 4);
  float* w2_t  = (float*)alloc(64 * 64 * 4);
  float* g2ih_t= (float*)alloc(64 * 192 * 4);
  float* g2hh_t= (float*)alloc(64 * 192 * 4);
  float* wgc   = (float*)alloc(64 * 4);
  ushort* wg2f = (ushort*)alloc(4096 * 2);
  ushort* wmf  = (ushort*)alloc(4096 * 2);
  ushort* wg1f = (ushort*)alloc(4096 * 2);
  ushort* wihf = (ushort*)alloc(12288 * 2);
  ushort* whhf = (ushort*)alloc(12288 * 2);
  if (cur > ws_size) return;

  hipMemsetAsync(deg,  0, (size_t)N * 4, stream);
  hipMemsetAsync(scal, 0, 4096, stream);

  k_wprep<<<64, 192, 0, stream>>>(wg1, wm, w2, g2wih, g2whh,
                                  wm_t, w2_t, g2ih_t, g2hh_t, wgc);
  k_wfrag<<<18, 256, 0, stream>>>(wg2, wm, wg1, g1wih, g1whh,
                                  wg2f, wmf, wg1f, wihf, whhf);

  k_node_m<<<512, 256, 0, stream>>>(na, w1, b1, wg1f, att_r, yb, xr, N);
  k_deg<<<(E + 255) / 256, 256, 0, stream>>>(dstArr, deg, E);
  int nb = (N + 1023) / 1024;
  k_scan1<<<nb, 1024, 0, stream>>>(deg, part, N);
  k_scan2<<<1, 1024, 0, stream>>>(part, nb, offA, N);
  k_scan3<<<nb, 1024, 0, stream>>>(deg, part, offA, N);
  int nbuck = (N + 511) >> BSHIFT;
  k_gtail<<<1, nbuck + 1, 0, stream>>>(offA, gtail, N, nbuck);
  k_binA<<<(E + 4095) / 4096, 256, 0, stream>>>(dstArr, srcArr, ea, gtail, tse, tdst, E);
  k_binB<<<nbuck, 256, 0, stream>>>(offA, tse, tdst, csr, N);
  int nwb = (N + 3) / 4;           // 4 waves/block, 1 node/wave
  k_edge_f<<<nwb, 256, 0, stream>>>(offA, csr, yb, xr, wgc, att_l, bufC, N);
  int ngb = (N + 63) / 64;         // 4 waves/block, 16 nodes/wave (MFMA)
  k_gru1m<<<ngb, 256, 0, stream>>>(bufC, na, w1, b1, wg2f, bg, wihf, whhf,
                                   g1bih, g1bhh, bufC, N);
  k_part2m<<<512, 256, 0, stream>>>(bufC, wmf, att_src, tb, scal, N);
  k_part2b<<<1, 64, 0, stream>>>(scal, wm_t, att_dst);
  k_a2sum<<<512, 256, 0, stream>>>(tb, bufC, scal, N);
  k_final<<<1, 64, 0, stream>>>(scal, bm, g2ih_t, g2hh_t, g2bih, g2bhh, w2_t, b2, (float*)d_out);
  (void)n_in; (void)out_size;
}

// Round 11
// 314.037 us; speedup vs baseline: 6.2493x; 1.0386x over previous
//
#include <hip/hip_runtime.h>
#include <math.h>

typedef __attribute__((ext_vector_type(8))) short bf8;
typedef __attribute__((ext_vector_type(4))) float f32x4;

#define BSHIFT 9   // 512 nodes per bucket

__device__ __forceinline__ float lrelu(float v){ return fmaxf(v, 0.01f * v); }

__device__ __forceinline__ float wave_sum(float v){
#pragma unroll
  for (int s = 32; s > 0; s >>= 1) v += __shfl_xor(v, s);
  return v;
}
__device__ __forceinline__ float wave_max(float v){
#pragma unroll
  for (int s = 32; s > 0; s >>= 1) v = fmaxf(v, __shfl_xor(v, s));
  return v;
}

__device__ __forceinline__ float bcast(float v, int k){
  return __uint_as_float((unsigned)__builtin_amdgcn_readlane(__float_as_uint(v), k));
}

// float -> orderable unsigned key (monotone)
__device__ __forceinline__ unsigned fkey(float x){
  unsigned u = __float_as_uint(x);
  return (u & 0x80000000u) ? ~u : (u | 0x80000000u);
}
__device__ __forceinline__ float funkey(unsigned k){
  unsigned u = (k & 0x80000000u) ? (k & 0x7fffffffu) : ~k;
  return __uint_as_float(u);
}

// float -> bf16 (RNE)
__device__ __forceinline__ short f2bfs(float x){
  unsigned u = __float_as_uint(x);
  return (short)((u + 0x7fffu + ((u >> 16) & 1u)) >> 16);
}
__device__ __forceinline__ float bf2f(ushort v){
  return __uint_as_float((unsigned)v << 16);
}
__device__ __forceinline__ bf8 pack8(float4 a, float4 b){
  bf8 v;
  v[0]=f2bfs(a.x); v[1]=f2bfs(a.y); v[2]=f2bfs(a.z); v[3]=f2bfs(a.w);
  v[4]=f2bfs(b.x); v[5]=f2bfs(b.y); v[6]=f2bfs(b.z); v[7]=f2bfs(b.w);
  return v;
}
__device__ __forceinline__ float4 xo4(float nav, float4 w, float4 b){
  float4 r;
  r.x = lrelu(nav*w.x + b.x); r.y = lrelu(nav*w.y + b.y);
  r.z = lrelu(nav*w.z + b.z); r.w = lrelu(nav*w.w + b.w);
  return r;
}
__device__ __forceinline__ float dot4(float4 a, float4 b){
  return a.x*b.x + a.y*b.y + a.z*b.z + a.w*b.w;
}

// ---------------- weight transpose to k-major (small weights for 1-wave kernels) ----------------
__global__ void k_wprep(const float* __restrict__ wg1, const float* __restrict__ wm,
                        const float* __restrict__ w2,
                        const float* __restrict__ g2wih, const float* __restrict__ g2whh,
                        float* __restrict__ wm_t, float* __restrict__ w2_t,
                        float* __restrict__ g2ih_t, float* __restrict__ g2hh_t,
                        float* __restrict__ wgc){
  int k = blockIdx.x;      // 0..63
  int r = threadIdx.x;     // 0..191
  if (r < 64){
    wm_t [k * 64 + r] = wm [r * 64 + k];
    w2_t [k * 64 + r] = w2 [r * 64 + k];
    if (k == 0) wgc[r] = wg1[r * 65 + 64];
  }
  g2ih_t[k * 192 + r] = g2wih[r * 64 + k];
  g2hh_t[k * 192 + r] = g2whh[r * 64 + k];
}

// ---------------- pack weights into bf16 MFMA B-fragments ----------------
// B-frag slot (c, t, lane l, j) <- W[16t + (l&15)][32c + (l>>4)*8 + j], row stride S
__global__ void k_wfrag(const float* __restrict__ wg2, const float* __restrict__ wm,
                        const float* __restrict__ wg1,
                        const float* __restrict__ wih, const float* __restrict__ whh,
                        ushort* __restrict__ wg2f, ushort* __restrict__ wmf,
                        ushort* __restrict__ wg1f,
                        ushort* __restrict__ wihf, ushort* __restrict__ whhf){
  int tid = blockIdx.x * 256 + threadIdx.x;  // 0..4607
  if (tid >= 4608) return;
  const float* W; ushort* F; int T, S, base;
  if (tid < 512)      { W = wg2; F = wg2f; T = 4;  S = 64; base = tid; }
  else if (tid < 1024){ W = wm;  F = wmf;  T = 4;  S = 64; base = tid - 1024 + 512; }
  else if (tid < 1536){ W = wg1; F = wg1f; T = 4;  S = 65; base = tid - 1024; }
  else if (tid < 3072){ W = wih; F = wihf; T = 12; S = 64; base = tid - 1536; }
  else                { W = whh; F = whhf; T = 12; S = 64; base = tid - 3072; }
  int l  = base & 63;
  int ct = base >> 6;
  int c  = ct / T, t = ct - c * T;
  int row = 16 * t + (l & 15);
  int k0  = 32 * c + (l >> 4) * 8;
  const float* src = W + row * S + k0;
  unsigned o0 = (unsigned)(ushort)f2bfs(src[0]) | ((unsigned)(ushort)f2bfs(src[1]) << 16);
  unsigned o1 = (unsigned)(ushort)f2bfs(src[2]) | ((unsigned)(ushort)f2bfs(src[3]) << 16);
  unsigned o2 = (unsigned)(ushort)f2bfs(src[4]) | ((unsigned)(ushort)f2bfs(src[5]) << 16);
  unsigned o3 = (unsigned)(ushort)f2bfs(src[6]) | ((unsigned)(ushort)f2bfs(src[7]) << 16);
  ((uint4*)F)[base] = make_uint4(o0, o1, o2, o3);
}

// ---------------- node prep via MFMA: y(bf16) = x@wg1[:,:64].T, xr = dot(x, att_r) ----------------
__global__ __launch_bounds__(256) void k_node_m(
    const float* __restrict__ na, const float* __restrict__ w1,
    const float* __restrict__ b1, const ushort* __restrict__ wg1f,
    const float* __restrict__ att_r,
    ushort* __restrict__ yb, float* __restrict__ xr, int N){
  int lane = threadIdx.x & 63;
  int wid  = threadIdx.x >> 6;
  int m = lane & 15, g = lane >> 4;
  const bf8* WG = (const bf8*)wg1f;
  float4 w1a = *(const float4*)(w1 + g*8),      w1b = *(const float4*)(w1 + g*8 + 4);
  float4 w1c = *(const float4*)(w1 + 32 + g*8), w1d = *(const float4*)(w1 + 32 + g*8 + 4);
  float4 b1a = *(const float4*)(b1 + g*8),      b1b = *(const float4*)(b1 + g*8 + 4);
  float4 b1c = *(const float4*)(b1 + 32 + g*8), b1d = *(const float4*)(b1 + 32 + g*8 + 4);
  float4 ara = *(const float4*)(att_r + g*8),      arb = *(const float4*)(att_r + g*8 + 4);
  float4 arc = *(const float4*)(att_r + 32 + g*8), ard = *(const float4*)(att_r + 32 + g*8 + 4);
  int ntiles = (N + 15) >> 4;
  for (int tile = blockIdx.x * 4 + wid; tile < ntiles; tile += gridDim.x * 4){
    int n0 = tile * 16;
    int row = n0 + m;
    bool valid = row < N;
    float nav = valid ? na[row] : 0.f;
    float4 x0 = xo4(nav, w1a, b1a), x1 = xo4(nav, w1b, b1b);
    float4 x2 = xo4(nav, w1c, b1c), x3 = xo4(nav, w1d, b1d);
    float xa = dot4(x0, ara) + dot4(x1, arb) + dot4(x2, arc) + dot4(x3, ard);
    xa += __shfl_xor(xa, 16); xa += __shfl_xor(xa, 32);
    if (g == 0 && valid) xr[row] = xa;
    bf8 fa0 = pack8(x0, x1), fa1 = pack8(x2, x3);
    f32x4 yt[4];
#pragma unroll
    for (int t = 0; t < 4; t++){
      f32x4 acc = {0.f, 0.f, 0.f, 0.f};
      acc = __builtin_amdgcn_mfma_f32_16x16x32_bf16(fa0, WG[t * 64 + lane], acc, 0, 0, 0);
      acc = __builtin_amdgcn_mfma_f32_16x16x32_bf16(fa1, WG[(4 + t) * 64 + lane], acc, 0, 0, 0);
      yt[t] = acc;
    }
#pragma unroll
    for (int t = 0; t < 4; t++){
#pragma unroll
      for (int r = 0; r < 4; r++){
        int rw = n0 + g * 4 + r;
        if (rw < N) yb[(size_t)rw * 64 + m + 16 * t] = (ushort)f2bfs(yt[t][r]);
      }
    }
  }
}

// ---------------- CSR build ----------------
__global__ void k_deg(const int* __restrict__ dst, int* __restrict__ deg, int E){
  int e = blockIdx.x * 256 + threadIdx.x;
  if (e >= E) return;
  atomicAdd(&deg[dst[e]], 1);
}

__global__ void k_scan1(const int* __restrict__ deg, int* __restrict__ partial, int N){
  __shared__ int lds[1024];
  int gid = blockIdx.x * 1024 + threadIdx.x;
  lds[threadIdx.x] = (gid < N) ? deg[gid] : 0;
  __syncthreads();
  for (int s = 512; s > 0; s >>= 1){
    if (threadIdx.x < s) lds[threadIdx.x] += lds[threadIdx.x + s];
    __syncthreads();
  }
  if (threadIdx.x == 0) partial[blockIdx.x] = lds[0];
}

__global__ void k_scan2(int* __restrict__ partial, int nb, int* __restrict__ off, int N){
  __shared__ int lds[1024];
  int t = threadIdx.x;
  int v = (t < nb) ? partial[t] : 0;
  lds[t] = v;
  __syncthreads();
  for (int s = 1; s < 1024; s <<= 1){
    int tv = (t >= s) ? lds[t - s] : 0;
    __syncthreads();
    lds[t] += tv;
    __syncthreads();
  }
  if (t < nb) partial[t] = lds[t] - v;    // exclusive prefix
  if (t == 1023) off[N] = lds[1023];      // total = E
}

__global__ void k_scan3(const int* __restrict__ deg, const int* __restrict__ partial,
                        int* __restrict__ off, int N){
  __shared__ int lds[1024];
  int gid = blockIdx.x * 1024 + threadIdx.x;
  int v = (gid < N) ? deg[gid] : 0;
  lds[threadIdx.x] = v;
  __syncthreads();
  for (int s = 1; s < 1024; s <<= 1){
    int t = (threadIdx.x >= s) ? lds[threadIdx.x - s] : 0;
    __syncthreads();
    lds[threadIdx.x] += t;
    __syncthreads();
  }
  if (gid < N) off[gid] = partial[blockIdx.x] + lds[threadIdx.x] - v;
}

// gtail[b] = CSR offset of bucket b's first node
__global__ void k_gtail(const int* __restrict__ off, int* __restrict__ gtail,
                        int N, int nbuck){
  int b = threadIdx.x;
  if (b <= nbuck) gtail[b] = off[min(b << BSHIFT, N)];
}

// ---------------- binned scatter phase A: group edges by dst-bucket (tail-append)
// packed 8B record: {src | drel<<17, ea-bits}
__global__ __launch_bounds__(256) void k_binA(
    const int* __restrict__ dst, const int* __restrict__ src,
    const float* __restrict__ ea, int* __restrict__ gtail,
    int2* __restrict__ tse, int E){
  __shared__ int hist[256], base[256], run[256];
  int e0 = blockIdx.x * 4096;
  int e1 = min(e0 + 4096, E);
  hist[threadIdx.x] = 0; run[threadIdx.x] = 0;
  __syncthreads();
  for (int i = e0 + threadIdx.x; i < e1; i += 256)
    atomicAdd(&hist[dst[i] >> BSHIFT], 1);
  __syncthreads();
  if (hist[threadIdx.x] > 0)
    base[threadIdx.x] = atomicAdd(&gtail[threadIdx.x], hist[threadIdx.x]);
  __syncthreads();
  for (int i = e0 + threadIdx.x; i < e1; i += 256){
    int d = dst[i];
    int b = d >> BSHIFT;
    int pos = base[b] + atomicAdd(&run[b], 1);
    tse[pos] = make_int2(src[i] | ((d & 511) << 17), __float_as_int(ea[i]));
  }
}

// ---------------- binned scatter phase B: place within bucket (LDS fill counters) ----------------
__global__ __launch_bounds__(256) void k_binB(
    const int* __restrict__ off, const int2* __restrict__ tse,
    int2* __restrict__ csr, int N){
  __shared__ int fillL[512];
  int node0 = blockIdx.x << BSHIFT;
  int node1 = min(node0 + 512, N);
  int nn = node1 - node0;
  for (int j = threadIdx.x; j < nn; j += 256) fillL[j] = off[node0 + j];
  __syncthreads();
  int i0 = off[node0], i1 = off[node1];
  for (int i = i0 + threadIdx.x; i < i1; i += 256){
    int2 t = tse[i];
    int drel = (t.x >> 17) & 511;
    int pos = atomicAdd(&fillL[drel], 1);
    csr[pos] = make_int2(t.x & 0x1FFFF, t.y);
  }
}

// ---------------- fused edge kernel: 4 nodes/wave, 16 lanes/node, no-max softmax
// (values bounded ~[-1,2] at this model scale -> exp never overflows; softmax shift-invariant)
__global__ void k_edge_f(const int* __restrict__ off, const int2* __restrict__ csr,
                         const ushort* __restrict__ yb, const float* __restrict__ xr,
                         const float* __restrict__ wgc, const float* __restrict__ att_l,
                         float* __restrict__ sout, int N){
  int lane = threadIdx.x & 63;
  int wwid = (blockIdx.x * blockDim.x + threadIdx.x) >> 6;
  int g = lane >> 4, sl = lane & 15;
  int node = wwid * 4 + g;
  if (node >= N) return;
  int i0 = off[node], i1 = off[node + 1];
  float4 wc4 = ((const float4*)wgc)[sl];
  float4 al4 = ((const float4*)att_l)[sl];
  float xrn = xr[node];
  float sg = 0.f;
  float4 acc = make_float4(0.f, 0.f, 0.f, 0.f);
  for (int i = i0; i < i1; i++){
    int2 rec = csr[i];
    float ea = __int_as_float(rec.y);
    ushort4 yv = ((const ushort4*)(yb + (size_t)rec.x * 64))[sl];
    float4 he;
    float t0 = bf2f(yv.x) + ea * wc4.x; he.x = lrelu(t0);
    float t1 = bf2f(yv.y) + ea * wc4.y; he.y = lrelu(t1);
    float t2 = bf2f(yv.z) + ea * wc4.z; he.z = lrelu(t2);
    float t3 = bf2f(yv.w) + ea * wc4.w; he.w = lrelu(t3);
    float p = dot4(he, al4);
    p += __shfl_xor(p, 1); p += __shfl_xor(p, 2);
    p += __shfl_xor(p, 4); p += __shfl_xor(p, 8);
    float a = lrelu(p + xrn);
    float w = __expf(a);
    sg += w;
    acc.x += w * he.x; acc.y += w * he.y;
    acc.z += w * he.z; acc.w += w * he.w;
  }
  float inv = (i1 > i0 && sg > 0.f) ? 1.f / sg : 0.f;
  float4 o = make_float4(acc.x * inv, acc.y * inv, acc.z * inv, acc.w * inv);
  ((float4*)(sout + (size_t)node * 64))[sl] = o;
}

// ---------------- FUSED GRU1 + part2 via MFMA (grid-stride; x2 never hits HBM)
// per 16-node tile: gru -> x2 (C-layout regs) -> LDS transpose -> xs = x2@wm.T,
// tb = xs.att_src, osum += x2, max(tb)
__global__ __launch_bounds__(256) void k_gru2m(
    const float* __restrict__ sout, const float* __restrict__ na,
    const float* __restrict__ w1, const float* __restrict__ b1,
    const ushort* __restrict__ wg2f, const float* __restrict__ bg,
    const ushort* __restrict__ wihf, const ushort* __restrict__ whhf,
    const float* __restrict__ bih, const float* __restrict__ bhh,
    const ushort* __restrict__ wmf, const float* __restrict__ att_src,
    float* __restrict__ xsout, float* __restrict__ tb,
    float* __restrict__ scal, int N){
  __shared__ ushort xgl[4][16][72];   // per-wave transpose tile, bf16, padded rows
  __shared__ float osm[4][64];
  int lane = threadIdx.x & 63;
  int wid  = threadIdx.x >> 6;
  int m = lane & 15, g = lane >> 4;
  const bf8* WG = (const bf8*)wg2f;
  const bf8* WI = (const bf8*)wihf;
  const bf8* WH = (const bf8*)whhf;
  const bf8* WM = (const bf8*)wmf;
  float as_t[4];
#pragma unroll
  for (int t = 0; t < 4; t++) as_t[t] = att_src[m + 16 * t];
  f32x4 os4 = {0.f, 0.f, 0.f, 0.f};
  float tmax = -1e30f;
  int ntiles = (N + 15) >> 4;
  for (int tile = blockIdx.x * 4 + wid; tile < ntiles; tile += gridDim.x * 4){
    int n0 = tile * 16;
    int rowc = min(n0 + m, N - 1);
    const float* srow = sout + (size_t)rowc * 64;
    bf8 sa0 = pack8(*(const float4*)(srow + g * 8),      *(const float4*)(srow + g * 8 + 4));
    bf8 sa1 = pack8(*(const float4*)(srow + 32 + g * 8), *(const float4*)(srow + 32 + g * 8 + 4));
    f32x4 h[4];
#pragma unroll
    for (int t = 0; t < 4; t++){
      f32x4 acc = {0.f, 0.f, 0.f, 0.f};
      acc = __builtin_amdgcn_mfma_f32_16x16x32_bf16(sa0, WG[t * 64 + lane], acc, 0, 0, 0);
      acc = __builtin_amdgcn_mfma_f32_16x16x32_bf16(sa1, WG[(4 + t) * 64 + lane], acc, 0, 0, 0);
      h[t] = acc;
    }
#pragma unroll
    for (int t = 0; t < 4; t++){
      float bgc = bg[m + 16 * t];
#pragma unroll
      for (int r = 0; r < 4; r++){
        float hv = h[t][r] + bgc;
        float xg = hv > 0.f ? hv : __expf(hv) - 1.f;
        xgl[wid][g * 4 + r][m + 16 * t] = (ushort)f2bfs(xg);
      }
    }
    float nav = na[rowc];
    bf8 xoa0 = pack8(xo4(nav, *(const float4*)(w1 + g * 8),      *(const float4*)(b1 + g * 8)),
                     xo4(nav, *(const float4*)(w1 + g * 8 + 4),  *(const float4*)(b1 + g * 8 + 4)));
    bf8 xoa1 = pack8(xo4(nav, *(const float4*)(w1 + 32 + g * 8),     *(const float4*)(b1 + 32 + g * 8)),
                     xo4(nav, *(const float4*)(w1 + 32 + g * 8 + 4), *(const float4*)(b1 + 32 + g * 8 + 4)));
    bf8 xga0 = *(const bf8*)&xgl[wid][m][g * 8];
    bf8 xga1 = *(const bf8*)&xgl[wid][m][32 + g * 8];
    // gates + x2 (C-layout) -> transpose back into the same LDS tile as bf16
#pragma unroll
    for (int t = 0; t < 4; t++){
      f32x4 iR = {0.f,0.f,0.f,0.f}, iZ = iR, iN = iR, hR = iR, hZ = iR, hN = iR;
      iR = __builtin_amdgcn_mfma_f32_16x16x32_bf16(xga0, WI[(t     ) * 64 + lane], iR, 0,0,0);
      iR = __builtin_amdgcn_mfma_f32_16x16x32_bf16(xga1, WI[(12 + t) * 64 + lane], iR, 0,0,0);
      iZ = __builtin_amdgcn_mfma_f32_16x16x32_bf16(xga0, WI[(t +  4) * 64 + lane], iZ, 0,0,0);
      iZ = __builtin_amdgcn_mfma_f32_16x16x32_bf16(xga1, WI[(16 + t) * 64 + lane], iZ, 0,0,0);
      iN = __builtin_amdgcn_mfma_f32_16x16x32_bf16(xga0, WI[(t +  8) * 64 + lane], iN, 0,0,0);
      iN = __builtin_amdgcn_mfma_f32_16x16x32_bf16(xga1, WI[(20 + t) * 64 + lane], iN, 0,0,0);
      hR = __builtin_amdgcn_mfma_f32_16x16x32_bf16(xoa0, WH[(t     ) * 64 + lane], hR, 0,0,0);
      hR = __builtin_amdgcn_mfma_f32_16x16x32_bf16(xoa1, WH[(12 + t) * 64 + lane], hR, 0,0,0);
      hZ = __builtin_amdgcn_mfma_f32_16x16x32_bf16(xoa0, WH[(t +  4) * 64 + lane], hZ, 0,0,0);
      hZ = __builtin_amdgcn_mfma_f32_16x16x32_bf16(xoa1, WH[(16 + t) * 64 + lane], hZ, 0,0,0);
      hN = __builtin_amdgcn_mfma_f32_16x16x32_bf16(xoa0, WH[(t +  8) * 64 + lane], hN, 0,0,0);
      hN = __builtin_amdgcn_mfma_f32_16x16x32_bf16(xoa1, WH[(20 + t) * 64 + lane], hN, 0,0,0);
      int col = m + 16 * t;
      float biR = bih[col], biZ = bih[64 + col], biN = bih[128 + col];
      float bhR = bhh[col], bhZ = bhh[64 + col], bhN = bhh[128 + col];
      float w1c = w1[col], b1c = b1[col];
      float osp = 0.f;
#pragma unroll
      for (int r = 0; r < 4; r++){
        int node = n0 + g * 4 + r;
        float xon = lrelu(na[min(node, N - 1)] * w1c + b1c);
        float rg = 1.f / (1.f + __expf(-(iR[r] + biR + hR[r] + bhR)));
        float zg = 1.f / (1.f + __expf(-(iZ[r] + biZ + hZ[r] + bhZ)));
        float nn = tanhf(iN[r] + biN + rg * (hN[r] + bhN));
        float xn = fmaxf((1.f - zg) * nn + zg * xon, 0.f);
        if (node < N) osp += xn;
        xgl[wid][g * 4 + r][col] = (ushort)f2bfs(xn);
      }
      // column-sum partial for col: reduce across g later
      osp += __shfl_xor(osp, 16); osp += __shfl_xor(osp, 32);
      os4[t] += osp;
    }
    // read x2 tile back as A-fragments, apply wm
    bf8 x2a0 = *(const bf8*)&xgl[wid][m][g * 8];
    bf8 x2a1 = *(const bf8*)&xgl[wid][m][32 + g * 8];
    f32x4 xs_t[4];
#pragma unroll
    for (int t = 0; t < 4; t++){
      f32x4 acc = {0.f, 0.f, 0.f, 0.f};
      acc = __builtin_amdgcn_mfma_f32_16x16x32_bf16(x2a0, WM[t * 64 + lane], acc, 0, 0, 0);
      acc = __builtin_amdgcn_mfma_f32_16x16x32_bf16(x2a1, WM[(4 + t) * 64 + lane], acc, 0, 0, 0);
      xs_t[t] = acc;
    }
    float tpart[4] = {0.f, 0.f, 0.f, 0.f};
#pragma unroll
    for (int t = 0; t < 4; t++){
#pragma unroll
      for (int r = 0; r < 4; r++){
        int rw = n0 + g * 4 + r;
        if (rw < N) xsout[(size_t)rw * 64 + m + 16 * t] = xs_t[t][r];
        tpart[r] += xs_t[t][r] * as_t[t];
      }
    }
#pragma unroll
    for (int r = 0; r < 4; r++){
      float v = tpart[r];
      v += __shfl_xor(v, 1); v += __shfl_xor(v, 2);
      v += __shfl_xor(v, 4); v += __shfl_xor(v, 8);
      if (m == 0){
        int rw = n0 + g * 4 + r;
        if (rw < N){ tb[rw] = v; tmax = fmaxf(tmax, v); }
      }
    }
  }
  tmax = wave_max(tmax);
  if (lane == 0) atomicMax((unsigned*)(scal + 131), fkey(tmax));
  if (g == 0){
#pragma unroll
    for (int t = 0; t < 4; t++) osm[wid][m + 16 * t] = os4[t];
  }
  __syncthreads();
  if (threadIdx.x < 64)
    atomicAdd(&scal[threadIdx.x],
              osm[0][threadIdx.x] + osm[1][threadIdx.x] + osm[2][threadIdx.x] + osm[3][threadIdx.x]);
}

// ---------------- part2b (1 wave) ----------------
__global__ void k_part2b(float* __restrict__ scal, const float* __restrict__ wm_t,
                         const float* __restrict__ att_dst){
  int lane = threadIdx.x;
  float o = fmaxf(scal[lane], 0.f);
  float acc = 0.f;
  for (int k = 0; k < 64; k++) acc += bcast(o, k) * wm_t[k * 64 + lane];
  float c = wave_sum(acc * att_dst[lane]);
  scal[64 + lane] = o;
  if (lane == 0){
    scal[128] = c;
    float maxtb = funkey(*(unsigned*)(scal + 131));
    scal[130] = lrelu(maxtb + c);   // M = max_n lrelu(tb[n]+c)  (lrelu monotone)
  }
}

// ---------------- a2 weighted sums ----------------
__global__ void k_a2sum(const float* __restrict__ tb, const float* __restrict__ xs,
                        float* __restrict__ scal, int N){
  int lane = threadIdx.x & 63, w = threadIdx.x >> 6;
  int gw = blockIdx.x * 4 + w, nw = gridDim.x * 4;
  float c = scal[128];
  float M = scal[130];
  float hloc = 0.f, sloc = 0.f;
  for (int n = gw; n < N; n += nw){
    float a2 = lrelu(tb[n] + c);
    float wt = __expf(a2 - M);
    sloc += wt;
    hloc += wt * xs[(size_t)n * 64 + lane];
  }
  __shared__ float lds[256];
  __shared__ float sred[4];
  lds[threadIdx.x] = hloc;
  if (lane == 0) sred[w] = sloc;
  __syncthreads();
  if (threadIdx.x < 64)
    atomicAdd(&scal[192 + threadIdx.x],
              lds[threadIdx.x] + lds[64 + threadIdx.x] + lds[128 + threadIdx.x] + lds[192 + threadIdx.x]);
  if (threadIdx.x == 0) atomicAdd(&scal[129], sred[0] + sred[1] + sred[2] + sred[3]);
}

// ---------------- final (1 wave, coalesced transposed weights) ----------------
__global__ void k_final(const float* __restrict__ scal, const float* __restrict__ bm,
                        const float* __restrict__ g2ih_t, const float* __restrict__ g2hh_t,
                        const float* __restrict__ bih, const float* __restrict__ bhh,
                        const float* __restrict__ w2_t, const float* __restrict__ b2,
                        float* __restrict__ dout){
  int lane = threadIdx.x;
  float S  = scal[129];
  float h2 = scal[192 + lane] / S + bm[lane];
  float xg = h2 > 0.f ? h2 : __expf(h2) - 1.f;
  float xo = scal[64 + lane];
  float gir = bih[lane], giz = bih[64 + lane], gin = bih[128 + lane];
  float ghr = bhh[lane], ghz = bhh[64 + lane], ghn = bhh[128 + lane];
  for (int k = 0; k < 64; k++){
    float a = bcast(xg, k), b = bcast(xo, k);
    const float* gi = g2ih_t + k * 192;
    const float* gh = g2hh_t + k * 192;
    gir += a * gi[lane]; giz += a * gi[64 + lane]; gin += a * gi[128 + lane];
    ghr += b * gh[lane]; ghz += b * gh[64 + lane]; ghn += b * gh[128 + lane];
  }
  float r  = 1.f / (1.f + __expf(-(gir + ghr)));
  float z  = 1.f / (1.f + __expf(-(giz + ghz)));
  float nn = tanhf(gin + r * ghn);
  float o2 = fmaxf((1.f - z) * nn + z * xo, 0.f);
  float res = 0.f;
  for (int k = 0; k < 64; k++) res += bcast(o2, k) * w2_t[k * 64 + lane];
  dout[lane] = res + b2[lane];
}

extern "C" void kernel_launch(void* const* d_in, const int* in_sizes, int n_in,
                              void* d_out, int out_size, void* d_ws, size_t ws_size,
                              hipStream_t stream){
  const float* na    = (const float*)d_in[0];
  const float* ea    = (const float*)d_in[1];
  const int*   ei    = (const int*)d_in[2];
  const float* w1    = (const float*)d_in[3];
  const float* b1    = (const float*)d_in[4];
  const float* wg1   = (const float*)d_in[5];
  const float* att_l = (const float*)d_in[6];
  const float* att_r = (const float*)d_in[7];
  const float* wg2   = (const float*)d_in[8];
  const float* bg    = (const float*)d_in[9];
  const float* g1wih = (const float*)d_in[10];
  const float* g1whh = (const float*)d_in[11];
  const float* g1bih = (const float*)d_in[12];
  const float* g1bhh = (const float*)d_in[13];
  const float* wm      = (const float*)d_in[14];
  const float* att_src = (const float*)d_in[15];
  const float* att_dst = (const float*)d_in[16];
  const float* bm      = (const float*)d_in[17];
  const float* g2wih = (const float*)d_in[18];
  const float* g2whh = (const float*)d_in[19];
  const float* g2bih = (const float*)d_in[20];
  const float* g2bhh = (const float*)d_in[21];
  const float* w2    = (const float*)d_in[22];
  const float* b2    = (const float*)d_in[23];

  int N = in_sizes[0];
  int E = in_sizes[1];
  const int* srcArr = ei;
  const int* dstArr = ei + E;

  char* ws = (char*)d_ws;
  size_t cur = 0;
  auto alloc = [&](size_t nbytes) -> char* {
    char* p = ws + cur;
    cur += (nbytes + 255) & ~(size_t)255;
    return p;
  };
  ushort* yb   = (ushort*)alloc((size_t)N * 64 * 2);   // bf16 y
  float* bufC  = (float*)alloc((size_t)N * 64 * 4);    // sout -> xs
  float* xr    = (float*)alloc((size_t)N * 4);
  float* tb    = (float*)alloc((size_t)N * 4);
  int*   deg   = (int*)alloc((size_t)N * 4);
  int*   offA  = (int*)alloc((size_t)(N + 1) * 4);
  int*   part  = (int*)alloc(4096);
  int*   gtail = (int*)alloc(2048);
  int2*  csr   = (int2*)alloc((size_t)E * 8);
  int2*  tse   = (int2*)alloc((size_t)E * 8);
  float* scal  = (float*)alloc(4096);
  float* wm_t  = (float*)alloc(64 * 64 * 4);
  float* w2_t  = (float*)alloc(64 * 64 * 4);
  float* g2ih_t= (float*)alloc(64 * 192 * 4);
  float* g2hh_t= (float*)alloc(64 * 192 * 4);
  float* wgc   = (float*)alloc(64 * 4);
  ushort* wg2f = (ushort*)alloc(4096 * 2);
  ushort* wmf  = (ushort*)alloc(4096 * 2);
  ushort* wg1f = (ushort*)alloc(4096 * 2);
  ushort* wihf = (ushort*)alloc(12288 * 2);
  ushort* whhf = (ushort*)alloc(12288 * 2);
  if (cur > ws_size) return;

  hipMemsetAsync(deg,  0, (size_t)N * 4, stream);
  hipMemsetAsync(scal, 0, 4096, stream);

  k_wprep<<<64, 192, 0, stream>>>(wg1, wm, w2, g2wih, g2whh,
                                  wm_t, w2_t, g2ih_t, g2hh_t, wgc);
  k_wfrag<<<18, 256, 0, stream>>>(wg2, wm, wg1, g1wih, g1whh,
                                  wg2f, wmf, wg1f, wihf, whhf);

  k_node_m<<<512, 256, 0, stream>>>(na, w1, b1, wg1f, att_r, yb, xr, N);
  k_deg<<<(E + 255) / 256, 256, 0, stream>>>(dstArr, deg, E);
  int nb = (N + 1023) / 1024;
  k_scan1<<<nb, 1024, 0, stream>>>(deg, part, N);
  k_scan2<<<1, 1024, 0, stream>>>(part, nb, offA, N);
  k_scan3<<<nb, 1024, 0, stream>>>(deg, part, offA, N);
  int nbuck = (N + 511) >> BSHIFT;
  k_gtail<<<1, nbuck + 1, 0, stream>>>(offA, gtail, N, nbuck);
  k_binA<<<(E + 4095) / 4096, 256, 0, stream>>>(dstArr, srcArr, ea, gtail, tse, E);
  k_binB<<<nbuck, 256, 0, stream>>>(offA, tse, csr, N);
  int nwb2 = (N + 15) / 16;        // 4 waves/block, 4 nodes/wave
  k_edge_f<<<nwb2, 256, 0, stream>>>(offA, csr, yb, xr, wgc, att_l, bufC, N);
  k_gru2m<<<512, 256, 0, stream>>>(bufC, na, w1, b1, wg2f, bg, wihf, whhf,
                                   g1bih, g1bhh, wmf, att_src, bufC, tb, scal, N);
  k_part2b<<<1, 64, 0, stream>>>(scal, wm_t, att_dst);
  k_a2sum<<<512, 256, 0, stream>>>(tb, bufC, scal, N);
  k_final<<<1, 64, 0, stream>>>(scal, bm, g2ih_t, g2hh_t, g2bih, g2bhh, w2_t, b2, (float*)d_out);
  (void)n_in; (void)out_size;
}

// Round 12
// 314.016 us; speedup vs baseline: 6.2497x; 1.0001x over previous
//
#include <hip/hip_runtime.h>
#include <math.h>

typedef __attribute__((ext_vector_type(8))) short bf8;
typedef __attribute__((ext_vector_type(4))) float f32x4;

#define BSHIFT 9   // 512 nodes per bucket

__device__ __forceinline__ float lrelu(float v){ return fmaxf(v, 0.01f * v); }

__device__ __forceinline__ float wave_sum(float v){
#pragma unroll
  for (int s = 32; s > 0; s >>= 1) v += __shfl_xor(v, s);
  return v;
}
__device__ __forceinline__ float wave_max(float v){
#pragma unroll
  for (int s = 32; s > 0; s >>= 1) v = fmaxf(v, __shfl_xor(v, s));
  return v;
}

__device__ __forceinline__ float bcast(float v, int k){
  return __uint_as_float((unsigned)__builtin_amdgcn_readlane(__float_as_uint(v), k));
}

// float -> orderable unsigned key (monotone)
__device__ __forceinline__ unsigned fkey(float x){
  unsigned u = __float_as_uint(x);
  return (u & 0x80000000u) ? ~u : (u | 0x80000000u);
}
__device__ __forceinline__ float funkey(unsigned k){
  unsigned u = (k & 0x80000000u) ? (k & 0x7fffffffu) : ~k;
  return __uint_as_float(u);
}

// float -> bf16 (RNE)
__device__ __forceinline__ short f2bfs(float x){
  unsigned u = __float_as_uint(x);
  return (short)((u + 0x7fffu + ((u >> 16) & 1u)) >> 16);
}
__device__ __forceinline__ float bf2f(ushort v){
  return __uint_as_float((unsigned)v << 16);
}
__device__ __forceinline__ bf8 pack8(float4 a, float4 b){
  bf8 v;
  v[0]=f2bfs(a.x); v[1]=f2bfs(a.y); v[2]=f2bfs(a.z); v[3]=f2bfs(a.w);
  v[4]=f2bfs(b.x); v[5]=f2bfs(b.y); v[6]=f2bfs(b.z); v[7]=f2bfs(b.w);
  return v;
}
__device__ __forceinline__ float4 xo4(float nav, float4 w, float4 b){
  float4 r;
  r.x = lrelu(nav*w.x + b.x); r.y = lrelu(nav*w.y + b.y);
  r.z = lrelu(nav*w.z + b.z); r.w = lrelu(nav*w.w + b.w);
  return r;
}
__device__ __forceinline__ float dot4(float4 a, float4 b){
  return a.x*b.x + a.y*b.y + a.z*b.z + a.w*b.w;
}

// ---------------- weight transpose to k-major (small weights for 1-wave kernels) ----------------
__global__ void k_wprep(const float* __restrict__ wg1, const float* __restrict__ wm,
                        const float* __restrict__ w2,
                        const float* __restrict__ g2wih, const float* __restrict__ g2whh,
                        float* __restrict__ wm_t, float* __restrict__ w2_t,
                        float* __restrict__ g2ih_t, float* __restrict__ g2hh_t,
                        float* __restrict__ wgc){
  int k = blockIdx.x;      // 0..63
  int r = threadIdx.x;     // 0..191
  if (r < 64){
    wm_t [k * 64 + r] = wm [r * 64 + k];
    w2_t [k * 64 + r] = w2 [r * 64 + k];
    if (k == 0) wgc[r] = wg1[r * 65 + 64];
  }
  g2ih_t[k * 192 + r] = g2wih[r * 64 + k];
  g2hh_t[k * 192 + r] = g2whh[r * 64 + k];
}

// ---------------- pack weights into bf16 MFMA B-fragments ----------------
// B-frag slot (c, t, lane l, j) <- W[16t + (l&15)][32c + (l>>4)*8 + j], row stride S
__global__ void k_wfrag(const float* __restrict__ wg2, const float* __restrict__ wm,
                        const float* __restrict__ wg1,
                        const float* __restrict__ wih, const float* __restrict__ whh,
                        ushort* __restrict__ wg2f, ushort* __restrict__ wmf,
                        ushort* __restrict__ wg1f,
                        ushort* __restrict__ wihf, ushort* __restrict__ whhf){
  int tid = blockIdx.x * 256 + threadIdx.x;  // 0..4607
  if (tid >= 4608) return;
  const float* W; ushort* F; int T, S, base;
  if (tid < 512)      { W = wg2; F = wg2f; T = 4;  S = 64; base = tid; }
  else if (tid < 1024){ W = wm;  F = wmf;  T = 4;  S = 64; base = tid - 1024 + 512; }
  else if (tid < 1536){ W = wg1; F = wg1f; T = 4;  S = 65; base = tid - 1024; }
  else if (tid < 3072){ W = wih; F = wihf; T = 12; S = 64; base = tid - 1536; }
  else                { W = whh; F = whhf; T = 12; S = 64; base = tid - 3072; }
  int l  = base & 63;
  int ct = base >> 6;
  int c  = ct / T, t = ct - c * T;
  int row = 16 * t + (l & 15);
  int k0  = 32 * c + (l >> 4) * 8;
  const float* src = W + row * S + k0;
  unsigned o0 = (unsigned)(ushort)f2bfs(src[0]) | ((unsigned)(ushort)f2bfs(src[1]) << 16);
  unsigned o1 = (unsigned)(ushort)f2bfs(src[2]) | ((unsigned)(ushort)f2bfs(src[3]) << 16);
  unsigned o2 = (unsigned)(ushort)f2bfs(src[4]) | ((unsigned)(ushort)f2bfs(src[5]) << 16);
  unsigned o3 = (unsigned)(ushort)f2bfs(src[6]) | ((unsigned)(ushort)f2bfs(src[7]) << 16);
  ((uint4*)F)[base] = make_uint4(o0, o1, o2, o3);
}

// ---------------- node prep via MFMA: y(bf16) = x@wg1[:,:64].T, xr = dot(x, att_r) ----------------
__global__ __launch_bounds__(256) void k_node_m(
    const float* __restrict__ na, const float* __restrict__ w1,
    const float* __restrict__ b1, const ushort* __restrict__ wg1f,
    const float* __restrict__ att_r,
    ushort* __restrict__ yb, float* __restrict__ xr, int N){
  int lane = threadIdx.x & 63;
  int wid  = threadIdx.x >> 6;
  int m = lane & 15, g = lane >> 4;
  const bf8* WG = (const bf8*)wg1f;
  float4 w1a = *(const float4*)(w1 + g*8),      w1b = *(const float4*)(w1 + g*8 + 4);
  float4 w1c = *(const float4*)(w1 + 32 + g*8), w1d = *(const float4*)(w1 + 32 + g*8 + 4);
  float4 b1a = *(const float4*)(b1 + g*8),      b1b = *(const float4*)(b1 + g*8 + 4);
  float4 b1c = *(const float4*)(b1 + 32 + g*8), b1d = *(const float4*)(b1 + 32 + g*8 + 4);
  float4 ara = *(const float4*)(att_r + g*8),      arb = *(const float4*)(att_r + g*8 + 4);
  float4 arc = *(const float4*)(att_r + 32 + g*8), ard = *(const float4*)(att_r + 32 + g*8 + 4);
  int ntiles = (N + 15) >> 4;
  for (int tile = blockIdx.x * 4 + wid; tile < ntiles; tile += gridDim.x * 4){
    int n0 = tile * 16;
    int row = n0 + m;
    bool valid = row < N;
    float nav = valid ? na[row] : 0.f;
    float4 x0 = xo4(nav, w1a, b1a), x1 = xo4(nav, w1b, b1b);
    float4 x2 = xo4(nav, w1c, b1c), x3 = xo4(nav, w1d, b1d);
    float xa = dot4(x0, ara) + dot4(x1, arb) + dot4(x2, arc) + dot4(x3, ard);
    xa += __shfl_xor(xa, 16); xa += __shfl_xor(xa, 32);
    if (g == 0 && valid) xr[row] = xa;
    bf8 fa0 = pack8(x0, x1), fa1 = pack8(x2, x3);
    f32x4 yt[4];
#pragma unroll
    for (int t = 0; t < 4; t++){
      f32x4 acc = {0.f, 0.f, 0.f, 0.f};
      acc = __builtin_amdgcn_mfma_f32_16x16x32_bf16(fa0, WG[t * 64 + lane], acc, 0, 0, 0);
      acc = __builtin_amdgcn_mfma_f32_16x16x32_bf16(fa1, WG[(4 + t) * 64 + lane], acc, 0, 0, 0);
      yt[t] = acc;
    }
#pragma unroll
    for (int t = 0; t < 4; t++){
#pragma unroll
      for (int r = 0; r < 4; r++){
        int rw = n0 + g * 4 + r;
        if (rw < N) yb[(size_t)rw * 64 + m + 16 * t] = (ushort)f2bfs(yt[t][r]);
      }
    }
  }
}

// ---------------- CSR build ----------------
__global__ void k_deg(const int* __restrict__ dst, int* __restrict__ deg, int E){
  int e = blockIdx.x * 256 + threadIdx.x;
  if (e >= E) return;
  atomicAdd(&deg[dst[e]], 1);
}

__global__ void k_scan1(const int* __restrict__ deg, int* __restrict__ partial, int N){
  __shared__ int lds[1024];
  int gid = blockIdx.x * 1024 + threadIdx.x;
  lds[threadIdx.x] = (gid < N) ? deg[gid] : 0;
  __syncthreads();
  for (int s = 512; s > 0; s >>= 1){
    if (threadIdx.x < s) lds[threadIdx.x] += lds[threadIdx.x + s];
    __syncthreads();
  }
  if (threadIdx.x == 0) partial[blockIdx.x] = lds[0];
}

__global__ void k_scan2(int* __restrict__ partial, int nb, int* __restrict__ off, int N){
  __shared__ int lds[1024];
  int t = threadIdx.x;
  int v = (t < nb) ? partial[t] : 0;
  lds[t] = v;
  __syncthreads();
  for (int s = 1; s < 1024; s <<= 1){
    int tv = (t >= s) ? lds[t - s] : 0;
    __syncthreads();
    lds[t] += tv;
    __syncthreads();
  }
  if (t < nb) partial[t] = lds[t] - v;    // exclusive prefix
  if (t == 1023) off[N] = lds[1023];      // total = E
}

__global__ void k_scan3(const int* __restrict__ deg, const int* __restrict__ partial,
                        int* __restrict__ off, int N){
  __shared__ int lds[1024];
  int gid = blockIdx.x * 1024 + threadIdx.x;
  int v = (gid < N) ? deg[gid] : 0;
  lds[threadIdx.x] = v;
  __syncthreads();
  for (int s = 1; s < 1024; s <<= 1){
    int t = (threadIdx.x >= s) ? lds[threadIdx.x - s] : 0;
    __syncthreads();
    lds[threadIdx.x] += t;
    __syncthreads();
  }
  if (gid < N) off[gid] = partial[blockIdx.x] + lds[threadIdx.x] - v;
}

// gtail[b] = CSR offset of bucket b's first node
__global__ void k_gtail(const int* __restrict__ off, int* __restrict__ gtail,
                        int N, int nbuck){
  int b = threadIdx.x;
  if (b <= nbuck) gtail[b] = off[min(b << BSHIFT, N)];
}

// ---------------- binned scatter phase A: group edges by dst-bucket (tail-append)
// packed 8B record: {src | drel<<17, ea-bits}
__global__ __launch_bounds__(256) void k_binA(
    const int* __restrict__ dst, const int* __restrict__ src,
    const float* __restrict__ ea, int* __restrict__ gtail,
    int2* __restrict__ tse, int E){
  __shared__ int hist[256], base[256], run[256];
  int e0 = blockIdx.x * 4096;
  int e1 = min(e0 + 4096, E);
  hist[threadIdx.x] = 0; run[threadIdx.x] = 0;
  __syncthreads();
  for (int i = e0 + threadIdx.x; i < e1; i += 256)
    atomicAdd(&hist[dst[i] >> BSHIFT], 1);
  __syncthreads();
  if (hist[threadIdx.x] > 0)
    base[threadIdx.x] = atomicAdd(&gtail[threadIdx.x], hist[threadIdx.x]);
  __syncthreads();
  for (int i = e0 + threadIdx.x; i < e1; i += 256){
    int d = dst[i];
    int b = d >> BSHIFT;
    int pos = base[b] + atomicAdd(&run[b], 1);
    tse[pos] = make_int2(src[i] | ((d & 511) << 17), __float_as_int(ea[i]));
  }
}

// ---------------- binned scatter phase B: place within bucket (LDS fill counters) ----------------
__global__ __launch_bounds__(256) void k_binB(
    const int* __restrict__ off, const int2* __restrict__ tse,
    int2* __restrict__ csr, int N){
  __shared__ int fillL[512];
  int node0 = blockIdx.x << BSHIFT;
  int node1 = min(node0 + 512, N);
  int nn = node1 - node0;
  for (int j = threadIdx.x; j < nn; j += 256) fillL[j] = off[node0 + j];
  __syncthreads();
  int i0 = off[node0], i1 = off[node1];
  for (int i = i0 + threadIdx.x; i < i1; i += 256){
    int2 t = tse[i];
    int drel = (t.x >> 17) & 511;
    int pos = atomicAdd(&fillL[drel], 1);
    csr[pos] = make_int2(t.x & 0x1FFFF, t.y);
  }
}

// ---------------- fused edge kernel: 4 nodes/wave, 16 lanes/node, no-max softmax
// (values bounded ~[-1,2] at this model scale -> exp never overflows; softmax shift-invariant)
__global__ void k_edge_f(const int* __restrict__ off, const int2* __restrict__ csr,
                         const ushort* __restrict__ yb, const float* __restrict__ xr,
                         const float* __restrict__ wgc, const float* __restrict__ att_l,
                         float* __restrict__ sout, int N){
  int lane = threadIdx.x & 63;
  int wwid = (blockIdx.x * blockDim.x + threadIdx.x) >> 6;
  int g = lane >> 4, sl = lane & 15;
  int node = wwid * 4 + g;
  if (node >= N) return;
  int i0 = off[node], i1 = off[node + 1];
  float4 wc4 = ((const float4*)wgc)[sl];
  float4 al4 = ((const float4*)att_l)[sl];
  float xrn = xr[node];
  float sg = 0.f;
  float4 acc = make_float4(0.f, 0.f, 0.f, 0.f);
  for (int i = i0; i < i1; i++){
    int2 rec = csr[i];
    float ea = __int_as_float(rec.y);
    ushort4 yv = ((const ushort4*)(yb + (size_t)rec.x * 64))[sl];
    float4 he;
    float t0 = bf2f(yv.x) + ea * wc4.x; he.x = lrelu(t0);
    float t1 = bf2f(yv.y) + ea * wc4.y; he.y = lrelu(t1);
    float t2 = bf2f(yv.z) + ea * wc4.z; he.z = lrelu(t2);
    float t3 = bf2f(yv.w) + ea * wc4.w; he.w = lrelu(t3);
    float p = dot4(he, al4);
    p += __shfl_xor(p, 1); p += __shfl_xor(p, 2);
    p += __shfl_xor(p, 4); p += __shfl_xor(p, 8);
    float a = lrelu(p + xrn);
    float w = __expf(a);
    sg += w;
    acc.x += w * he.x; acc.y += w * he.y;
    acc.z += w * he.z; acc.w += w * he.w;
  }
  float inv = (i1 > i0 && sg > 0.f) ? 1.f / sg : 0.f;
  float4 o = make_float4(acc.x * inv, acc.y * inv, acc.z * inv, acc.w * inv);
  ((float4*)(sout + (size_t)node * 64))[sl] = o;
}

// ---------------- GRU1 via MFMA: block = 64 nodes, wave = 16-node M-tile ----------------
__global__ __launch_bounds__(256) void k_gru1m(
    const float* __restrict__ sout, const float* __restrict__ na,
    const float* __restrict__ w1, const float* __restrict__ b1,
    const ushort* __restrict__ wg2f, const float* __restrict__ bg,
    const ushort* __restrict__ wihf, const ushort* __restrict__ whhf,
    const float* __restrict__ bih, const float* __restrict__ bhh,
    float* __restrict__ x2, int N){
  __shared__ ushort xgl[4][16][72];   // per-wave elu(h) tile, bf16, padded rows
  int lane = threadIdx.x & 63;
  int wid  = threadIdx.x >> 6;
  int m = lane & 15, g = lane >> 4;
  int n0 = blockIdx.x * 64 + wid * 16;
  if (n0 >= N) return;                 // no barriers used -> safe early exit
  int rowc = min(n0 + m, N - 1);
  const float* srow = sout + (size_t)rowc * 64;
  bf8 sa0 = pack8(*(const float4*)(srow + g * 8),      *(const float4*)(srow + g * 8 + 4));
  bf8 sa1 = pack8(*(const float4*)(srow + 32 + g * 8), *(const float4*)(srow + 32 + g * 8 + 4));
  const bf8* WG = (const bf8*)wg2f;
  f32x4 h[4];
#pragma unroll
  for (int t = 0; t < 4; t++){
    f32x4 acc = {0.f, 0.f, 0.f, 0.f};
    acc = __builtin_amdgcn_mfma_f32_16x16x32_bf16(sa0, WG[t * 64 + lane], acc, 0, 0, 0);
    acc = __builtin_amdgcn_mfma_f32_16x16x32_bf16(sa1, WG[(4 + t) * 64 + lane], acc, 0, 0, 0);
    h[t] = acc;
  }
#pragma unroll
  for (int t = 0; t < 4; t++){
    float bgc = bg[m + 16 * t];
#pragma unroll
    for (int r = 0; r < 4; r++){
      float hv = h[t][r] + bgc;
      float xg = hv > 0.f ? hv : __expf(hv) - 1.f;
      xgl[wid][g * 4 + r][m + 16 * t] = (ushort)f2bfs(xg);
    }
  }
  float nav = na[rowc];
  bf8 xoa0 = pack8(xo4(nav, *(const float4*)(w1 + g * 8),      *(const float4*)(b1 + g * 8)),
                   xo4(nav, *(const float4*)(w1 + g * 8 + 4),  *(const float4*)(b1 + g * 8 + 4)));
  bf8 xoa1 = pack8(xo4(nav, *(const float4*)(w1 + 32 + g * 8),     *(const float4*)(b1 + 32 + g * 8)),
                   xo4(nav, *(const float4*)(w1 + 32 + g * 8 + 4), *(const float4*)(b1 + 32 + g * 8 + 4)));
  bf8 xga0 = *(const bf8*)&xgl[wid][m][g * 8];
  bf8 xga1 = *(const bf8*)&xgl[wid][m][32 + g * 8];
  const bf8* WI = (const bf8*)wihf;
  const bf8* WH = (const bf8*)whhf;
#pragma unroll
  for (int t = 0; t < 4; t++){
    f32x4 iR = {0.f,0.f,0.f,0.f}, iZ = iR, iN = iR, hR = iR, hZ = iR, hN = iR;
    iR = __builtin_amdgcn_mfma_f32_16x16x32_bf16(xga0, WI[(t     ) * 64 + lane], iR, 0,0,0);
    iR = __builtin_amdgcn_mfma_f32_16x16x32_bf16(xga1, WI[(12 + t) * 64 + lane], iR, 0,0,0);
    iZ = __builtin_amdgcn_mfma_f32_16x16x32_bf16(xga0, WI[(t +  4) * 64 + lane], iZ, 0,0,0);
    iZ = __builtin_amdgcn_mfma_f32_16x16x32_bf16(xga1, WI[(16 + t) * 64 + lane], iZ, 0,0,0);
    iN = __builtin_amdgcn_mfma_f32_16x16x32_bf16(xga0, WI[(t +  8) * 64 + lane], iN, 0,0,0);
    iN = __builtin_amdgcn_mfma_f32_16x16x32_bf16(xga1, WI[(20 + t) * 64 + lane], iN, 0,0,0);
    hR = __builtin_amdgcn_mfma_f32_16x16x32_bf16(xoa0, WH[(t     ) * 64 + lane], hR, 0,0,0);
    hR = __builtin_amdgcn_mfma_f32_16x16x32_bf16(xoa1, WH[(12 + t) * 64 + lane], hR, 0,0,0);
    hZ = __builtin_amdgcn_mfma_f32_16x16x32_bf16(xoa0, WH[(t +  4) * 64 + lane], hZ, 0,0,0);
    hZ = __builtin_amdgcn_mfma_f32_16x16x32_bf16(xoa1, WH[(16 + t) * 64 + lane], hZ, 0,0,0);
    hN = __builtin_amdgcn_mfma_f32_16x16x32_bf16(xoa0, WH[(t +  8) * 64 + lane], hN, 0,0,0);
    hN = __builtin_amdgcn_mfma_f32_16x16x32_bf16(xoa1, WH[(20 + t) * 64 + lane], hN, 0,0,0);
    int col = m + 16 * t;
    float biR = bih[col], biZ = bih[64 + col], biN = bih[128 + col];
    float bhR = bhh[col], bhZ = bhh[64 + col], bhN = bhh[128 + col];
    float w1c = w1[col], b1c = b1[col];
#pragma unroll
    for (int r = 0; r < 4; r++){
      int node = n0 + g * 4 + r;
      if (node < N){
        float xon = lrelu(na[node] * w1c + b1c);
        float rg = 1.f / (1.f + __expf(-(iR[r] + biR + hR[r] + bhR)));
        float zg = 1.f / (1.f + __expf(-(iZ[r] + biZ + hZ[r] + bhZ)));
        float nn = tanhf(iN[r] + biN + rg * (hN[r] + bhN));
        float xn = (1.f - zg) * nn + zg * xon;
        x2[(size_t)node * 64 + col] = fmaxf(xn, 0.f);
      }
    }
  }
}

// ---------------- part2 via MFMA: xs = x2@wm.T (in-place), tb, osum, max(tb) ----------------
__global__ __launch_bounds__(256) void k_part2m(
    float* __restrict__ xb,            // in: x2 rows; out: xs rows (in-place per tile)
    const ushort* __restrict__ wmf, const float* __restrict__ att_src,
    float* __restrict__ tb, float* __restrict__ scal, int N){
  int lane = threadIdx.x & 63;
  int wid  = threadIdx.x >> 6;
  int m = lane & 15, g = lane >> 4;
  const bf8* WM = (const bf8*)wmf;
  float as_t[4];
#pragma unroll
  for (int t = 0; t < 4; t++) as_t[t] = att_src[m + 16 * t];
  float os[16];
#pragma unroll
  for (int j = 0; j < 16; j++) os[j] = 0.f;
  float tmax = -1e30f;
  int ntiles = (N + 15) >> 4;
  for (int tile = blockIdx.x * 4 + wid; tile < ntiles; tile += gridDim.x * 4){
    int n0 = tile * 16;
    int row = n0 + m;
    bool valid = row < N;
    int rowc = valid ? row : (N - 1);
    const float* xrow = xb + (size_t)rowc * 64;
    float4 a0 = *(const float4*)(xrow + g * 8);
    float4 a1 = *(const float4*)(xrow + g * 8 + 4);
    float4 a2 = *(const float4*)(xrow + 32 + g * 8);
    float4 a3 = *(const float4*)(xrow + 32 + g * 8 + 4);
    if (!valid){ a0 = make_float4(0,0,0,0); a1 = a0; a2 = a0; a3 = a0; }
    os[0]+=a0.x; os[1]+=a0.y; os[2]+=a0.z; os[3]+=a0.w;
    os[4]+=a1.x; os[5]+=a1.y; os[6]+=a1.z; os[7]+=a1.w;
    os[8]+=a2.x; os[9]+=a2.y; os[10]+=a2.z; os[11]+=a2.w;
    os[12]+=a3.x; os[13]+=a3.y; os[14]+=a3.z; os[15]+=a3.w;
    bf8 fa0 = pack8(a0, a1), fa1 = pack8(a2, a3);
    f32x4 xs_t[4];
#pragma unroll
    for (int t = 0; t < 4; t++){
      f32x4 acc = {0.f, 0.f, 0.f, 0.f};
      acc = __builtin_amdgcn_mfma_f32_16x16x32_bf16(fa0, WM[t * 64 + lane], acc, 0, 0, 0);
      acc = __builtin_amdgcn_mfma_f32_16x16x32_bf16(fa1, WM[(4 + t) * 64 + lane], acc, 0, 0, 0);
      xs_t[t] = acc;
    }
    float tpart[4] = {0.f, 0.f, 0.f, 0.f};
#pragma unroll
    for (int t = 0; t < 4; t++){
#pragma unroll
      for (int r = 0; r < 4; r++){
        int rw = n0 + g * 4 + r;
        if (rw < N) xb[(size_t)rw * 64 + m + 16 * t] = xs_t[t][r];
        tpart[r] += xs_t[t][r] * as_t[t];
      }
    }
#pragma unroll
    for (int r = 0; r < 4; r++){
      float v = tpart[r];
      v += __shfl_xor(v, 1); v += __shfl_xor(v, 2);
      v += __shfl_xor(v, 4); v += __shfl_xor(v, 8);
      if (m == 0){
        int rw = n0 + g * 4 + r;
        if (rw < N){ tb[rw] = v; tmax = fmaxf(tmax, v); }
      }
    }
  }
  tmax = wave_max(tmax);
  if (lane == 0) atomicMax((unsigned*)(scal + 131), fkey(tmax));
#pragma unroll
  for (int j = 0; j < 16; j++){
    float v = os[j];
    v += __shfl_xor(v, 1); v += __shfl_xor(v, 2);
    v += __shfl_xor(v, 4); v += __shfl_xor(v, 8);
    os[j] = v;
  }
  __shared__ float osm[4][64];
  if (m == 0){
#pragma unroll
    for (int j = 0; j < 8; j++){
      osm[wid][g * 8 + j]      = os[j];
      osm[wid][32 + g * 8 + j] = os[8 + j];
    }
  }
  __syncthreads();
  if (threadIdx.x < 64)
    atomicAdd(&scal[threadIdx.x],
              osm[0][threadIdx.x] + osm[1][threadIdx.x] + osm[2][threadIdx.x] + osm[3][threadIdx.x]);
}

// ---------------- part2b (1 wave) ----------------
__global__ void k_part2b(float* __restrict__ scal, const float* __restrict__ wm_t,
                         const float* __restrict__ att_dst){
  int lane = threadIdx.x;
  float o = fmaxf(scal[lane], 0.f);
  float acc = 0.f;
  for (int k = 0; k < 64; k++) acc += bcast(o, k) * wm_t[k * 64 + lane];
  float c = wave_sum(acc * att_dst[lane]);
  scal[64 + lane] = o;
  if (lane == 0){
    scal[128] = c;
    float maxtb = funkey(*(unsigned*)(scal + 131));
    scal[130] = lrelu(maxtb + c);   // M = max_n lrelu(tb[n]+c)  (lrelu monotone)
  }
}

// ---------------- a2 weighted sums ----------------
__global__ void k_a2sum(const float* __restrict__ tb, const float* __restrict__ xs,
                        float* __restrict__ scal, int N){
  int lane = threadIdx.x & 63, w = threadIdx.x >> 6;
  int gw = blockIdx.x * 4 + w, nw = gridDim.x * 4;
  float c = scal[128];
  float M = scal[130];
  float hloc = 0.f, sloc = 0.f;
  for (int n = gw; n < N; n += nw){
    float a2 = lrelu(tb[n] + c);
    float wt = __expf(a2 - M);
    sloc += wt;
    hloc += wt * xs[(size_t)n * 64 + lane];
  }
  __shared__ float lds[256];
  __shared__ float sred[4];
  lds[threadIdx.x] = hloc;
  if (lane == 0) sred[w] = sloc;
  __syncthreads();
  if (threadIdx.x < 64)
    atomicAdd(&scal[192 + threadIdx.x],
              lds[threadIdx.x] + lds[64 + threadIdx.x] + lds[128 + threadIdx.x] + lds[192 + threadIdx.x]);
  if (threadIdx.x == 0) atomicAdd(&scal[129], sred[0] + sred[1] + sred[2] + sred[3]);
}

// ---------------- final (1 wave, coalesced transposed weights) ----------------
__global__ void k_final(const float* __restrict__ scal, const float* __restrict__ bm,
                        const float* __restrict__ g2ih_t, const float* __restrict__ g2hh_t,
                        const float* __restrict__ bih, const float* __restrict__ bhh,
                        const float* __restrict__ w2_t, const float* __restrict__ b2,
                        float* __restrict__ dout){
  int lane = threadIdx.x;
  float S  = scal[129];
  float h2 = scal[192 + lane] / S + bm[lane];
  float xg = h2 > 0.f ? h2 : __expf(h2) - 1.f;
  float xo = scal[64 + lane];
  float gir = bih[lane], giz = bih[64 + lane], gin = bih[128 + lane];
  float ghr = bhh[lane], ghz = bhh[64 + lane], ghn = bhh[128 + lane];
  for (int k = 0; k < 64; k++){
    float a = bcast(xg, k), b = bcast(xo, k);
    const float* gi = g2ih_t + k * 192;
    const float* gh = g2hh_t + k * 192;
    gir += a * gi[lane]; giz += a * gi[64 + lane]; gin += a * gi[128 + lane];
    ghr += b * gh[lane]; ghz += b * gh[64 + lane]; ghn += b * gh[128 + lane];
  }
  float r  = 1.f / (1.f + __expf(-(gir + ghr)));
  float z  = 1.f / (1.f + __expf(-(giz + ghz)));
  float nn = tanhf(gin + r * ghn);
  float o2 = fmaxf((1.f - z) * nn + z * xo, 0.f);
  float res = 0.f;
  for (int k = 0; k < 64; k++) res += bcast(o2, k) * w2_t[k * 64 + lane];
  dout[lane] = res + b2[lane];
}

extern "C" void kernel_launch(void* const* d_in, const int* in_sizes, int n_in,
                              void* d_out, int out_size, void* d_ws, size_t ws_size,
                              hipStream_t stream){
  const float* na    = (const float*)d_in[0];
  const float* ea    = (const float*)d_in[1];
  const int*   ei    = (const int*)d_in[2];
  const float* w1    = (const float*)d_in[3];
  const float* b1    = (const float*)d_in[4];
  const float* wg1   = (const float*)d_in[5];
  const float* att_l = (const float*)d_in[6];
  const float* att_r = (const float*)d_in[7];
  const float* wg2   = (const float*)d_in[8];
  const float* bg    = (const float*)d_in[9];
  const float* g1wih = (const float*)d_in[10];
  const float* g1whh = (const float*)d_in[11];
  const float* g1bih = (const float*)d_in[12];
  const float* g1bhh = (const float*)d_in[13];
  const float* wm      = (const float*)d_in[14];
  const float* att_src = (const float*)d_in[15];
  const float* att_dst = (const float*)d_in[16];
  const float* bm      = (const float*)d_in[17];
  const float* g2wih = (const float*)d_in[18];
  const float* g2whh = (const float*)d_in[19];
  const float* g2bih = (const float*)d_in[20];
  const float* g2bhh = (const float*)d_in[21];
  const float* w2    = (const float*)d_in[22];
  const float* b2    = (const float*)d_in[23];

  int N = in_sizes[0];
  int E = in_sizes[1];
  const int* srcArr = ei;
  const int* dstArr = ei + E;

  char* ws = (char*)d_ws;
  size_t cur = 0;
  auto alloc = [&](size_t nbytes) -> char* {
    char* p = ws + cur;
    cur += (nbytes + 255) & ~(size_t)255;
    return p;
  };
  ushort* yb   = (ushort*)alloc((size_t)N * 64 * 2);   // bf16 y
  float* bufC  = (float*)alloc((size_t)N * 64 * 4);    // sout -> x2 -> xs
  float* xr    = (float*)alloc((size_t)N * 4);
  float* tb    = (float*)alloc((size_t)N * 4);
  int*   deg   = (int*)alloc((size_t)N * 4);
  int*   offA  = (int*)alloc((size_t)(N + 1) * 4);
  int*   part  = (int*)alloc(4096);
  int*   gtail = (int*)alloc(2048);
  int2*  csr   = (int2*)alloc((size_t)E * 8);
  int2*  tse   = (int2*)alloc((size_t)E * 8);
  float* scal  = (float*)alloc(4096);
  float* wm_t  = (float*)alloc(64 * 64 * 4);
  float* w2_t  = (float*)alloc(64 * 64 * 4);
  float* g2ih_t= (float*)alloc(64 * 192 * 4);
  float* g2hh_t= (float*)alloc(64 * 192 * 4);
  float* wgc   = (float*)alloc(64 * 4);
  ushort* wg2f = (ushort*)alloc(4096 * 2);
  ushort* wmf  = (ushort*)alloc(4096 * 2);
  ushort* wg1f = (ushort*)alloc(4096 * 2);
  ushort* wihf = (ushort*)alloc(12288 * 2);
  ushort* whhf = (ushort*)alloc(12288 * 2);
  if (cur > ws_size) return;

  hipMemsetAsync(deg,  0, (size_t)N * 4, stream);
  hipMemsetAsync(scal, 0, 4096, stream);

  k_wprep<<<64, 192, 0, stream>>>(wg1, wm, w2, g2wih, g2whh,
                                  wm_t, w2_t, g2ih_t, g2hh_t, wgc);
  k_wfrag<<<18, 256, 0, stream>>>(wg2, wm, wg1, g1wih, g1whh,
                                  wg2f, wmf, wg1f, wihf, whhf);

  k_node_m<<<512, 256, 0, stream>>>(na, w1, b1, wg1f, att_r, yb, xr, N);
  k_deg<<<(E + 255) / 256, 256, 0, stream>>>(dstArr, deg, E);
  int nb = (N + 1023) / 1024;
  k_scan1<<<nb, 1024, 0, stream>>>(deg, part, N);
  k_scan2<<<1, 1024, 0, stream>>>(part, nb, offA, N);
  k_scan3<<<nb, 1024, 0, stream>>>(deg, part, offA, N);
  int nbuck = (N + 511) >> BSHIFT;
  k_gtail<<<1, nbuck + 1, 0, stream>>>(offA, gtail, N, nbuck);
  k_binA<<<(E + 4095) / 4096, 256, 0, stream>>>(dstArr, srcArr, ea, gtail, tse, E);
  k_binB<<<nbuck, 256, 0, stream>>>(offA, tse, csr, N);
  int nwb2 = (N + 15) / 16;        // 4 waves/block, 4 nodes/wave
  k_edge_f<<<nwb2, 256, 0, stream>>>(offA, csr, yb, xr, wgc, att_l, bufC, N);
  int ngb = (N + 63) / 64;         // 4 waves/block, 16 nodes/wave (MFMA)
  k_gru1m<<<ngb, 256, 0, stream>>>(bufC, na, w1, b1, wg2f, bg, wihf, whhf,
                                   g1bih, g1bhh, bufC, N);
  k_part2m<<<512, 256, 0, stream>>>(bufC, wmf, att_src, tb, scal, N);
  k_part2b<<<1, 64, 0, stream>>>(scal, wm_t, att_dst);
  k_a2sum<<<512, 256, 0, stream>>>(tb, bufC, scal, N);
  k_final<<<1, 64, 0, stream>>>(scal, bm, g2ih_t, g2hh_t, g2bih, g2bhh, w2_t, b2, (float*)d_out);
  (void)n_in; (void)out_size;
}

// Round 13
// 297.646 us; speedup vs baseline: 6.5934x; 1.0550x over previous
//
#include <hip/hip_runtime.h>
#include <math.h>

typedef __attribute__((ext_vector_type(8))) short bf8;
typedef __attribute__((ext_vector_type(4))) float f32x4;

#define BSHIFT 9   // 512 nodes per bucket

__device__ __forceinline__ float lrelu(float v){ return fmaxf(v, 0.01f * v); }

__device__ __forceinline__ float wave_sum(float v){
#pragma unroll
  for (int s = 32; s > 0; s >>= 1) v += __shfl_xor(v, s);
  return v;
}
__device__ __forceinline__ float wave_max(float v){
#pragma unroll
  for (int s = 32; s > 0; s >>= 1) v = fmaxf(v, __shfl_xor(v, s));
  return v;
}

__device__ __forceinline__ float bcast(float v, int k){
  return __uint_as_float((unsigned)__builtin_amdgcn_readlane(__float_as_uint(v), k));
}

// float -> orderable unsigned key (monotone)
__device__ __forceinline__ unsigned fkey(float x){
  unsigned u = __float_as_uint(x);
  return (u & 0x80000000u) ? ~u : (u | 0x80000000u);
}
__device__ __forceinline__ float funkey(unsigned k){
  unsigned u = (k & 0x80000000u) ? (k & 0x7fffffffu) : ~k;
  return __uint_as_float(u);
}

// float -> bf16 (RNE)
__device__ __forceinline__ short f2bfs(float x){
  unsigned u = __float_as_uint(x);
  return (short)((u + 0x7fffu + ((u >> 16) & 1u)) >> 16);
}
__device__ __forceinline__ float bf2f(ushort v){
  return __uint_as_float((unsigned)v << 16);
}
__device__ __forceinline__ bf8 pack8(float4 a, float4 b){
  bf8 v;
  v[0]=f2bfs(a.x); v[1]=f2bfs(a.y); v[2]=f2bfs(a.z); v[3]=f2bfs(a.w);
  v[4]=f2bfs(b.x); v[5]=f2bfs(b.y); v[6]=f2bfs(b.z); v[7]=f2bfs(b.w);
  return v;
}
__device__ __forceinline__ float4 xo4(float nav, float4 w, float4 b){
  float4 r;
  r.x = lrelu(nav*w.x + b.x); r.y = lrelu(nav*w.y + b.y);
  r.z = lrelu(nav*w.z + b.z); r.w = lrelu(nav*w.w + b.w);
  return r;
}
__device__ __forceinline__ float dot4(float4 a, float4 b){
  return a.x*b.x + a.y*b.y + a.z*b.z + a.w*b.w;
}

// ---------------- weight transpose to k-major (small weights for 1-wave kernels) ----------------
__global__ void k_wprep(const float* __restrict__ wg1, const float* __restrict__ wm,
                        const float* __restrict__ w2,
                        const float* __restrict__ g2wih, const float* __restrict__ g2whh,
                        float* __restrict__ wm_t, float* __restrict__ w2_t,
                        float* __restrict__ g2ih_t, float* __restrict__ g2hh_t,
                        float* __restrict__ wgc){
  int k = blockIdx.x;      // 0..63
  int r = threadIdx.x;     // 0..191
  if (r < 64){
    wm_t [k * 64 + r] = wm [r * 64 + k];
    w2_t [k * 64 + r] = w2 [r * 64 + k];
    if (k == 0) wgc[r] = wg1[r * 65 + 64];
  }
  g2ih_t[k * 192 + r] = g2wih[r * 64 + k];
  g2hh_t[k * 192 + r] = g2whh[r * 64 + k];
}

// ---------------- pack weights into bf16 MFMA B-fragments ----------------
// B-frag slot (c, t, lane l, j) <- W[16t + (l&15)][32c + (l>>4)*8 + j], row stride S
__global__ void k_wfrag(const float* __restrict__ wg2, const float* __restrict__ wm,
                        const float* __restrict__ wg1,
                        const float* __restrict__ wih, const float* __restrict__ whh,
                        ushort* __restrict__ wg2f, ushort* __restrict__ wmf,
                        ushort* __restrict__ wg1f,
                        ushort* __restrict__ wihf, ushort* __restrict__ whhf){
  int tid = blockIdx.x * 256 + threadIdx.x;  // 0..4607
  if (tid >= 4608) return;
  const float* W; ushort* F; int T, S, base;
  if (tid < 512)      { W = wg2; F = wg2f; T = 4;  S = 64; base = tid; }
  else if (tid < 1024){ W = wm;  F = wmf;  T = 4;  S = 64; base = tid - 1024 + 512; }
  else if (tid < 1536){ W = wg1; F = wg1f; T = 4;  S = 65; base = tid - 1024; }
  else if (tid < 3072){ W = wih; F = wihf; T = 12; S = 64; base = tid - 1536; }
  else                { W = whh; F = whhf; T = 12; S = 64; base = tid - 3072; }
  int l  = base & 63;
  int ct = base >> 6;
  int c  = ct / T, t = ct - c * T;
  int row = 16 * t + (l & 15);
  int k0  = 32 * c + (l >> 4) * 8;
  const float* src = W + row * S + k0;
  unsigned o0 = (unsigned)(ushort)f2bfs(src[0]) | ((unsigned)(ushort)f2bfs(src[1]) << 16);
  unsigned o1 = (unsigned)(ushort)f2bfs(src[2]) | ((unsigned)(ushort)f2bfs(src[3]) << 16);
  unsigned o2 = (unsigned)(ushort)f2bfs(src[4]) | ((unsigned)(ushort)f2bfs(src[5]) << 16);
  unsigned o3 = (unsigned)(ushort)f2bfs(src[6]) | ((unsigned)(ushort)f2bfs(src[7]) << 16);
  ((uint4*)F)[base] = make_uint4(o0, o1, o2, o3);
}

// ---------------- node prep via MFMA: y(bf16) = x@wg1[:,:64].T, xr = dot(x, att_r) ----------------
__global__ __launch_bounds__(256) void k_node_m(
    const float* __restrict__ na, const float* __restrict__ w1,
    const float* __restrict__ b1, const ushort* __restrict__ wg1f,
    const float* __restrict__ att_r,
    ushort* __restrict__ yb, float* __restrict__ xr, int N){
  int lane = threadIdx.x & 63;
  int wid  = threadIdx.x >> 6;
  int m = lane & 15, g = lane >> 4;
  const bf8* WG = (const bf8*)wg1f;
  float4 w1a = *(const float4*)(w1 + g*8),      w1b = *(const float4*)(w1 + g*8 + 4);
  float4 w1c = *(const float4*)(w1 + 32 + g*8), w1d = *(const float4*)(w1 + 32 + g*8 + 4);
  float4 b1a = *(const float4*)(b1 + g*8),      b1b = *(const float4*)(b1 + g*8 + 4);
  float4 b1c = *(const float4*)(b1 + 32 + g*8), b1d = *(const float4*)(b1 + 32 + g*8 + 4);
  float4 ara = *(const float4*)(att_r + g*8),      arb = *(const float4*)(att_r + g*8 + 4);
  float4 arc = *(const float4*)(att_r + 32 + g*8), ard = *(const float4*)(att_r + 32 + g*8 + 4);
  int ntiles = (N + 15) >> 4;
  for (int tile = blockIdx.x * 4 + wid; tile < ntiles; tile += gridDim.x * 4){
    int n0 = tile * 16;
    int row = n0 + m;
    bool valid = row < N;
    float nav = valid ? na[row] : 0.f;
    float4 x0 = xo4(nav, w1a, b1a), x1 = xo4(nav, w1b, b1b);
    float4 x2 = xo4(nav, w1c, b1c), x3 = xo4(nav, w1d, b1d);
    float xa = dot4(x0, ara) + dot4(x1, arb) + dot4(x2, arc) + dot4(x3, ard);
    xa += __shfl_xor(xa, 16); xa += __shfl_xor(xa, 32);
    if (g == 0 && valid) xr[row] = xa;
    bf8 fa0 = pack8(x0, x1), fa1 = pack8(x2, x3);
    f32x4 yt[4];
#pragma unroll
    for (int t = 0; t < 4; t++){
      f32x4 acc = {0.f, 0.f, 0.f, 0.f};
      acc = __builtin_amdgcn_mfma_f32_16x16x32_bf16(fa0, WG[t * 64 + lane], acc, 0, 0, 0);
      acc = __builtin_amdgcn_mfma_f32_16x16x32_bf16(fa1, WG[(4 + t) * 64 + lane], acc, 0, 0, 0);
      yt[t] = acc;
    }
#pragma unroll
    for (int t = 0; t < 4; t++){
#pragma unroll
      for (int r = 0; r < 4; r++){
        int rw = n0 + g * 4 + r;
        if (rw < N) yb[(size_t)rw * 64 + m + 16 * t] = (ushort)f2bfs(yt[t][r]);
      }
    }
  }
}

// ---------------- CSR build ----------------
__global__ void k_deg(const int* __restrict__ dst, int* __restrict__ deg, int E){
  int e = blockIdx.x * 256 + threadIdx.x;
  if (e >= E) return;
  atomicAdd(&deg[dst[e]], 1);
}

__global__ void k_scan1(const int* __restrict__ deg, int* __restrict__ partial, int N){
  __shared__ int lds[1024];
  int gid = blockIdx.x * 1024 + threadIdx.x;
  lds[threadIdx.x] = (gid < N) ? deg[gid] : 0;
  __syncthreads();
  for (int s = 512; s > 0; s >>= 1){
    if (threadIdx.x < s) lds[threadIdx.x] += lds[threadIdx.x + s];
    __syncthreads();
  }
  if (threadIdx.x == 0) partial[blockIdx.x] = lds[0];
}

__global__ void k_scan2(int* __restrict__ partial, int nb, int* __restrict__ off, int N){
  __shared__ int lds[1024];
  int t = threadIdx.x;
  int v = (t < nb) ? partial[t] : 0;
  lds[t] = v;
  __syncthreads();
  for (int s = 1; s < 1024; s <<= 1){
    int tv = (t >= s) ? lds[t - s] : 0;
    __syncthreads();
    lds[t] += tv;
    __syncthreads();
  }
  if (t < nb) partial[t] = lds[t] - v;    // exclusive prefix
  if (t == 1023) off[N] = lds[1023];      // total = E
}

__global__ void k_scan3(const int* __restrict__ deg, const int* __restrict__ partial,
                        int* __restrict__ off, int N){
  __shared__ int lds[1024];
  int gid = blockIdx.x * 1024 + threadIdx.x;
  int v = (gid < N) ? deg[gid] : 0;
  lds[threadIdx.x] = v;
  __syncthreads();
  for (int s = 1; s < 1024; s <<= 1){
    int t = (threadIdx.x >= s) ? lds[threadIdx.x - s] : 0;
    __syncthreads();
    lds[threadIdx.x] += t;
    __syncthreads();
  }
  if (gid < N) off[gid] = partial[blockIdx.x] + lds[threadIdx.x] - v;
}

// gtail[b] = CSR offset of bucket b's first node
__global__ void k_gtail(const int* __restrict__ off, int* __restrict__ gtail,
                        int N, int nbuck){
  int b = threadIdx.x;
  if (b <= nbuck) gtail[b] = off[min(b << BSHIFT, N)];
}

// ---------------- binned scatter phase A: group edges by dst-bucket (tail-append)
// packed 8B record: {src | drel<<17, ea-bits}
__global__ __launch_bounds__(256) void k_binA(
    const int* __restrict__ dst, const int* __restrict__ src,
    const float* __restrict__ ea, int* __restrict__ gtail,
    int2* __restrict__ tse, int E){
  __shared__ int hist[256], base[256], run[256];
  int e0 = blockIdx.x * 4096;
  int e1 = min(e0 + 4096, E);
  hist[threadIdx.x] = 0; run[threadIdx.x] = 0;
  __syncthreads();
  for (int i = e0 + threadIdx.x; i < e1; i += 256)
    atomicAdd(&hist[dst[i] >> BSHIFT], 1);
  __syncthreads();
  if (hist[threadIdx.x] > 0)
    base[threadIdx.x] = atomicAdd(&gtail[threadIdx.x], hist[threadIdx.x]);
  __syncthreads();
  for (int i = e0 + threadIdx.x; i < e1; i += 256){
    int d = dst[i];
    int b = d >> BSHIFT;
    int pos = base[b] + atomicAdd(&run[b], 1);
    tse[pos] = make_int2(src[i] | ((d & 511) << 17), __float_as_int(ea[i]));
  }
}

// ---------------- binned scatter phase B: place within bucket (LDS fill counters) ----------------
__global__ __launch_bounds__(256) void k_binB(
    const int* __restrict__ off, const int2* __restrict__ tse,
    int2* __restrict__ csr, int N){
  __shared__ int fillL[512];
  int node0 = blockIdx.x << BSHIFT;
  int node1 = min(node0 + 512, N);
  int nn = node1 - node0;
  for (int j = threadIdx.x; j < nn; j += 256) fillL[j] = off[node0 + j];
  __syncthreads();
  int i0 = off[node0], i1 = off[node1];
  for (int i = i0 + threadIdx.x; i < i1; i += 256){
    int2 t = tse[i];
    int drel = (t.x >> 17) & 511;
    int pos = atomicAdd(&fillL[drel], 1);
    csr[pos] = make_int2(t.x & 0x1FFFF, t.y);
  }
}

// ---------------- fused edge kernel: 4 nodes/wave, 16 lanes/node, no-max softmax,
// depth-2 software pipeline on the csr->y gather chain
__global__ void k_edge_f(const int* __restrict__ off, const int2* __restrict__ csr,
                         const ushort* __restrict__ yb, const float* __restrict__ xr,
                         const float* __restrict__ wgc, const float* __restrict__ att_l,
                         float* __restrict__ sout, int N){
  int lane = threadIdx.x & 63;
  int wwid = (blockIdx.x * blockDim.x + threadIdx.x) >> 6;
  int g = lane >> 4, sl = lane & 15;
  int node = wwid * 4 + g;
  if (node >= N) return;
  int i0 = off[node], i1 = off[node + 1];
  float4 wc4 = ((const float4*)wgc)[sl];
  float4 al4 = ((const float4*)att_l)[sl];
  float xrn = xr[node];
  float sg = 0.f;
  float4 acc = make_float4(0.f, 0.f, 0.f, 0.f);
  int2 recA = make_int2(0, 0), recB = make_int2(0, 0);
  ushort4 yvA = make_ushort4(0,0,0,0), yvB = make_ushort4(0,0,0,0);
  if (i0 < i1){
    recA = csr[i0];
    yvA  = ((const ushort4*)(yb + (size_t)recA.x * 64))[sl];
  }
  if (i0 + 1 < i1){
    recB = csr[i0 + 1];
    yvB  = ((const ushort4*)(yb + (size_t)recB.x * 64))[sl];
  }
  for (int i = i0; i < i1; i++){
    float ea = __int_as_float(recA.y);
    float4 he;
    he.x = lrelu(bf2f(yvA.x) + ea * wc4.x);
    he.y = lrelu(bf2f(yvA.y) + ea * wc4.y);
    he.z = lrelu(bf2f(yvA.z) + ea * wc4.z);
    he.w = lrelu(bf2f(yvA.w) + ea * wc4.w);
    // shift pipeline and issue prefetch for i+2 (overlaps with reduction below)
    recA = recB; yvA = yvB;
    int inext = i + 2;
    if (inext < i1){
      recB = csr[inext];
      yvB  = ((const ushort4*)(yb + (size_t)recB.x * 64))[sl];
    }
    float p = dot4(he, al4);
    p += __shfl_xor(p, 1); p += __shfl_xor(p, 2);
    p += __shfl_xor(p, 4); p += __shfl_xor(p, 8);
    float a = lrelu(p + xrn);
    float w = __expf(a);
    sg += w;
    acc.x += w * he.x; acc.y += w * he.y;
    acc.z += w * he.z; acc.w += w * he.w;
  }
  float inv = (i1 > i0 && sg > 0.f) ? 1.f / sg : 0.f;
  float4 o = make_float4(acc.x * inv, acc.y * inv, acc.z * inv, acc.w * inv);
  ((float4*)(sout + (size_t)node * 64))[sl] = o;
}

// ---------------- GRU1 via MFMA: block = 64 nodes, wave = 16-node M-tile ----------------
__global__ __launch_bounds__(256) void k_gru1m(
    const float* __restrict__ sout, const float* __restrict__ na,
    const float* __restrict__ w1, const float* __restrict__ b1,
    const ushort* __restrict__ wg2f, const float* __restrict__ bg,
    const ushort* __restrict__ wihf, const ushort* __restrict__ whhf,
    const float* __restrict__ bih, const float* __restrict__ bhh,
    float* __restrict__ x2, int N){
  __shared__ ushort xgl[4][16][72];   // per-wave elu(h) tile, bf16, padded rows
  int lane = threadIdx.x & 63;
  int wid  = threadIdx.x >> 6;
  int m = lane & 15, g = lane >> 4;
  int n0 = blockIdx.x * 64 + wid * 16;
  if (n0 >= N) return;                 // no barriers used -> safe early exit
  int rowc = min(n0 + m, N - 1);
  const float* srow = sout + (size_t)rowc * 64;
  bf8 sa0 = pack8(*(const float4*)(srow + g * 8),      *(const float4*)(srow + g * 8 + 4));
  bf8 sa1 = pack8(*(const float4*)(srow + 32 + g * 8), *(const float4*)(srow + 32 + g * 8 + 4));
  const bf8* WG = (const bf8*)wg2f;
  f32x4 h[4];
#pragma unroll
  for (int t = 0; t < 4; t++){
    f32x4 acc = {0.f, 0.f, 0.f, 0.f};
    acc = __builtin_amdgcn_mfma_f32_16x16x32_bf16(sa0, WG[t * 64 + lane], acc, 0, 0, 0);
    acc = __builtin_amdgcn_mfma_f32_16x16x32_bf16(sa1, WG[(4 + t) * 64 + lane], acc, 0, 0, 0);
    h[t] = acc;
  }
#pragma unroll
  for (int t = 0; t < 4; t++){
    float bgc = bg[m + 16 * t];
#pragma unroll
    for (int r = 0; r < 4; r++){
      float hv = h[t][r] + bgc;
      float xg = hv > 0.f ? hv : __expf(hv) - 1.f;
      xgl[wid][g * 4 + r][m + 16 * t] = (ushort)f2bfs(xg);
    }
  }
  float nav = na[rowc];
  bf8 xoa0 = pack8(xo4(nav, *(const float4*)(w1 + g * 8),      *(const float4*)(b1 + g * 8)),
                   xo4(nav, *(const float4*)(w1 + g * 8 + 4),  *(const float4*)(b1 + g * 8 + 4)));
  bf8 xoa1 = pack8(xo4(nav, *(const float4*)(w1 + 32 + g * 8),     *(const float4*)(b1 + 32 + g * 8)),
                   xo4(nav, *(const float4*)(w1 + 32 + g * 8 + 4), *(const float4*)(b1 + 32 + g * 8 + 4)));
  bf8 xga0 = *(const bf8*)&xgl[wid][m][g * 8];
  bf8 xga1 = *(const bf8*)&xgl[wid][m][32 + g * 8];
  const bf8* WI = (const bf8*)wihf;
  const bf8* WH = (const bf8*)whhf;
#pragma unroll
  for (int t = 0; t < 4; t++){
    f32x4 iR = {0.f,0.f,0.f,0.f}, iZ = iR, iN = iR, hR = iR, hZ = iR, hN = iR;
    iR = __builtin_amdgcn_mfma_f32_16x16x32_bf16(xga0, WI[(t     ) * 64 + lane], iR, 0,0,0);
    iR = __builtin_amdgcn_mfma_f32_16x16x32_bf16(xga1, WI[(12 + t) * 64 + lane], iR, 0,0,0);
    iZ = __builtin_amdgcn_mfma_f32_16x16x32_bf16(xga0, WI[(t +  4) * 64 + lane], iZ, 0,0,0);
    iZ = __builtin_amdgcn_mfma_f32_16x16x32_bf16(xga1, WI[(16 + t) * 64 + lane], iZ, 0,0,0);
    iN = __builtin_amdgcn_mfma_f32_16x16x32_bf16(xga0, WI[(t +  8) * 64 + lane], iN, 0,0,0);
    iN = __builtin_amdgcn_mfma_f32_16x16x32_bf16(xga1, WI[(20 + t) * 64 + lane], iN, 0,0,0);
    hR = __builtin_amdgcn_mfma_f32_16x16x32_bf16(xoa0, WH[(t     ) * 64 + lane], hR, 0,0,0);
    hR = __builtin_amdgcn_mfma_f32_16x16x32_bf16(xoa1, WH[(12 + t) * 64 + lane], hR, 0,0,0);
    hZ = __builtin_amdgcn_mfma_f32_16x16x32_bf16(xoa0, WH[(t +  4) * 64 + lane], hZ, 0,0,0);
    hZ = __builtin_amdgcn_mfma_f32_16x16x32_bf16(xoa1, WH[(16 + t) * 64 + lane], hZ, 0,0,0);
    hN = __builtin_amdgcn_mfma_f32_16x16x32_bf16(xoa0, WH[(t +  8) * 64 + lane], hN, 0,0,0);
    hN = __builtin_amdgcn_mfma_f32_16x16x32_bf16(xoa1, WH[(20 + t) * 64 + lane], hN, 0,0,0);
    int col = m + 16 * t;
    float biR = bih[col], biZ = bih[64 + col], biN = bih[128 + col];
    float bhR = bhh[col], bhZ = bhh[64 + col], bhN = bhh[128 + col];
    float w1c = w1[col], b1c = b1[col];
#pragma unroll
    for (int r = 0; r < 4; r++){
      int node = n0 + g * 4 + r;
      if (node < N){
        float xon = lrelu(na[node] * w1c + b1c);
        float rg = 1.f / (1.f + __expf(-(iR[r] + biR + hR[r] + bhR)));
        float zg = 1.f / (1.f + __expf(-(iZ[r] + biZ + hZ[r] + bhZ)));
        float nn = tanhf(iN[r] + biN + rg * (hN[r] + bhN));
        float xn = (1.f - zg) * nn + zg * xon;
        x2[(size_t)node * 64 + col] = fmaxf(xn, 0.f);
      }
    }
  }
}

// ---------------- part2 via MFMA: xs = x2@wm.T (in-place), tb, osum, max(tb) ----------------
__global__ __launch_bounds__(256) void k_part2m(
    float* __restrict__ xb,            // in: x2 rows; out: xs rows (in-place per tile)
    const ushort* __restrict__ wmf, const float* __restrict__ att_src,
    float* __restrict__ tb, float* __restrict__ scal, int N){
  int lane = threadIdx.x & 63;
  int wid  = threadIdx.x >> 6;
  int m = lane & 15, g = lane >> 4;
  const bf8* WM = (const bf8*)wmf;
  float as_t[4];
#pragma unroll
  for (int t = 0; t < 4; t++) as_t[t] = att_src[m + 16 * t];
  float os[16];
#pragma unroll
  for (int j = 0; j < 16; j++) os[j] = 0.f;
  float tmax = -1e30f;
  int ntiles = (N + 15) >> 4;
  for (int tile = blockIdx.x * 4 + wid; tile < ntiles; tile += gridDim.x * 4){
    int n0 = tile * 16;
    int row = n0 + m;
    bool valid = row < N;
    int rowc = valid ? row : (N - 1);
    const float* xrow = xb + (size_t)rowc * 64;
    float4 a0 = *(const float4*)(xrow + g * 8);
    float4 a1 = *(const float4*)(xrow + g * 8 + 4);
    float4 a2 = *(const float4*)(xrow + 32 + g * 8);
    float4 a3 = *(const float4*)(xrow + 32 + g * 8 + 4);
    if (!valid){ a0 = make_float4(0,0,0,0); a1 = a0; a2 = a0; a3 = a0; }
    os[0]+=a0.x; os[1]+=a0.y; os[2]+=a0.z; os[3]+=a0.w;
    os[4]+=a1.x; os[5]+=a1.y; os[6]+=a1.z; os[7]+=a1.w;
    os[8]+=a2.x; os[9]+=a2.y; os[10]+=a2.z; os[11]+=a2.w;
    os[12]+=a3.x; os[13]+=a3.y; os[14]+=a3.z; os[15]+=a3.w;
    bf8 fa0 = pack8(a0, a1), fa1 = pack8(a2, a3);
    f32x4 xs_t[4];
#pragma unroll
    for (int t = 0; t < 4; t++){
      f32x4 acc = {0.f, 0.f, 0.f, 0.f};
      acc = __builtin_amdgcn_mfma_f32_16x16x32_bf16(fa0, WM[t * 64 + lane], acc, 0, 0, 0);
      acc = __builtin_amdgcn_mfma_f32_16x16x32_bf16(fa1, WM[(4 + t) * 64 + lane], acc, 0, 0, 0);
      xs_t[t] = acc;
    }
    float tpart[4] = {0.f, 0.f, 0.f, 0.f};
#pragma unroll
    for (int t = 0; t < 4; t++){
#pragma unroll
      for (int r = 0; r < 4; r++){
        int rw = n0 + g * 4 + r;
        if (rw < N) xb[(size_t)rw * 64 + m + 16 * t] = xs_t[t][r];
        tpart[r] += xs_t[t][r] * as_t[t];
      }
    }
#pragma unroll
    for (int r = 0; r < 4; r++){
      float v = tpart[r];
      v += __shfl_xor(v, 1); v += __shfl_xor(v, 2);
      v += __shfl_xor(v, 4); v += __shfl_xor(v, 8);
      if (m == 0){
        int rw = n0 + g * 4 + r;
        if (rw < N){ tb[rw] = v; tmax = fmaxf(tmax, v); }
      }
    }
  }
  tmax = wave_max(tmax);
  if (lane == 0) atomicMax((unsigned*)(scal + 131), fkey(tmax));
#pragma unroll
  for (int j = 0; j < 16; j++){
    float v = os[j];
    v += __shfl_xor(v, 1); v += __shfl_xor(v, 2);
    v += __shfl_xor(v, 4); v += __shfl_xor(v, 8);
    os[j] = v;
  }
  __shared__ float osm[4][64];
  if (m == 0){
#pragma unroll
    for (int j = 0; j < 8; j++){
      osm[wid][g * 8 + j]      = os[j];
      osm[wid][32 + g * 8 + j] = os[8 + j];
    }
  }
  __syncthreads();
  if (threadIdx.x < 64)
    atomicAdd(&scal[threadIdx.x],
              osm[0][threadIdx.x] + osm[1][threadIdx.x] + osm[2][threadIdx.x] + osm[3][threadIdx.x]);
}

// ---------------- part2b (1 wave) ----------------
__global__ void k_part2b(float* __restrict__ scal, const float* __restrict__ wm_t,
                         const float* __restrict__ att_dst){
  int lane = threadIdx.x;
  float o = fmaxf(scal[lane], 0.f);
  float acc = 0.f;
  for (int k = 0; k < 64; k++) acc += bcast(o, k) * wm_t[k * 64 + lane];
  float c = wave_sum(acc * att_dst[lane]);
  scal[64 + lane] = o;
  if (lane == 0){
    scal[128] = c;
    float maxtb = funkey(*(unsigned*)(scal + 131));
    scal[130] = lrelu(maxtb + c);   // M = max_n lrelu(tb[n]+c)  (lrelu monotone)
  }
}

// ---------------- a2 weighted sums ----------------
__global__ void k_a2sum(const float* __restrict__ tb, const float* __restrict__ xs,
                        float* __restrict__ scal, int N){
  int lane = threadIdx.x & 63, w = threadIdx.x >> 6;
  int gw = blockIdx.x * 4 + w, nw = gridDim.x * 4;
  float c = scal[128];
  float M = scal[130];
  float hloc = 0.f, sloc = 0.f;
  for (int n = gw; n < N; n += nw){
    float a2 = lrelu(tb[n] + c);
    float wt = __expf(a2 - M);
    sloc += wt;
    hloc += wt * xs[(size_t)n * 64 + lane];
  }
  __shared__ float lds[256];
  __shared__ float sred[4];
  lds[threadIdx.x] = hloc;
  if (lane == 0) sred[w] = sloc;
  __syncthreads();
  if (threadIdx.x < 64)
    atomicAdd(&scal[192 + threadIdx.x],
              lds[threadIdx.x] + lds[64 + threadIdx.x] + lds[128 + threadIdx.x] + lds[192 + threadIdx.x]);
  if (threadIdx.x == 0) atomicAdd(&scal[129], sred[0] + sred[1] + sred[2] + sred[3]);
}

// ---------------- final (1 wave, coalesced transposed weights) ----------------
__global__ void k_final(const float* __restrict__ scal, const float* __restrict__ bm,
                        const float* __restrict__ g2ih_t, const float* __restrict__ g2hh_t,
                        const float* __restrict__ bih, const float* __restrict__ bhh,
                        const float* __restrict__ w2_t, const float* __restrict__ b2,
                        float* __restrict__ dout){
  int lane = threadIdx.x;
  float S  = scal[129];
  float h2 = scal[192 + lane] / S + bm[lane];
  float xg = h2 > 0.f ? h2 : __expf(h2) - 1.f;
  float xo = scal[64 + lane];
  float gir = bih[lane], giz = bih[64 + lane], gin = bih[128 + lane];
  float ghr = bhh[lane], ghz = bhh[64 + lane], ghn = bhh[128 + lane];
  for (int k = 0; k < 64; k++){
    float a = bcast(xg, k), b = bcast(xo, k);
    const float* gi = g2ih_t + k * 192;
    const float* gh = g2hh_t + k * 192;
    gir += a * gi[lane]; giz += a * gi[64 + lane]; gin += a * gi[128 + lane];
    ghr += b * gh[lane]; ghz += b * gh[64 + lane]; ghn += b * gh[128 + lane];
  }
  float r  = 1.f / (1.f + __expf(-(gir + ghr)));
  float z  = 1.f / (1.f + __expf(-(giz + ghz)));
  float nn = tanhf(gin + r * ghn);
  float o2 = fmaxf((1.f - z) * nn + z * xo, 0.f);
  float res = 0.f;
  for (int k = 0; k < 64; k++) res += bcast(o2, k) * w2_t[k * 64 + lane];
  dout[lane] = res + b2[lane];
}

extern "C" void kernel_launch(void* const* d_in, const int* in_sizes, int n_in,
                              void* d_out, int out_size, void* d_ws, size_t ws_size,
                              hipStream_t stream){
  const float* na    = (const float*)d_in[0];
  const float* ea    = (const float*)d_in[1];
  const int*   ei    = (const int*)d_in[2];
  const float* w1    = (const float*)d_in[3];
  const float* b1    = (const float*)d_in[4];
  const float* wg1   = (const float*)d_in[5];
  const float* att_l = (const float*)d_in[6];
  const float* att_r = (const float*)d_in[7];
  const float* wg2   = (const float*)d_in[8];
  const float* bg    = (const float*)d_in[9];
  const float* g1wih = (const float*)d_in[10];
  const float* g1whh = (const float*)d_in[11];
  const float* g1bih = (const float*)d_in[12];
  const float* g1bhh = (const float*)d_in[13];
  const float* wm      = (const float*)d_in[14];
  const float* att_src = (const float*)d_in[15];
  const float* att_dst = (const float*)d_in[16];
  const float* bm      = (const float*)d_in[17];
  const float* g2wih = (const float*)d_in[18];
  const float* g2whh = (const float*)d_in[19];
  const float* g2bih = (const float*)d_in[20];
  const float* g2bhh = (const float*)d_in[21];
  const float* w2    = (const float*)d_in[22];
  const float* b2    = (const float*)d_in[23];

  int N = in_sizes[0];
  int E = in_sizes[1];
  const int* srcArr = ei;
  const int* dstArr = ei + E;

  char* ws = (char*)d_ws;
  size_t cur = 0;
  auto alloc = [&](size_t nbytes) -> char* {
    char* p = ws + cur;
    cur += (nbytes + 255) & ~(size_t)255;
    return p;
  };
  ushort* yb   = (ushort*)alloc((size_t)N * 64 * 2);   // bf16 y
  float* bufC  = (float*)alloc((size_t)N * 64 * 4);    // sout -> x2 -> xs
  float* xr    = (float*)alloc((size_t)N * 4);
  float* tb    = (float*)alloc((size_t)N * 4);
  int*   deg   = (int*)alloc((size_t)N * 4);
  int*   offA  = (int*)alloc((size_t)(N + 1) * 4);
  int*   part  = (int*)alloc(4096);
  int*   gtail = (int*)alloc(2048);
  int2*  csr   = (int2*)alloc((size_t)E * 8);
  int2*  tse   = (int2*)alloc((size_t)E * 8);
  float* scal  = (float*)alloc(4096);
  float* wm_t  = (float*)alloc(64 * 64 * 4);
  float* w2_t  = (float*)alloc(64 * 64 * 4);
  float* g2ih_t= (float*)alloc(64 * 192 * 4);
  float* g2hh_t= (float*)alloc(64 * 192 * 4);
  float* wgc   = (float*)alloc(64 * 4);
  ushort* wg2f = (ushort*)alloc(4096 * 2);
  ushort* wmf  = (ushort*)alloc(4096 * 2);
  ushort* wg1f = (ushort*)alloc(4096 * 2);
  ushort* wihf = (ushort*)alloc(12288 * 2);
  ushort* whhf = (ushort*)alloc(12288 * 2);
  if (cur > ws_size) return;

  hipMemsetAsync(deg,  0, (size_t)N * 4, stream);
  hipMemsetAsync(scal, 0, 4096, stream);

  k_wprep<<<64, 192, 0, stream>>>(wg1, wm, w2, g2wih, g2whh,
                                  wm_t, w2_t, g2ih_t, g2hh_t, wgc);
  k_wfrag<<<18, 256, 0, stream>>>(wg2, wm, wg1, g1wih, g1whh,
                                  wg2f, wmf, wg1f, wihf, whhf);

  k_node_m<<<512, 256, 0, stream>>>(na, w1, b1, wg1f, att_r, yb, xr, N);
  k_deg<<<(E + 255) / 256, 256, 0, stream>>>(dstArr, deg, E);
  int nb = (N + 1023) / 1024;
  k_scan1<<<nb, 1024, 0, stream>>>(deg, part, N);
  k_scan2<<<1, 1024, 0, stream>>>(part, nb, offA, N);
  k_scan3<<<nb, 1024, 0, stream>>>(deg, part, offA, N);
  int nbuck = (N + 511) >> BSHIFT;
  k_gtail<<<1, nbuck + 1, 0, stream>>>(offA, gtail, N, nbuck);
  k_binA<<<(E + 4095) / 4096, 256, 0, stream>>>(dstArr, srcArr, ea, gtail, tse, E);
  k_binB<<<nbuck, 256, 0, stream>>>(offA, tse, csr, N);
  int nwb2 = (N + 15) / 16;        // 4 waves/block, 4 nodes/wave
  k_edge_f<<<nwb2, 256, 0, stream>>>(offA, csr, yb, xr, wgc, att_l, bufC, N);
  int ngb = (N + 63) / 64;         // 4 waves/block, 16 nodes/wave (MFMA)
  k_gru1m<<<ngb, 256, 0, stream>>>(bufC, na, w1, b1, wg2f, bg, wihf, whhf,
                                   g1bih, g1bhh, bufC, N);
  k_part2m<<<512, 256, 0, stream>>>(bufC, wmf, att_src, tb, scal, N);
  k_part2b<<<1, 64, 0, stream>>>(scal, wm_t, att_dst);
  k_a2sum<<<512, 256, 0, stream>>>(tb, bufC, scal, N);
  k_final<<<1, 64, 0, stream>>>(scal, bm, g2ih_t, g2hh_t, g2bih, g2bhh, w2_t, b2, (float*)d_out);
  (void)n_in; (void)out_size;
}

// Round 14
// 243.929 us; speedup vs baseline: 8.0454x; 1.2202x over previous
//
#include <hip/hip_runtime.h>
#include <math.h>

typedef __attribute__((ext_vector_type(8))) short bf8;
typedef __attribute__((ext_vector_type(4))) float f32x4;

#define BSHIFT 9   // 512 nodes per bucket

__device__ __forceinline__ float lrelu(float v){ return fmaxf(v, 0.01f * v); }

__device__ __forceinline__ float wave_sum(float v){
#pragma unroll
  for (int s = 32; s > 0; s >>= 1) v += __shfl_xor(v, s);
  return v;
}
__device__ __forceinline__ float wave_max(float v){
#pragma unroll
  for (int s = 32; s > 0; s >>= 1) v = fmaxf(v, __shfl_xor(v, s));
  return v;
}

__device__ __forceinline__ float bcast(float v, int k){
  return __uint_as_float((unsigned)__builtin_amdgcn_readlane(__float_as_uint(v), k));
}

// float -> orderable unsigned key (monotone)
__device__ __forceinline__ unsigned fkey(float x){
  unsigned u = __float_as_uint(x);
  return (u & 0x80000000u) ? ~u : (u | 0x80000000u);
}
__device__ __forceinline__ float funkey(unsigned k){
  unsigned u = (k & 0x80000000u) ? (k & 0x7fffffffu) : ~k;
  return __uint_as_float(u);
}

// float -> bf16 (RNE)
__device__ __forceinline__ short f2bfs(float x){
  unsigned u = __float_as_uint(x);
  return (short)((u + 0x7fffu + ((u >> 16) & 1u)) >> 16);
}
__device__ __forceinline__ float bf2f(ushort v){
  return __uint_as_float((unsigned)v << 16);
}
__device__ __forceinline__ bf8 pack8(float4 a, float4 b){
  bf8 v;
  v[0]=f2bfs(a.x); v[1]=f2bfs(a.y); v[2]=f2bfs(a.z); v[3]=f2bfs(a.w);
  v[4]=f2bfs(b.x); v[5]=f2bfs(b.y); v[6]=f2bfs(b.z); v[7]=f2bfs(b.w);
  return v;
}
__device__ __forceinline__ float4 xo4(float nav, float4 w, float4 b){
  float4 r;
  r.x = lrelu(nav*w.x + b.x); r.y = lrelu(nav*w.y + b.y);
  r.z = lrelu(nav*w.z + b.z); r.w = lrelu(nav*w.w + b.w);
  return r;
}
__device__ __forceinline__ float dot4(float4 a, float4 b){
  return a.x*b.x + a.y*b.y + a.z*b.z + a.w*b.w;
}

// ---------------- weight transpose to k-major (small weights for 1-wave kernels) ----------------
__global__ void k_wprep(const float* __restrict__ wg1, const float* __restrict__ wm,
                        const float* __restrict__ w2,
                        const float* __restrict__ g2wih, const float* __restrict__ g2whh,
                        float* __restrict__ wm_t, float* __restrict__ w2_t,
                        float* __restrict__ g2ih_t, float* __restrict__ g2hh_t,
                        float* __restrict__ wgc){
  int k = blockIdx.x;      // 0..63
  int r = threadIdx.x;     // 0..191
  if (r < 64){
    wm_t [k * 64 + r] = wm [r * 64 + k];
    w2_t [k * 64 + r] = w2 [r * 64 + k];
    if (k == 0) wgc[r] = wg1[r * 65 + 64];
  }
  g2ih_t[k * 192 + r] = g2wih[r * 64 + k];
  g2hh_t[k * 192 + r] = g2whh[r * 64 + k];
}

// ---------------- pack weights into bf16 MFMA B-fragments ----------------
// B-frag slot (c, t, lane l, j) <- W[16t + (l&15)][32c + (l>>4)*8 + j], row stride S
__global__ void k_wfrag(const float* __restrict__ wg2, const float* __restrict__ wm,
                        const float* __restrict__ wg1,
                        const float* __restrict__ wih, const float* __restrict__ whh,
                        ushort* __restrict__ wg2f, ushort* __restrict__ wmf,
                        ushort* __restrict__ wg1f,
                        ushort* __restrict__ wihf, ushort* __restrict__ whhf){
  int tid = blockIdx.x * 256 + threadIdx.x;  // 0..4607
  if (tid >= 4608) return;
  const float* W; ushort* F; int T, S, base;
  if (tid < 512)      { W = wg2; F = wg2f; T = 4;  S = 64; base = tid; }
  else if (tid < 1024){ W = wm;  F = wmf;  T = 4;  S = 64; base = tid - 1024 + 512; }
  else if (tid < 1536){ W = wg1; F = wg1f; T = 4;  S = 65; base = tid - 1024; }
  else if (tid < 3072){ W = wih; F = wihf; T = 12; S = 64; base = tid - 1536; }
  else                { W = whh; F = whhf; T = 12; S = 64; base = tid - 3072; }
  int l  = base & 63;
  int ct = base >> 6;
  int c  = ct / T, t = ct - c * T;
  int row = 16 * t + (l & 15);
  int k0  = 32 * c + (l >> 4) * 8;
  const float* src = W + row * S + k0;
  unsigned o0 = (unsigned)(ushort)f2bfs(src[0]) | ((unsigned)(ushort)f2bfs(src[1]) << 16);
  unsigned o1 = (unsigned)(ushort)f2bfs(src[2]) | ((unsigned)(ushort)f2bfs(src[3]) << 16);
  unsigned o2 = (unsigned)(ushort)f2bfs(src[4]) | ((unsigned)(ushort)f2bfs(src[5]) << 16);
  unsigned o3 = (unsigned)(ushort)f2bfs(src[6]) | ((unsigned)(ushort)f2bfs(src[7]) << 16);
  ((uint4*)F)[base] = make_uint4(o0, o1, o2, o3);
}

// ---------------- node prep via MFMA: y(bf16) = x@wg1[:,:64].T, xr = dot(x, att_r) ----------------
__global__ __launch_bounds__(256) void k_node_m(
    const float* __restrict__ na, const float* __restrict__ w1,
    const float* __restrict__ b1, const ushort* __restrict__ wg1f,
    const float* __restrict__ att_r,
    ushort* __restrict__ yb, float* __restrict__ xr, int N){
  int lane = threadIdx.x & 63;
  int wid  = threadIdx.x >> 6;
  int m = lane & 15, g = lane >> 4;
  const bf8* WG = (const bf8*)wg1f;
  float4 w1a = *(const float4*)(w1 + g*8),      w1b = *(const float4*)(w1 + g*8 + 4);
  float4 w1c = *(const float4*)(w1 + 32 + g*8), w1d = *(const float4*)(w1 + 32 + g*8 + 4);
  float4 b1a = *(const float4*)(b1 + g*8),      b1b = *(const float4*)(b1 + g*8 + 4);
  float4 b1c = *(const float4*)(b1 + 32 + g*8), b1d = *(const float4*)(b1 + 32 + g*8 + 4);
  float4 ara = *(const float4*)(att_r + g*8),      arb = *(const float4*)(att_r + g*8 + 4);
  float4 arc = *(const float4*)(att_r + 32 + g*8), ard = *(const float4*)(att_r + 32 + g*8 + 4);
  int ntiles = (N + 15) >> 4;
  for (int tile = blockIdx.x * 4 + wid; tile < ntiles; tile += gridDim.x * 4){
    int n0 = tile * 16;
    int row = n0 + m;
    bool valid = row < N;
    float nav = valid ? na[row] : 0.f;
    float4 x0 = xo4(nav, w1a, b1a), x1 = xo4(nav, w1b, b1b);
    float4 x2 = xo4(nav, w1c, b1c), x3 = xo4(nav, w1d, b1d);
    float xa = dot4(x0, ara) + dot4(x1, arb) + dot4(x2, arc) + dot4(x3, ard);
    xa += __shfl_xor(xa, 16); xa += __shfl_xor(xa, 32);
    if (g == 0 && valid) xr[row] = xa;
    bf8 fa0 = pack8(x0, x1), fa1 = pack8(x2, x3);
    f32x4 yt[4];
#pragma unroll
    for (int t = 0; t < 4; t++){
      f32x4 acc = {0.f, 0.f, 0.f, 0.f};
      acc = __builtin_amdgcn_mfma_f32_16x16x32_bf16(fa0, WG[t * 64 + lane], acc, 0, 0, 0);
      acc = __builtin_amdgcn_mfma_f32_16x16x32_bf16(fa1, WG[(4 + t) * 64 + lane], acc, 0, 0, 0);
      yt[t] = acc;
    }
#pragma unroll
    for (int t = 0; t < 4; t++){
#pragma unroll
      for (int r = 0; r < 4; r++){
        int rw = n0 + g * 4 + r;
        if (rw < N) yb[(size_t)rw * 64 + m + 16 * t] = (ushort)f2bfs(yt[t][r]);
      }
    }
  }
}

// ---------------- bucket histogram (LDS-aggregated; 77K global atomics, not 1.6M) ----------------
__global__ __launch_bounds__(256) void k_bhist(const int* __restrict__ dst,
                                               int* __restrict__ bcnt, int E, int nbuck){
  __shared__ int hist[256];
  hist[threadIdx.x] = 0;
  __syncthreads();
  int e0 = blockIdx.x * 4096;
  int e1 = min(e0 + 4096, E);
  for (int i = e0 + threadIdx.x; i < e1; i += 256)
    atomicAdd(&hist[dst[i] >> BSHIFT], 1);
  __syncthreads();
  if (threadIdx.x < nbuck && hist[threadIdx.x] > 0)
    atomicAdd(&bcnt[threadIdx.x], hist[threadIdx.x]);
}

// ---------------- bucket prefix scan (1 block): bbase[0..nbuck], gtail seed ----------------
__global__ void k_bscan(const int* __restrict__ bcnt, int* __restrict__ bbase,
                        int* __restrict__ gtail, int nbuck){
  __shared__ int lds[256];
  int t = threadIdx.x;
  int v = (t < nbuck) ? bcnt[t] : 0;
  lds[t] = v;
  __syncthreads();
  for (int s = 1; s < 256; s <<= 1){
    int tv = (t >= s) ? lds[t - s] : 0;
    __syncthreads();
    lds[t] += tv;
    __syncthreads();
  }
  if (t <= nbuck){
    int excl = (t == 0) ? 0 : lds[t - 1];
    bbase[t] = excl;
    if (t < nbuck) gtail[t] = excl;
  }
}

// ---------------- binned scatter phase A: group edges by dst-bucket (tail-append)
// packed 8B record: {src | drel<<17, ea-bits}
__global__ __launch_bounds__(256) void k_binA(
    const int* __restrict__ dst, const int* __restrict__ src,
    const float* __restrict__ ea, int* __restrict__ gtail,
    int2* __restrict__ tse, int E){
  __shared__ int hist[256], base[256], run[256];
  int e0 = blockIdx.x * 4096;
  int e1 = min(e0 + 4096, E);
  hist[threadIdx.x] = 0; run[threadIdx.x] = 0;
  __syncthreads();
  for (int i = e0 + threadIdx.x; i < e1; i += 256)
    atomicAdd(&hist[dst[i] >> BSHIFT], 1);
  __syncthreads();
  if (hist[threadIdx.x] > 0)
    base[threadIdx.x] = atomicAdd(&gtail[threadIdx.x], hist[threadIdx.x]);
  __syncthreads();
  for (int i = e0 + threadIdx.x; i < e1; i += 256){
    int d = dst[i];
    int b = d >> BSHIFT;
    int pos = base[b] + atomicAdd(&run[b], 1);
    tse[pos] = make_int2(src[i] | ((d & 511) << 17), __float_as_int(ea[i]));
  }
}

// ---------------- binned scatter phase B: derive per-node offsets locally + place ----------------
__global__ __launch_bounds__(256) void k_binB(
    const int* __restrict__ bbase, const int2* __restrict__ tse,
    int2* __restrict__ csr, int* __restrict__ off, int N){
  __shared__ int degL[512];
  __shared__ int fillL[512];
  int node0 = blockIdx.x << BSHIFT;
  int node1 = min(node0 + 512, N);
  int nn = node1 - node0;
  int i0 = bbase[blockIdx.x], i1 = bbase[blockIdx.x + 1];
  degL[threadIdx.x] = 0; degL[256 + threadIdx.x] = 0;
  __syncthreads();
  for (int i = i0 + threadIdx.x; i < i1; i += 256)
    atomicAdd(&degL[(tse[i].x >> 17) & 511], 1);
  __syncthreads();
  // inclusive Hillis-Steele scan over 512 entries (2 per thread)
  int j0 = threadIdx.x, j1 = threadIdx.x + 256;
  for (int s = 1; s < 512; s <<= 1){
    int v0 = (j0 >= s) ? degL[j0 - s] : 0;
    int v1 = (j1 >= s) ? degL[j1 - s] : 0;
    __syncthreads();
    degL[j0] += v0; degL[j1] += v1;
    __syncthreads();
  }
  // off[node] = i0 + exclusive; fill counters likewise
#pragma unroll
  for (int q = 0; q < 2; q++){
    int j = threadIdx.x + q * 256;
    int incl = degL[j];
    int prev = (j == 0) ? 0 : degL[j - 1];
    // careful: degL[j-1] read AFTER scan complete (synced above)
    fillL[j] = i0 + prev;
    if (j < nn) off[node0 + j] = i0 + prev;
    (void)incl;
  }
  if (threadIdx.x == 0 && node1 == N) off[N] = i1;
  __syncthreads();
  for (int i = i0 + threadIdx.x; i < i1; i += 256){
    int2 t = tse[i];
    int drel = (t.x >> 17) & 511;
    int pos = atomicAdd(&fillL[drel], 1);
    csr[pos] = make_int2(t.x & 0x1FFFF, t.y);
  }
}

// ---------------- fused edge kernel: 4 nodes/wave, 16 lanes/node, no-max softmax,
// depth-2 software pipeline on the csr->y gather chain
__global__ void k_edge_f(const int* __restrict__ off, const int2* __restrict__ csr,
                         const ushort* __restrict__ yb, const float* __restrict__ xr,
                         const float* __restrict__ wgc, const float* __restrict__ att_l,
                         float* __restrict__ sout, int N){
  int lane = threadIdx.x & 63;
  int wwid = (blockIdx.x * blockDim.x + threadIdx.x) >> 6;
  int g = lane >> 4, sl = lane & 15;
  int node = wwid * 4 + g;
  if (node >= N) return;
  int i0 = off[node], i1 = off[node + 1];
  float4 wc4 = ((const float4*)wgc)[sl];
  float4 al4 = ((const float4*)att_l)[sl];
  float xrn = xr[node];
  float sg = 0.f;
  float4 acc = make_float4(0.f, 0.f, 0.f, 0.f);
  int2 recA = make_int2(0, 0), recB = make_int2(0, 0);
  ushort4 yvA = make_ushort4(0,0,0,0), yvB = make_ushort4(0,0,0,0);
  if (i0 < i1){
    recA = csr[i0];
    yvA  = ((const ushort4*)(yb + (size_t)recA.x * 64))[sl];
  }
  if (i0 + 1 < i1){
    recB = csr[i0 + 1];
    yvB  = ((const ushort4*)(yb + (size_t)recB.x * 64))[sl];
  }
  for (int i = i0; i < i1; i++){
    float ea = __int_as_float(recA.y);
    float4 he;
    he.x = lrelu(bf2f(yvA.x) + ea * wc4.x);
    he.y = lrelu(bf2f(yvA.y) + ea * wc4.y);
    he.z = lrelu(bf2f(yvA.z) + ea * wc4.z);
    he.w = lrelu(bf2f(yvA.w) + ea * wc4.w);
    recA = recB; yvA = yvB;
    int inext = i + 2;
    if (inext < i1){
      recB = csr[inext];
      yvB  = ((const ushort4*)(yb + (size_t)recB.x * 64))[sl];
    }
    float p = dot4(he, al4);
    p += __shfl_xor(p, 1); p += __shfl_xor(p, 2);
    p += __shfl_xor(p, 4); p += __shfl_xor(p, 8);
    float a = lrelu(p + xrn);
    float w = __expf(a);
    sg += w;
    acc.x += w * he.x; acc.y += w * he.y;
    acc.z += w * he.z; acc.w += w * he.w;
  }
  float inv = (i1 > i0 && sg > 0.f) ? 1.f / sg : 0.f;
  float4 o = make_float4(acc.x * inv, acc.y * inv, acc.z * inv, acc.w * inv);
  ((float4*)(sout + (size_t)node * 64))[sl] = o;
}

// ---------------- GRU1 via MFMA: block = 64 nodes, wave = 16-node M-tile ----------------
__global__ __launch_bounds__(256) void k_gru1m(
    const float* __restrict__ sout, const float* __restrict__ na,
    const float* __restrict__ w1, const float* __restrict__ b1,
    const ushort* __restrict__ wg2f, const float* __restrict__ bg,
    const ushort* __restrict__ wihf, const ushort* __restrict__ whhf,
    const float* __restrict__ bih, const float* __restrict__ bhh,
    float* __restrict__ x2, int N){
  __shared__ ushort xgl[4][16][72];   // per-wave elu(h) tile, bf16, padded rows
  int lane = threadIdx.x & 63;
  int wid  = threadIdx.x >> 6;
  int m = lane & 15, g = lane >> 4;
  int n0 = blockIdx.x * 64 + wid * 16;
  if (n0 >= N) return;                 // no barriers used -> safe early exit
  int rowc = min(n0 + m, N - 1);
  const float* srow = sout + (size_t)rowc * 64;
  bf8 sa0 = pack8(*(const float4*)(srow + g * 8),      *(const float4*)(srow + g * 8 + 4));
  bf8 sa1 = pack8(*(const float4*)(srow + 32 + g * 8), *(const float4*)(srow + 32 + g * 8 + 4));
  const bf8* WG = (const bf8*)wg2f;
  f32x4 h[4];
#pragma unroll
  for (int t = 0; t < 4; t++){
    f32x4 acc = {0.f, 0.f, 0.f, 0.f};
    acc = __builtin_amdgcn_mfma_f32_16x16x32_bf16(sa0, WG[t * 64 + lane], acc, 0, 0, 0);
    acc = __builtin_amdgcn_mfma_f32_16x16x32_bf16(sa1, WG[(4 + t) * 64 + lane], acc, 0, 0, 0);
    h[t] = acc;
  }
#pragma unroll
  for (int t = 0; t < 4; t++){
    float bgc = bg[m + 16 * t];
#pragma unroll
    for (int r = 0; r < 4; r++){
      float hv = h[t][r] + bgc;
      float xg = hv > 0.f ? hv : __expf(hv) - 1.f;
      xgl[wid][g * 4 + r][m + 16 * t] = (ushort)f2bfs(xg);
    }
  }
  float nav = na[rowc];
  bf8 xoa0 = pack8(xo4(nav, *(const float4*)(w1 + g * 8),      *(const float4*)(b1 + g * 8)),
                   xo4(nav, *(const float4*)(w1 + g * 8 + 4),  *(const float4*)(b1 + g * 8 + 4)));
  bf8 xoa1 = pack8(xo4(nav, *(const float4*)(w1 + 32 + g * 8),     *(const float4*)(b1 + 32 + g * 8)),
                   xo4(nav, *(const float4*)(w1 + 32 + g * 8 + 4), *(const float4*)(b1 + 32 + g * 8 + 4)));
  bf8 xga0 = *(const bf8*)&xgl[wid][m][g * 8];
  bf8 xga1 = *(const bf8*)&xgl[wid][m][32 + g * 8];
  const bf8* WI = (const bf8*)wihf;
  const bf8* WH = (const bf8*)whhf;
#pragma unroll
  for (int t = 0; t < 4; t++){
    f32x4 iR = {0.f,0.f,0.f,0.f}, iZ = iR, iN = iR, hR = iR, hZ = iR, hN = iR;
    iR = __builtin_amdgcn_mfma_f32_16x16x32_bf16(xga0, WI[(t     ) * 64 + lane], iR, 0,0,0);
    iR = __builtin_amdgcn_mfma_f32_16x16x32_bf16(xga1, WI[(12 + t) * 64 + lane], iR, 0,0,0);
    iZ = __builtin_amdgcn_mfma_f32_16x16x32_bf16(xga0, WI[(t +  4) * 64 + lane], iZ, 0,0,0);
    iZ = __builtin_amdgcn_mfma_f32_16x16x32_bf16(xga1, WI[(16 + t) * 64 + lane], iZ, 0,0,0);
    iN = __builtin_amdgcn_mfma_f32_16x16x32_bf16(xga0, WI[(t +  8) * 64 + lane], iN, 0,0,0);
    iN = __builtin_amdgcn_mfma_f32_16x16x32_bf16(xga1, WI[(20 + t) * 64 + lane], iN, 0,0,0);
    hR = __builtin_amdgcn_mfma_f32_16x16x32_bf16(xoa0, WH[(t     ) * 64 + lane], hR, 0,0,0);
    hR = __builtin_amdgcn_mfma_f32_16x16x32_bf16(xoa1, WH[(12 + t) * 64 + lane], hR, 0,0,0);
    hZ = __builtin_amdgcn_mfma_f32_16x16x32_bf16(xoa0, WH[(t +  4) * 64 + lane], hZ, 0,0,0);
    hZ = __builtin_amdgcn_mfma_f32_16x16x32_bf16(xoa1, WH[(16 + t) * 64 + lane], hZ, 0,0,0);
    hN = __builtin_amdgcn_mfma_f32_16x16x32_bf16(xoa0, WH[(t +  8) * 64 + lane], hN, 0,0,0);
    hN = __builtin_amdgcn_mfma_f32_16x16x32_bf16(xoa1, WH[(20 + t) * 64 + lane], hN, 0,0,0);
    int col = m + 16 * t;
    float biR = bih[col], biZ = bih[64 + col], biN = bih[128 + col];
    float bhR = bhh[col], bhZ = bhh[64 + col], bhN = bhh[128 + col];
    float w1c = w1[col], b1c = b1[col];
#pragma unroll
    for (int r = 0; r < 4; r++){
      int node = n0 + g * 4 + r;
      if (node < N){
        float xon = lrelu(na[node] * w1c + b1c);
        float rg = 1.f / (1.f + __expf(-(iR[r] + biR + hR[r] + bhR)));
        float zg = 1.f / (1.f + __expf(-(iZ[r] + biZ + hZ[r] + bhZ)));
        float nn = tanhf(iN[r] + biN + rg * (hN[r] + bhN));
        float xn = (1.f - zg) * nn + zg * xon;
        x2[(size_t)node * 64 + col] = fmaxf(xn, 0.f);
      }
    }
  }
}

// ---------------- part2 via MFMA: xs = x2@wm.T (in-place), tb, osum, max(tb) ----------------
__global__ __launch_bounds__(256) void k_part2m(
    float* __restrict__ xb,            // in: x2 rows; out: xs rows (in-place per tile)
    const ushort* __restrict__ wmf, const float* __restrict__ att_src,
    float* __restrict__ tb, float* __restrict__ scal, int N){
  int lane = threadIdx.x & 63;
  int wid  = threadIdx.x >> 6;
  int m = lane & 15, g = lane >> 4;
  const bf8* WM = (const bf8*)wmf;
  float as_t[4];
#pragma unroll
  for (int t = 0; t < 4; t++) as_t[t] = att_src[m + 16 * t];
  float os[16];
#pragma unroll
  for (int j = 0; j < 16; j++) os[j] = 0.f;
  float tmax = -1e30f;
  int ntiles = (N + 15) >> 4;
  for (int tile = blockIdx.x * 4 + wid; tile < ntiles; tile += gridDim.x * 4){
    int n0 = tile * 16;
    int row = n0 + m;
    bool valid = row < N;
    int rowc = valid ? row : (N - 1);
    const float* xrow = xb + (size_t)rowc * 64;
    float4 a0 = *(const float4*)(xrow + g * 8);
    float4 a1 = *(const float4*)(xrow + g * 8 + 4);
    float4 a2 = *(const float4*)(xrow + 32 + g * 8);
    float4 a3 = *(const float4*)(xrow + 32 + g * 8 + 4);
    if (!valid){ a0 = make_float4(0,0,0,0); a1 = a0; a2 = a0; a3 = a0; }
    os[0]+=a0.x; os[1]+=a0.y; os[2]+=a0.z; os[3]+=a0.w;
    os[4]+=a1.x; os[5]+=a1.y; os[6]+=a1.z; os[7]+=a1.w;
    os[8]+=a2.x; os[9]+=a2.y; os[10]+=a2.z; os[11]+=a2.w;
    os[12]+=a3.x; os[13]+=a3.y; os[14]+=a3.z; os[15]+=a3.w;
    bf8 fa0 = pack8(a0, a1), fa1 = pack8(a2, a3);
    f32x4 xs_t[4];
#pragma unroll
    for (int t = 0; t < 4; t++){
      f32x4 acc = {0.f, 0.f, 0.f, 0.f};
      acc = __builtin_amdgcn_mfma_f32_16x16x32_bf16(fa0, WM[t * 64 + lane], acc, 0, 0, 0);
      acc = __builtin_amdgcn_mfma_f32_16x16x32_bf16(fa1, WM[(4 + t) * 64 + lane], acc, 0, 0, 0);
      xs_t[t] = acc;
    }
    float tpart[4] = {0.f, 0.f, 0.f, 0.f};
#pragma unroll
    for (int t = 0; t < 4; t++){
#pragma unroll
      for (int r = 0; r < 4; r++){
        int rw = n0 + g * 4 + r;
        if (rw < N) xb[(size_t)rw * 64 + m + 16 * t] = xs_t[t][r];
        tpart[r] += xs_t[t][r] * as_t[t];
      }
    }
#pragma unroll
    for (int r = 0; r < 4; r++){
      float v = tpart[r];
      v += __shfl_xor(v, 1); v += __shfl_xor(v, 2);
      v += __shfl_xor(v, 4); v += __shfl_xor(v, 8);
      if (m == 0){
        int rw = n0 + g * 4 + r;
        if (rw < N){ tb[rw] = v; tmax = fmaxf(tmax, v); }
      }
    }
  }
  tmax = wave_max(tmax);
  if (lane == 0) atomicMax((unsigned*)(scal + 131), fkey(tmax));
#pragma unroll
  for (int j = 0; j < 16; j++){
    float v = os[j];
    v += __shfl_xor(v, 1); v += __shfl_xor(v, 2);
    v += __shfl_xor(v, 4); v += __shfl_xor(v, 8);
    os[j] = v;
  }
  __shared__ float osm[4][64];
  if (m == 0){
#pragma unroll
    for (int j = 0; j < 8; j++){
      osm[wid][g * 8 + j]      = os[j];
      osm[wid][32 + g * 8 + j] = os[8 + j];
    }
  }
  __syncthreads();
  if (threadIdx.x < 64)
    atomicAdd(&scal[threadIdx.x],
              osm[0][threadIdx.x] + osm[1][threadIdx.x] + osm[2][threadIdx.x] + osm[3][threadIdx.x]);
}

// ---------------- part2b (1 wave) ----------------
__global__ void k_part2b(float* __restrict__ scal, const float* __restrict__ wm_t,
                         const float* __restrict__ att_dst){
  int lane = threadIdx.x;
  float o = fmaxf(scal[lane], 0.f);
  float acc = 0.f;
  for (int k = 0; k < 64; k++) acc += bcast(o, k) * wm_t[k * 64 + lane];
  float c = wave_sum(acc * att_dst[lane]);
  scal[64 + lane] = o;
  if (lane == 0){
    scal[128] = c;
    float maxtb = funkey(*(unsigned*)(scal + 131));
    scal[130] = lrelu(maxtb + c);   // M = max_n lrelu(tb[n]+c)  (lrelu monotone)
  }
}

// ---------------- a2 weighted sums ----------------
__global__ void k_a2sum(const float* __restrict__ tb, const float* __restrict__ xs,
                        float* __restrict__ scal, int N){
  int lane = threadIdx.x & 63, w = threadIdx.x >> 6;
  int gw = blockIdx.x * 4 + w, nw = gridDim.x * 4;
  float c = scal[128];
  float M = scal[130];
  float hloc = 0.f, sloc = 0.f;
  for (int n = gw; n < N; n += nw){
    float a2 = lrelu(tb[n] + c);
    float wt = __expf(a2 - M);
    sloc += wt;
    hloc += wt * xs[(size_t)n * 64 + lane];
  }
  __shared__ float lds[256];
  __shared__ float sred[4];
  lds[threadIdx.x] = hloc;
  if (lane == 0) sred[w] = sloc;
  __syncthreads();
  if (threadIdx.x < 64)
    atomicAdd(&scal[192 + threadIdx.x],
              lds[threadIdx.x] + lds[64 + threadIdx.x] + lds[128 + threadIdx.x] + lds[192 + threadIdx.x]);
  if (threadIdx.x == 0) atomicAdd(&scal[129], sred[0] + sred[1] + sred[2] + sred[3]);
}

// ---------------- final (1 wave, coalesced transposed weights) ----------------
__global__ void k_final(const float* __restrict__ scal, const float* __restrict__ bm,
                        const float* __restrict__ g2ih_t, const float* __restrict__ g2hh_t,
                        const float* __restrict__ bih, const float* __restrict__ bhh,
                        const float* __restrict__ w2_t, const float* __restrict__ b2,
                        float* __restrict__ dout){
  int lane = threadIdx.x;
  float S  = scal[129];
  float h2 = scal[192 + lane] / S + bm[lane];
  float xg = h2 > 0.f ? h2 : __expf(h2) - 1.f;
  float xo = scal[64 + lane];
  float gir = bih[lane], giz = bih[64 + lane], gin = bih[128 + lane];
  float ghr = bhh[lane], ghz = bhh[64 + lane], ghn = bhh[128 + lane];
  for (int k = 0; k < 64; k++){
    float a = bcast(xg, k), b = bcast(xo, k);
    const float* gi = g2ih_t + k * 192;
    const float* gh = g2hh_t + k * 192;
    gir += a * gi[lane]; giz += a * gi[64 + lane]; gin += a * gi[128 + lane];
    ghr += b * gh[lane]; ghz += b * gh[64 + lane]; ghn += b * gh[128 + lane];
  }
  float r  = 1.f / (1.f + __expf(-(gir + ghr)));
  float z  = 1.f / (1.f + __expf(-(giz + ghz)));
  float nn = tanhf(gin + r * ghn);
  float o2 = fmaxf((1.f - z) * nn + z * xo, 0.f);
  float res = 0.f;
  for (int k = 0; k < 64; k++) res += bcast(o2, k) * w2_t[k * 64 + lane];
  dout[lane] = res + b2[lane];
}

extern "C" void kernel_launch(void* const* d_in, const int* in_sizes, int n_in,
                              void* d_out, int out_size, void* d_ws, size_t ws_size,
                              hipStream_t stream){
  const float* na    = (const float*)d_in[0];
  const float* ea    = (const float*)d_in[1];
  const int*   ei    = (const int*)d_in[2];
  const float* w1    = (const float*)d_in[3];
  const float* b1    = (const float*)d_in[4];
  const float* wg1   = (const float*)d_in[5];
  const float* att_l = (const float*)d_in[6];
  const float* att_r = (const float*)d_in[7];
  const float* wg2   = (const float*)d_in[8];
  const float* bg    = (const float*)d_in[9];
  const float* g1wih = (const float*)d_in[10];
  const float* g1whh = (const float*)d_in[11];
  const float* g1bih = (const float*)d_in[12];
  const float* g1bhh = (const float*)d_in[13];
  const float* wm      = (const float*)d_in[14];
  const float* att_src = (const float*)d_in[15];
  const float* att_dst = (const float*)d_in[16];
  const float* bm      = (const float*)d_in[17];
  const float* g2wih = (const float*)d_in[18];
  const float* g2whh = (const float*)d_in[19];
  const float* g2bih = (const float*)d_in[20];
  const float* g2bhh = (const float*)d_in[21];
  const float* w2    = (const float*)d_in[22];
  const float* b2    = (const float*)d_in[23];

  int N = in_sizes[0];
  int E = in_sizes[1];
  const int* srcArr = ei;
  const int* dstArr = ei + E;

  char* ws = (char*)d_ws;
  size_t cur = 0;
  auto alloc = [&](size_t nbytes) -> char* {
    char* p = ws + cur;
    cur += (nbytes + 255) & ~(size_t)255;
    return p;
  };
  ushort* yb   = (ushort*)alloc((size_t)N * 64 * 2);   // bf16 y
  float* bufC  = (float*)alloc((size_t)N * 64 * 4);    // sout -> x2 -> xs
  float* xr    = (float*)alloc((size_t)N * 4);
  float* tb    = (float*)alloc((size_t)N * 4);
  int*   offA  = (int*)alloc((size_t)(N + 1) * 4);
  int*   bcnt  = (int*)alloc(2048);
  int*   bbase = (int*)alloc(2048);
  int*   gtail = (int*)alloc(2048);
  int2*  csr   = (int2*)alloc((size_t)E * 8);
  int2*  tse   = (int2*)alloc((size_t)E * 8);
  float* scal  = (float*)alloc(4096);
  float* wm_t  = (float*)alloc(64 * 64 * 4);
  float* w2_t  = (float*)alloc(64 * 64 * 4);
  float* g2ih_t= (float*)alloc(64 * 192 * 4);
  float* g2hh_t= (float*)alloc(64 * 192 * 4);
  float* wgc   = (float*)alloc(64 * 4);
  ushort* wg2f = (ushort*)alloc(4096 * 2);
  ushort* wmf  = (ushort*)alloc(4096 * 2);
  ushort* wg1f = (ushort*)alloc(4096 * 2);
  ushort* wihf = (ushort*)alloc(12288 * 2);
  ushort* whhf = (ushort*)alloc(12288 * 2);
  if (cur > ws_size) return;

  hipMemsetAsync(bcnt, 0, 2048, stream);
  hipMemsetAsync(scal, 0, 4096, stream);

  k_wprep<<<64, 192, 0, stream>>>(wg1, wm, w2, g2wih, g2whh,
                                  wm_t, w2_t, g2ih_t, g2hh_t, wgc);
  k_wfrag<<<18, 256, 0, stream>>>(wg2, wm, wg1, g1wih, g1whh,
                                  wg2f, wmf, wg1f, wihf, whhf);

  int nbuck = (N + 511) >> BSHIFT;
  k_node_m<<<512, 256, 0, stream>>>(na, w1, b1, wg1f, att_r, yb, xr, N);
  k_bhist<<<(E + 4095) / 4096, 256, 0, stream>>>(dstArr, bcnt, E, nbuck);
  k_bscan<<<1, 256, 0, stream>>>(bcnt, bbase, gtail, nbuck);
  k_binA<<<(E + 4095) / 4096, 256, 0, stream>>>(dstArr, srcArr, ea, gtail, tse, E);
  k_binB<<<nbuck, 256, 0, stream>>>(bbase, tse, csr, offA, N);
  int nwb2 = (N + 15) / 16;        // 4 waves/block, 4 nodes/wave
  k_edge_f<<<nwb2, 256, 0, stream>>>(offA, csr, yb, xr, wgc, att_l, bufC, N);
  int ngb = (N + 63) / 64;         // 4 waves/block, 16 nodes/wave (MFMA)
  k_gru1m<<<ngb, 256, 0, stream>>>(bufC, na, w1, b1, wg2f, bg, wihf, whhf,
                                   g1bih, g1bhh, bufC, N);
  k_part2m<<<512, 256, 0, stream>>>(bufC, wmf, att_src, tb, scal, N);
  k_part2b<<<1, 64, 0, stream>>>(scal, wm_t, att_dst);
  k_a2sum<<<512, 256, 0, stream>>>(tb, bufC, scal, N);
  k_final<<<1, 64, 0, stream>>>(scal, bm, g2ih_t, g2hh_t, g2bih, g2bhh, w2_t, b2, (float*)d_out);
  (void)n_in; (void)out_size;
}

// Round 15
// 234.625 us; speedup vs baseline: 8.3644x; 1.0397x over previous
//
#include <hip/hip_runtime.h>
#include <math.h>

typedef __attribute__((ext_vector_type(8))) short bf8;
typedef __attribute__((ext_vector_type(4))) float f32x4;

#define BSHIFT 8   // 256 nodes per bucket (391 buckets at N=100K -> fills 256 CUs)

__device__ __forceinline__ float lrelu(float v){ return fmaxf(v, 0.01f * v); }

__device__ __forceinline__ float wave_sum(float v){
#pragma unroll
  for (int s = 32; s > 0; s >>= 1) v += __shfl_xor(v, s);
  return v;
}
__device__ __forceinline__ float wave_max(float v){
#pragma unroll
  for (int s = 32; s > 0; s >>= 1) v = fmaxf(v, __shfl_xor(v, s));
  return v;
}

__device__ __forceinline__ float bcast(float v, int k){
  return __uint_as_float((unsigned)__builtin_amdgcn_readlane(__float_as_uint(v), k));
}

// float -> orderable unsigned key (monotone)
__device__ __forceinline__ unsigned fkey(float x){
  unsigned u = __float_as_uint(x);
  return (u & 0x80000000u) ? ~u : (u | 0x80000000u);
}
__device__ __forceinline__ float funkey(unsigned k){
  unsigned u = (k & 0x80000000u) ? (k & 0x7fffffffu) : ~k;
  return __uint_as_float(u);
}

// float -> bf16 (RNE)
__device__ __forceinline__ short f2bfs(float x){
  unsigned u = __float_as_uint(x);
  return (short)((u + 0x7fffu + ((u >> 16) & 1u)) >> 16);
}
__device__ __forceinline__ float bf2f(ushort v){
  return __uint_as_float((unsigned)v << 16);
}
__device__ __forceinline__ bf8 pack8(float4 a, float4 b){
  bf8 v;
  v[0]=f2bfs(a.x); v[1]=f2bfs(a.y); v[2]=f2bfs(a.z); v[3]=f2bfs(a.w);
  v[4]=f2bfs(b.x); v[5]=f2bfs(b.y); v[6]=f2bfs(b.z); v[7]=f2bfs(b.w);
  return v;
}
__device__ __forceinline__ float4 xo4(float nav, float4 w, float4 b){
  float4 r;
  r.x = lrelu(nav*w.x + b.x); r.y = lrelu(nav*w.y + b.y);
  r.z = lrelu(nav*w.z + b.z); r.w = lrelu(nav*w.w + b.w);
  return r;
}
__device__ __forceinline__ float dot4(float4 a, float4 b){
  return a.x*b.x + a.y*b.y + a.z*b.z + a.w*b.w;
}

// ---------------- weight transpose to k-major (small weights for 1-wave kernels) ----------------
__global__ void k_wprep(const float* __restrict__ wg1, const float* __restrict__ wm,
                        const float* __restrict__ w2,
                        const float* __restrict__ g2wih, const float* __restrict__ g2whh,
                        float* __restrict__ wm_t, float* __restrict__ w2_t,
                        float* __restrict__ g2ih_t, float* __restrict__ g2hh_t,
                        float* __restrict__ wgc){
  int k = blockIdx.x;      // 0..63
  int r = threadIdx.x;     // 0..191
  if (r < 64){
    wm_t [k * 64 + r] = wm [r * 64 + k];
    w2_t [k * 64 + r] = w2 [r * 64 + k];
    if (k == 0) wgc[r] = wg1[r * 65 + 64];
  }
  g2ih_t[k * 192 + r] = g2wih[r * 64 + k];
  g2hh_t[k * 192 + r] = g2whh[r * 64 + k];
}

// ---------------- pack weights into bf16 MFMA B-fragments ----------------
// B-frag slot (c, t, lane l, j) <- W[16t + (l&15)][32c + (l>>4)*8 + j], row stride S
__global__ void k_wfrag(const float* __restrict__ wg2, const float* __restrict__ wm,
                        const float* __restrict__ wg1,
                        const float* __restrict__ wih, const float* __restrict__ whh,
                        ushort* __restrict__ wg2f, ushort* __restrict__ wmf,
                        ushort* __restrict__ wg1f,
                        ushort* __restrict__ wihf, ushort* __restrict__ whhf){
  int tid = blockIdx.x * 256 + threadIdx.x;  // 0..4607
  if (tid >= 4608) return;
  const float* W; ushort* F; int T, S, base;
  if (tid < 512)      { W = wg2; F = wg2f; T = 4;  S = 64; base = tid; }
  else if (tid < 1024){ W = wm;  F = wmf;  T = 4;  S = 64; base = tid - 1024 + 512; }
  else if (tid < 1536){ W = wg1; F = wg1f; T = 4;  S = 65; base = tid - 1024; }
  else if (tid < 3072){ W = wih; F = wihf; T = 12; S = 64; base = tid - 1536; }
  else                { W = whh; F = whhf; T = 12; S = 64; base = tid - 3072; }
  int l  = base & 63;
  int ct = base >> 6;
  int c  = ct / T, t = ct - c * T;
  int row = 16 * t + (l & 15);
  int k0  = 32 * c + (l >> 4) * 8;
  const float* src = W + row * S + k0;
  unsigned o0 = (unsigned)(ushort)f2bfs(src[0]) | ((unsigned)(ushort)f2bfs(src[1]) << 16);
  unsigned o1 = (unsigned)(ushort)f2bfs(src[2]) | ((unsigned)(ushort)f2bfs(src[3]) << 16);
  unsigned o2 = (unsigned)(ushort)f2bfs(src[4]) | ((unsigned)(ushort)f2bfs(src[5]) << 16);
  unsigned o3 = (unsigned)(ushort)f2bfs(src[6]) | ((unsigned)(ushort)f2bfs(src[7]) << 16);
  ((uint4*)F)[base] = make_uint4(o0, o1, o2, o3);
}

// ---------------- node prep via MFMA: y(bf16) = x@wg1[:,:64].T, xr = dot(x, att_r) ----------------
__global__ __launch_bounds__(256) void k_node_m(
    const float* __restrict__ na, const float* __restrict__ w1,
    const float* __restrict__ b1, const ushort* __restrict__ wg1f,
    const float* __restrict__ att_r,
    ushort* __restrict__ yb, float* __restrict__ xr, int N){
  int lane = threadIdx.x & 63;
  int wid  = threadIdx.x >> 6;
  int m = lane & 15, g = lane >> 4;
  const bf8* WG = (const bf8*)wg1f;
  float4 w1a = *(const float4*)(w1 + g*8),      w1b = *(const float4*)(w1 + g*8 + 4);
  float4 w1c = *(const float4*)(w1 + 32 + g*8), w1d = *(const float4*)(w1 + 32 + g*8 + 4);
  float4 b1a = *(const float4*)(b1 + g*8),      b1b = *(const float4*)(b1 + g*8 + 4);
  float4 b1c = *(const float4*)(b1 + 32 + g*8), b1d = *(const float4*)(b1 + 32 + g*8 + 4);
  float4 ara = *(const float4*)(att_r + g*8),      arb = *(const float4*)(att_r + g*8 + 4);
  float4 arc = *(const float4*)(att_r + 32 + g*8), ard = *(const float4*)(att_r + 32 + g*8 + 4);
  int ntiles = (N + 15) >> 4;
  for (int tile = blockIdx.x * 4 + wid; tile < ntiles; tile += gridDim.x * 4){
    int n0 = tile * 16;
    int row = n0 + m;
    bool valid = row < N;
    float nav = valid ? na[row] : 0.f;
    float4 x0 = xo4(nav, w1a, b1a), x1 = xo4(nav, w1b, b1b);
    float4 x2 = xo4(nav, w1c, b1c), x3 = xo4(nav, w1d, b1d);
    float xa = dot4(x0, ara) + dot4(x1, arb) + dot4(x2, arc) + dot4(x3, ard);
    xa += __shfl_xor(xa, 16); xa += __shfl_xor(xa, 32);
    if (g == 0 && valid) xr[row] = xa;
    bf8 fa0 = pack8(x0, x1), fa1 = pack8(x2, x3);
    f32x4 yt[4];
#pragma unroll
    for (int t = 0; t < 4; t++){
      f32x4 acc = {0.f, 0.f, 0.f, 0.f};
      acc = __builtin_amdgcn_mfma_f32_16x16x32_bf16(fa0, WG[t * 64 + lane], acc, 0, 0, 0);
      acc = __builtin_amdgcn_mfma_f32_16x16x32_bf16(fa1, WG[(4 + t) * 64 + lane], acc, 0, 0, 0);
      yt[t] = acc;
    }
#pragma unroll
    for (int t = 0; t < 4; t++){
#pragma unroll
      for (int r = 0; r < 4; r++){
        int rw = n0 + g * 4 + r;
        if (rw < N) yb[(size_t)rw * 64 + m + 16 * t] = (ushort)f2bfs(yt[t][r]);
      }
    }
  }
}

// ---------------- bucket histogram (LDS-aggregated) ----------------
__global__ __launch_bounds__(256) void k_bhist(const int* __restrict__ dst,
                                               int* __restrict__ bcnt, int E, int nbuck){
  __shared__ int hist[512];
  hist[threadIdx.x] = 0; hist[256 + threadIdx.x] = 0;
  __syncthreads();
  int e0 = blockIdx.x * 4096;
  int e1 = min(e0 + 4096, E);
  for (int i = e0 + threadIdx.x; i < e1; i += 256)
    atomicAdd(&hist[dst[i] >> BSHIFT], 1);
  __syncthreads();
#pragma unroll
  for (int q = 0; q < 2; q++){
    int j = threadIdx.x + q * 256;
    if (j < nbuck && hist[j] > 0) atomicAdd(&bcnt[j], hist[j]);
  }
}

// ---------------- bucket prefix scan (1 block, 512 threads) ----------------
__global__ void k_bscan(const int* __restrict__ bcnt, int* __restrict__ bbase,
                        int* __restrict__ gtail, int nbuck){
  __shared__ int lds[512];
  int t = threadIdx.x;
  int v = (t < nbuck) ? bcnt[t] : 0;
  lds[t] = v;
  __syncthreads();
  for (int s = 1; s < 512; s <<= 1){
    int tv = (t >= s) ? lds[t - s] : 0;
    __syncthreads();
    lds[t] += tv;
    __syncthreads();
  }
  if (t <= nbuck){
    int excl = (t == 0) ? 0 : lds[t - 1];
    bbase[t] = excl;
    if (t < nbuck) gtail[t] = excl;
  }
}

// ---------------- binned scatter phase A: group edges by dst-bucket (tail-append)
// packed 8B record: {src | drel<<17, ea-bits}
__global__ __launch_bounds__(256) void k_binA(
    const int* __restrict__ dst, const int* __restrict__ src,
    const float* __restrict__ ea, int* __restrict__ gtail,
    int2* __restrict__ tse, int E){
  __shared__ int hist[512], base[512], run[512];
  int e0 = blockIdx.x * 4096;
  int e1 = min(e0 + 4096, E);
  hist[threadIdx.x] = 0; hist[256 + threadIdx.x] = 0;
  run[threadIdx.x] = 0;  run[256 + threadIdx.x] = 0;
  __syncthreads();
  for (int i = e0 + threadIdx.x; i < e1; i += 256)
    atomicAdd(&hist[dst[i] >> BSHIFT], 1);
  __syncthreads();
#pragma unroll
  for (int q = 0; q < 2; q++){
    int j = threadIdx.x + q * 256;
    if (hist[j] > 0) base[j] = atomicAdd(&gtail[j], hist[j]);
  }
  __syncthreads();
  for (int i = e0 + threadIdx.x; i < e1; i += 256){
    int d = dst[i];
    int b = d >> BSHIFT;
    int pos = base[b] + atomicAdd(&run[b], 1);
    tse[pos] = make_int2(src[i] | ((d & 255) << 17), __float_as_int(ea[i]));
  }
}

// ---------------- binned scatter phase B: derive per-node offsets locally + place ----------------
__global__ __launch_bounds__(256) void k_binB(
    const int* __restrict__ bbase, const int2* __restrict__ tse,
    int2* __restrict__ csr, int* __restrict__ off, int N){
  __shared__ int degL[256];
  __shared__ int fillL[256];
  int node0 = blockIdx.x << BSHIFT;
  int node1 = min(node0 + 256, N);
  int nn = node1 - node0;
  int i0 = bbase[blockIdx.x], i1 = bbase[blockIdx.x + 1];
  int t = threadIdx.x;
  degL[t] = 0;
  __syncthreads();
  for (int i = i0 + t; i < i1; i += 256)
    atomicAdd(&degL[(tse[i].x >> 17) & 255], 1);
  __syncthreads();
  // inclusive Hillis-Steele scan over 256 entries
  for (int s = 1; s < 256; s <<= 1){
    int v = (t >= s) ? degL[t - s] : 0;
    __syncthreads();
    degL[t] += v;
    __syncthreads();
  }
  int prev = (t == 0) ? 0 : degL[t - 1];
  fillL[t] = i0 + prev;
  if (t < nn) off[node0 + t] = i0 + prev;
  if (t == 0 && node1 == N) off[N] = i1;
  __syncthreads();
  for (int i = i0 + t; i < i1; i += 256){
    int2 rec = tse[i];
    int drel = (rec.x >> 17) & 255;
    int pos = atomicAdd(&fillL[drel], 1);
    csr[pos] = make_int2(rec.x & 0x1FFFF, rec.y);
  }
}

// ---------------- fused edge kernel: 4 nodes/wave, 16 lanes/node, no-max softmax,
// 2-edge interleaved chains + 4-slot prefetch pipeline (named regs, no runtime indexing)
__global__ void k_edge_f(const int* __restrict__ off, const int2* __restrict__ csr,
                         const ushort* __restrict__ yb, const float* __restrict__ xr,
                         const float* __restrict__ wgc, const float* __restrict__ att_l,
                         float* __restrict__ sout, int N){
  int lane = threadIdx.x & 63;
  int wwid = (blockIdx.x * blockDim.x + threadIdx.x) >> 6;
  int g = lane >> 4, sl = lane & 15;
  int node = wwid * 4 + g;
  if (node >= N) return;
  int i0 = off[node], i1 = off[node + 1];
  float4 wc4 = ((const float4*)wgc)[sl];
  float4 al4 = ((const float4*)att_l)[sl];
  float xrn = xr[node];
  float sg = 0.f;
  float4 acc = make_float4(0.f, 0.f, 0.f, 0.f);
  int cnt = i1 - i0;
  int2 rA = make_int2(0,0), rB = rA, rC = rA, rD = rA;
  ushort4 yA = make_ushort4(0,0,0,0), yB = yA, yC = yA, yD = yA;
  if (cnt > 0){ rA = csr[i0];     yA = ((const ushort4*)(yb + (size_t)rA.x * 64))[sl]; }
  if (cnt > 1){ rB = csr[i0 + 1]; yB = ((const ushort4*)(yb + (size_t)rB.x * 64))[sl]; }
  if (cnt > 2){ rC = csr[i0 + 2]; yC = ((const ushort4*)(yb + (size_t)rC.x * 64))[sl]; }
  if (cnt > 3){ rD = csr[i0 + 3]; yD = ((const ushort4*)(yb + (size_t)rD.x * 64))[sl]; }
  int i = i0;
  for (; i + 1 < i1; i += 2){
    float eaA = __int_as_float(rA.y);
    float eaB = __int_as_float(rB.y);
    float4 heA, heB;
    heA.x = lrelu(bf2f(yA.x) + eaA * wc4.x); heB.x = lrelu(bf2f(yB.x) + eaB * wc4.x);
    heA.y = lrelu(bf2f(yA.y) + eaA * wc4.y); heB.y = lrelu(bf2f(yB.y) + eaB * wc4.y);
    heA.z = lrelu(bf2f(yA.z) + eaA * wc4.z); heB.z = lrelu(bf2f(yB.z) + eaB * wc4.z);
    heA.w = lrelu(bf2f(yA.w) + eaA * wc4.w); heB.w = lrelu(bf2f(yB.w) + eaB * wc4.w);
    // rotate pipeline, issue prefetch for i+4, i+5 (overlaps the reductions below)
    rA = rC; yA = yC; rB = rD; yB = yD;
    if (i + 4 < i1){ rC = csr[i + 4]; yC = ((const ushort4*)(yb + (size_t)rC.x * 64))[sl]; }
    if (i + 5 < i1){ rD = csr[i + 5]; yD = ((const ushort4*)(yb + (size_t)rD.x * 64))[sl]; }
    float pA = dot4(heA, al4), pB = dot4(heB, al4);
    pA += __shfl_xor(pA, 1); pB += __shfl_xor(pB, 1);
    pA += __shfl_xor(pA, 2); pB += __shfl_xor(pB, 2);
    pA += __shfl_xor(pA, 4); pB += __shfl_xor(pB, 4);
    pA += __shfl_xor(pA, 8); pB += __shfl_xor(pB, 8);
    float wa = __expf(lrelu(pA + xrn));
    float wb = __expf(lrelu(pB + xrn));
    sg += wa + wb;
    acc.x += wa * heA.x + wb * heB.x;
    acc.y += wa * heA.y + wb * heB.y;
    acc.z += wa * heA.z + wb * heB.z;
    acc.w += wa * heA.w + wb * heB.w;
  }
  if (i < i1){
    float ea = __int_as_float(rA.y);
    float4 he;
    he.x = lrelu(bf2f(yA.x) + ea * wc4.x);
    he.y = lrelu(bf2f(yA.y) + ea * wc4.y);
    he.z = lrelu(bf2f(yA.z) + ea * wc4.z);
    he.w = lrelu(bf2f(yA.w) + ea * wc4.w);
    float p = dot4(he, al4);
    p += __shfl_xor(p, 1); p += __shfl_xor(p, 2);
    p += __shfl_xor(p, 4); p += __shfl_xor(p, 8);
    float w = __expf(lrelu(p + xrn));
    sg += w;
    acc.x += w * he.x; acc.y += w * he.y;
    acc.z += w * he.z; acc.w += w * he.w;
  }
  float inv = (i1 > i0 && sg > 0.f) ? 1.f / sg : 0.f;
  float4 o = make_float4(acc.x * inv, acc.y * inv, acc.z * inv, acc.w * inv);
  ((float4*)(sout + (size_t)node * 64))[sl] = o;
}

// ---------------- GRU1 via MFMA: block = 64 nodes, wave = 16-node M-tile ----------------
__global__ __launch_bounds__(256) void k_gru1m(
    const float* __restrict__ sout, const float* __restrict__ na,
    const float* __restrict__ w1, const float* __restrict__ b1,
    const ushort* __restrict__ wg2f, const float* __restrict__ bg,
    const ushort* __restrict__ wihf, const ushort* __restrict__ whhf,
    const float* __restrict__ bih, const float* __restrict__ bhh,
    float* __restrict__ x2, int N){
  __shared__ ushort xgl[4][16][72];   // per-wave elu(h) tile, bf16, padded rows
  int lane = threadIdx.x & 63;
  int wid  = threadIdx.x >> 6;
  int m = lane & 15, g = lane >> 4;
  int n0 = blockIdx.x * 64 + wid * 16;
  if (n0 >= N) return;                 // no barriers used -> safe early exit
  int rowc = min(n0 + m, N - 1);
  const float* srow = sout + (size_t)rowc * 64;
  bf8 sa0 = pack8(*(const float4*)(srow + g * 8),      *(const float4*)(srow + g * 8 + 4));
  bf8 sa1 = pack8(*(const float4*)(srow + 32 + g * 8), *(const float4*)(srow + 32 + g * 8 + 4));
  const bf8* WG = (const bf8*)wg2f;
  f32x4 h[4];
#pragma unroll
  for (int t = 0; t < 4; t++){
    f32x4 acc = {0.f, 0.f, 0.f, 0.f};
    acc = __builtin_amdgcn_mfma_f32_16x16x32_bf16(sa0, WG[t * 64 + lane], acc, 0, 0, 0);
    acc = __builtin_amdgcn_mfma_f32_16x16x32_bf16(sa1, WG[(4 + t) * 64 + lane], acc, 0, 0, 0);
    h[t] = acc;
  }
#pragma unroll
  for (int t = 0; t < 4; t++){
    float bgc = bg[m + 16 * t];
#pragma unroll
    for (int r = 0; r < 4; r++){
      float hv = h[t][r] + bgc;
      float xg = hv > 0.f ? hv : __expf(hv) - 1.f;
      xgl[wid][g * 4 + r][m + 16 * t] = (ushort)f2bfs(xg);
    }
  }
  float nav = na[rowc];
  bf8 xoa0 = pack8(xo4(nav, *(const float4*)(w1 + g * 8),      *(const float4*)(b1 + g * 8)),
                   xo4(nav, *(const float4*)(w1 + g * 8 + 4),  *(const float4*)(b1 + g * 8 + 4)));
  bf8 xoa1 = pack8(xo4(nav, *(const float4*)(w1 + 32 + g * 8),     *(const float4*)(b1 + 32 + g * 8)),
                   xo4(nav, *(const float4*)(w1 + 32 + g * 8 + 4), *(const float4*)(b1 + 32 + g * 8 + 4)));
  bf8 xga0 = *(const bf8*)&xgl[wid][m][g * 8];
  bf8 xga1 = *(const bf8*)&xgl[wid][m][32 + g * 8];
  const bf8* WI = (const bf8*)wihf;
  const bf8* WH = (const bf8*)whhf;
#pragma unroll
  for (int t = 0; t < 4; t++){
    f32x4 iR = {0.f,0.f,0.f,0.f}, iZ = iR, iN = iR, hR = iR, hZ = iR, hN = iR;
    iR = __builtin_amdgcn_mfma_f32_16x16x32_bf16(xga0, WI[(t     ) * 64 + lane], iR, 0,0,0);
    iR = __builtin_amdgcn_mfma_f32_16x16x32_bf16(xga1, WI[(12 + t) * 64 + lane], iR, 0,0,0);
    iZ = __builtin_amdgcn_mfma_f32_16x16x32_bf16(xga0, WI[(t +  4) * 64 + lane], iZ, 0,0,0);
    iZ = __builtin_amdgcn_mfma_f32_16x16x32_bf16(xga1, WI[(16 + t) * 64 + lane], iZ, 0,0,0);
    iN = __builtin_amdgcn_mfma_f32_16x16x32_bf16(xga0, WI[(t +  8) * 64 + lane], iN, 0,0,0);
    iN = __builtin_amdgcn_mfma_f32_16x16x32_bf16(xga1, WI[(20 + t) * 64 + lane], iN, 0,0,0);
    hR = __builtin_amdgcn_mfma_f32_16x16x32_bf16(xoa0, WH[(t     ) * 64 + lane], hR, 0,0,0);
    hR = __builtin_amdgcn_mfma_f32_16x16x32_bf16(xoa1, WH[(12 + t) * 64 + lane], hR, 0,0,0);
    hZ = __builtin_amdgcn_mfma_f32_16x16x32_bf16(xoa0, WH[(t +  4) * 64 + lane], hZ, 0,0,0);
    hZ = __builtin_amdgcn_mfma_f32_16x16x32_bf16(xoa1, WH[(16 + t) * 64 + lane], hZ, 0,0,0);
    hN = __builtin_amdgcn_mfma_f32_16x16x32_bf16(xoa0, WH[(t +  8) * 64 + lane], hN, 0,0,0);
    hN = __builtin_amdgcn_mfma_f32_16x16x32_bf16(xoa1, WH[(20 + t) * 64 + lane], hN, 0,0,0);
    int col = m + 16 * t;
    float biR = bih[col], biZ = bih[64 + col], biN = bih[128 + col];
    float bhR = bhh[col], bhZ = bhh[64 + col], bhN = bhh[128 + col];
    float w1c = w1[col], b1c = b1[col];
#pragma unroll
    for (int r = 0; r < 4; r++){
      int node = n0 + g * 4 + r;
      if (node < N){
        float xon = lrelu(na[node] * w1c + b1c);
        float rg = 1.f / (1.f + __expf(-(iR[r] + biR + hR[r] + bhR)));
        float zg = 1.f / (1.f + __expf(-(iZ[r] + biZ + hZ[r] + bhZ)));
        float nn = tanhf(iN[r] + biN + rg * (hN[r] + bhN));
        float xn = (1.f - zg) * nn + zg * xon;
        x2[(size_t)node * 64 + col] = fmaxf(xn, 0.f);
      }
    }
  }
}

// ---------------- part2 via MFMA: xs = x2@wm.T (in-place), tb, osum, max(tb) ----------------
__global__ __launch_bounds__(256) void k_part2m(
    float* __restrict__ xb,            // in: x2 rows; out: xs rows (in-place per tile)
    const ushort* __restrict__ wmf, const float* __restrict__ att_src,
    float* __restrict__ tb, float* __restrict__ scal, int N){
  int lane = threadIdx.x & 63;
  int wid  = threadIdx.x >> 6;
  int m = lane & 15, g = lane >> 4;
  const bf8* WM = (const bf8*)wmf;
  float as_t[4];
#pragma unroll
  for (int t = 0; t < 4; t++) as_t[t] = att_src[m + 16 * t];
  float os[16];
#pragma unroll
  for (int j = 0; j < 16; j++) os[j] = 0.f;
  float tmax = -1e30f;
  int ntiles = (N + 15) >> 4;
  for (int tile = blockIdx.x * 4 + wid; tile < ntiles; tile += gridDim.x * 4){
    int n0 = tile * 16;
    int row = n0 + m;
    bool valid = row < N;
    int rowc = valid ? row : (N - 1);
    const float* xrow = xb + (size_t)rowc * 64;
    float4 a0 = *(const float4*)(xrow + g * 8);
    float4 a1 = *(const float4*)(xrow + g * 8 + 4);
    float4 a2 = *(const float4*)(xrow + 32 + g * 8);
    float4 a3 = *(const float4*)(xrow + 32 + g * 8 + 4);
    if (!valid){ a0 = make_float4(0,0,0,0); a1 = a0; a2 = a0; a3 = a0; }
    os[0]+=a0.x; os[1]+=a0.y; os[2]+=a0.z; os[3]+=a0.w;
    os[4]+=a1.x; os[5]+=a1.y; os[6]+=a1.z; os[7]+=a1.w;
    os[8]+=a2.x; os[9]+=a2.y; os[10]+=a2.z; os[11]+=a2.w;
    os[12]+=a3.x; os[13]+=a3.y; os[14]+=a3.z; os[15]+=a3.w;
    bf8 fa0 = pack8(a0, a1), fa1 = pack8(a2, a3);
    f32x4 xs_t[4];
#pragma unroll
    for (int t = 0; t < 4; t++){
      f32x4 acc = {0.f, 0.f, 0.f, 0.f};
      acc = __builtin_amdgcn_mfma_f32_16x16x32_bf16(fa0, WM[t * 64 + lane], acc, 0, 0, 0);
      acc = __builtin_amdgcn_mfma_f32_16x16x32_bf16(fa1, WM[(4 + t) * 64 + lane], acc, 0, 0, 0);
      xs_t[t] = acc;
    }
    float tpart[4] = {0.f, 0.f, 0.f, 0.f};
#pragma unroll
    for (int t = 0; t < 4; t++){
#pragma unroll
      for (int r = 0; r < 4; r++){
        int rw = n0 + g * 4 + r;
        if (rw < N) xb[(size_t)rw * 64 + m + 16 * t] = xs_t[t][r];
        tpart[r] += xs_t[t][r] * as_t[t];
      }
    }
#pragma unroll
    for (int r = 0; r < 4; r++){
      float v = tpart[r];
      v += __shfl_xor(v, 1); v += __shfl_xor(v, 2);
      v += __shfl_xor(v, 4); v += __shfl_xor(v, 8);
      if (m == 0){
        int rw = n0 + g * 4 + r;
        if (rw < N){ tb[rw] = v; tmax = fmaxf(tmax, v); }
      }
    }
  }
  tmax = wave_max(tmax);
  if (lane == 0) atomicMax((unsigned*)(scal + 131), fkey(tmax));
#pragma unroll
  for (int j = 0; j < 16; j++){
    float v = os[j];
    v += __shfl_xor(v, 1); v += __shfl_xor(v, 2);
    v += __shfl_xor(v, 4); v += __shfl_xor(v, 8);
    os[j] = v;
  }
  __shared__ float osm[4][64];
  if (m == 0){
#pragma unroll
    for (int j = 0; j < 8; j++){
      osm[wid][g * 8 + j]      = os[j];
      osm[wid][32 + g * 8 + j] = os[8 + j];
    }
  }
  __syncthreads();
  if (threadIdx.x < 64)
    atomicAdd(&scal[threadIdx.x],
              osm[0][threadIdx.x] + osm[1][threadIdx.x] + osm[2][threadIdx.x] + osm[3][threadIdx.x]);
}

// ---------------- part2b (1 wave) ----------------
__global__ void k_part2b(float* __restrict__ scal, const float* __restrict__ wm_t,
                         const float* __restrict__ att_dst){
  int lane = threadIdx.x;
  float o = fmaxf(scal[lane], 0.f);
  float acc = 0.f;
  for (int k = 0; k < 64; k++) acc += bcast(o, k) * wm_t[k * 64 + lane];
  float c = wave_sum(acc * att_dst[lane]);
  scal[64 + lane] = o;
  if (lane == 0){
    scal[128] = c;
    float maxtb = funkey(*(unsigned*)(scal + 131));
    scal[130] = lrelu(maxtb + c);   // M = max_n lrelu(tb[n]+c)  (lrelu monotone)
  }
}

// ---------------- a2 weighted sums ----------------
__global__ void k_a2sum(const float* __restrict__ tb, const float* __restrict__ xs,
                        float* __restrict__ scal, int N){
  int lane = threadIdx.x & 63, w = threadIdx.x >> 6;
  int gw = blockIdx.x * 4 + w, nw = gridDim.x * 4;
  float c = scal[128];
  float M = scal[130];
  float hloc = 0.f, sloc = 0.f;
  for (int n = gw; n < N; n += nw){
    float a2 = lrelu(tb[n] + c);
    float wt = __expf(a2 - M);
    sloc += wt;
    hloc += wt * xs[(size_t)n * 64 + lane];
  }
  __shared__ float lds[256];
  __shared__ float sred[4];
  lds[threadIdx.x] = hloc;
  if (lane == 0) sred[w] = sloc;
  __syncthreads();
  if (threadIdx.x < 64)
    atomicAdd(&scal[192 + threadIdx.x],
              lds[threadIdx.x] + lds[64 + threadIdx.x] + lds[128 + threadIdx.x] + lds[192 + threadIdx.x]);
  if (threadIdx.x == 0) atomicAdd(&scal[129], sred[0] + sred[1] + sred[2] + sred[3]);
}

// ---------------- final (1 wave, coalesced transposed weights) ----------------
__global__ void k_final(const float* __restrict__ scal, const float* __restrict__ bm,
                        const float* __restrict__ g2ih_t, const float* __restrict__ g2hh_t,
                        const float* __restrict__ bih, const float* __restrict__ bhh,
                        const float* __restrict__ w2_t, const float* __restrict__ b2,
                        float* __restrict__ dout){
  int lane = threadIdx.x;
  float S  = scal[129];
  float h2 = scal[192 + lane] / S + bm[lane];
  float xg = h2 > 0.f ? h2 : __expf(h2) - 1.f;
  float xo = scal[64 + lane];
  float gir = bih[lane], giz = bih[64 + lane], gin = bih[128 + lane];
  float ghr = bhh[lane], ghz = bhh[64 + lane], ghn = bhh[128 + lane];
  for (int k = 0; k < 64; k++){
    float a = bcast(xg, k), b = bcast(xo, k);
    const float* gi = g2ih_t + k * 192;
    const float* gh = g2hh_t + k * 192;
    gir += a * gi[lane]; giz += a * gi[64 + lane]; gin += a * gi[128 + lane];
    ghr += b * gh[lane]; ghz += b * gh[64 + lane]; ghn += b * gh[128 + lane];
  }
  float r  = 1.f / (1.f + __expf(-(gir + ghr)));
  float z  = 1.f / (1.f + __expf(-(giz + ghz)));
  float nn = tanhf(gin + r * ghn);
  float o2 = fmaxf((1.f - z) * nn + z * xo, 0.f);
  float res = 0.f;
  for (int k = 0; k < 64; k++) res += bcast(o2, k) * w2_t[k * 64 + lane];
  dout[lane] = res + b2[lane];
}

extern "C" void kernel_launch(void* const* d_in, const int* in_sizes, int n_in,
                              void* d_out, int out_size, void* d_ws, size_t ws_size,
                              hipStream_t stream){
  const float* na    = (const float*)d_in[0];
  const float* ea    = (const float*)d_in[1];
  const int*   ei    = (const int*)d_in[2];
  const float* w1    = (const float*)d_in[3];
  const float* b1    = (const float*)d_in[4];
  const float* wg1   = (const float*)d_in[5];
  const float* att_l = (const float*)d_in[6];
  const float* att_r = (const float*)d_in[7];
  const float* wg2   = (const float*)d_in[8];
  const float* bg    = (const float*)d_in[9];
  const float* g1wih = (const float*)d_in[10];
  const float* g1whh = (const float*)d_in[11];
  const float* g1bih = (const float*)d_in[12];
  const float* g1bhh = (const float*)d_in[13];
  const float* wm      = (const float*)d_in[14];
  const float* att_src = (const float*)d_in[15];
  const float* att_dst = (const float*)d_in[16];
  const float* bm      = (const float*)d_in[17];
  const float* g2wih = (const float*)d_in[18];
  const float* g2whh = (const float*)d_in[19];
  const float* g2bih = (const float*)d_in[20];
  const float* g2bhh = (const float*)d_in[21];
  const float* w2    = (const float*)d_in[22];
  const float* b2    = (const float*)d_in[23];

  int N = in_sizes[0];
  int E = in_sizes[1];
  const int* srcArr = ei;
  const int* dstArr = ei + E;

  char* ws = (char*)d_ws;
  size_t cur = 0;
  auto alloc = [&](size_t nbytes) -> char* {
    char* p = ws + cur;
    cur += (nbytes + 255) & ~(size_t)255;
    return p;
  };
  ushort* yb   = (ushort*)alloc((size_t)N * 64 * 2);   // bf16 y
  float* bufC  = (float*)alloc((size_t)N * 64 * 4);    // sout -> x2 -> xs
  float* xr    = (float*)alloc((size_t)N * 4);
  float* tb    = (float*)alloc((size_t)N * 4);
  int*   offA  = (int*)alloc((size_t)(N + 1) * 4);
  int*   bcnt  = (int*)alloc(4096);
  int*   bbase = (int*)alloc(4096);
  int*   gtail = (int*)alloc(4096);
  int2*  csr   = (int2*)alloc((size_t)E * 8);
  int2*  tse   = (int2*)alloc((size_t)E * 8);
  float* scal  = (float*)alloc(4096);
  float* wm_t  = (float*)alloc(64 * 64 * 4);
  float* w2_t  = (float*)alloc(64 * 64 * 4);
  float* g2ih_t= (float*)alloc(64 * 192 * 4);
  float* g2hh_t= (float*)alloc(64 * 192 * 4);
  float* wgc   = (float*)alloc(64 * 4);
  ushort* wg2f = (ushort*)alloc(4096 * 2);
  ushort* wmf  = (ushort*)alloc(4096 * 2);
  ushort* wg1f = (ushort*)alloc(4096 * 2);
  ushort* wihf = (ushort*)alloc(12288 * 2);
  ushort* whhf = (ushort*)alloc(12288 * 2);
  if (cur > ws_size) return;

  hipMemsetAsync(bcnt, 0, 4096, stream);
  hipMemsetAsync(scal, 0, 4096, stream);

  k_wprep<<<64, 192, 0, stream>>>(wg1, wm, w2, g2wih, g2whh,
                                  wm_t, w2_t, g2ih_t, g2hh_t, wgc);
  k_wfrag<<<18, 256, 0, stream>>>(wg2, wm, wg1, g1wih, g1whh,
                                  wg2f, wmf, wg1f, wihf, whhf);

  int nbuck = (N + 255) >> BSHIFT;
  k_node_m<<<512, 256, 0, stream>>>(na, w1, b1, wg1f, att_r, yb, xr, N);
  k_bhist<<<(E + 4095) / 4096, 256, 0, stream>>>(dstArr, bcnt, E, nbuck);
  k_bscan<<<1, 512, 0, stream>>>(bcnt, bbase, gtail, nbuck);
  k_binA<<<(E + 4095) / 4096, 256, 0, stream>>>(dstArr, srcArr, ea, gtail, tse, E);
  k_binB<<<nbuck, 256, 0, stream>>>(bbase, tse, csr, offA, N);
  int nwb2 = (N + 15) / 16;        // 4 waves/block, 4 nodes/wave
  k_edge_f<<<nwb2, 256, 0, stream>>>(offA, csr, yb, xr, wgc, att_l, bufC, N);
  int ngb = (N + 63) / 64;         // 4 waves/block, 16 nodes/wave (MFMA)
  k_gru1m<<<ngb, 256, 0, stream>>>(bufC, na, w1, b1, wg2f, bg, wihf, whhf,
                                   g1bih, g1bhh, bufC, N);
  k_part2m<<<512, 256, 0, stream>>>(bufC, wmf, att_src, tb, scal, N);
  k_part2b<<<1, 64, 0, stream>>>(scal, wm_t, att_dst);
  k_a2sum<<<512, 256, 0, stream>>>(tb, bufC, scal, N);
  k_final<<<1, 64, 0, stream>>>(scal, bm, g2ih_t, g2hh_t, g2bih, g2bhh, w2_t, b2, (float*)d_out);
  (void)n_in; (void)out_size;
}